// Round 2
// baseline (4585.671 us; speedup 1.0000x reference)
//
#include <hip/hip_runtime.h>
#include <math.h>
#include <float.h>

#define B_ 64
#define N_ 197
#define C_ 768
#define H_ 12
#define CH_ 64
#define RC_ 32
#define RN_ 24

__device__ __forceinline__ float warp_sum(float v){
  #pragma unroll
  for(int o=32;o>=1;o>>=1) v += __shfl_xor(v,o);
  return v;
}
__device__ __forceinline__ float warp_max(float v){
  #pragma unroll
  for(int o=32;o>=1;o>>=1) v = fmaxf(v,__shfl_xor(v,o));
  return v;
}

// ---------------- LayerNorm: one block per row of 768 ----------------
__global__ __launch_bounds__(256) void ln_kernel(const float* __restrict__ x,
    const float* __restrict__ g, const float* __restrict__ bb, float* __restrict__ out){
  int r = blockIdx.x; int tid = threadIdx.x;
  const float* xr = x + (size_t)r*C_;
  float v0=xr[tid], v1=xr[tid+256], v2=xr[tid+512];
  __shared__ float red[8];
  float s = warp_sum(v0+v1+v2);
  if((tid&63)==0) red[tid>>6]=s;
  __syncthreads();
  float mu = (red[0]+red[1]+red[2]+red[3]) * (1.f/768.f);
  float d0=v0-mu,d1=v1-mu,d2=v2-mu;
  float s2 = warp_sum(d0*d0+d1*d1+d2*d2);
  if((tid&63)==0) red[4+(tid>>6)]=s2;
  __syncthreads();
  float rinv = rsqrtf((red[4]+red[5]+red[6]+red[7])*(1.f/768.f)+1e-5f);
  float* orow = out + (size_t)r*C_;
  orow[tid]     = d0*rinv*g[tid]    +bb[tid];
  orow[tid+256] = d1*rinv*g[tid+256]+bb[tid+256];
  orow[tid+512] = d2*rinv*g[tid+512]+bb[tid+512];
}

// ---------------- Generic f32 GEMM: C = act(A@W + bias) + resid ----------------
// 64x64 tile, BK=16, 256 threads, 4x4 per thread. M%64==0, Nc%64==0, K%16==0.
template<int ACT, bool RESID>
__global__ __launch_bounds__(256) void gemm_f32(
    const float* __restrict__ A, const float* __restrict__ W,
    const float* __restrict__ bias, const float* __restrict__ resid,
    float* __restrict__ Cout, int M, int K, int Nc){
  __shared__ float As[16][64];   // [k][m]
  __shared__ float Bs[16][64];   // [k][n]
  int tid=threadIdx.x;
  int n0 = blockIdx.x*64, m0 = blockIdx.y*64;
  int ty = tid>>4, tx = tid&15;
  int arow = tid>>2, ak4 = (tid&3)*4;
  int brow = tid>>4, bc4 = (tid&15)*4;
  const float* Aptr = A + (size_t)(m0+arow)*K + ak4;
  const float* Wptr = W + (size_t)brow*Nc + n0 + bc4;
  float acc[4][4]={};
  for(int kt=0;kt<K;kt+=16){
    float4 a4 = *(const float4*)(Aptr + kt);
    float4 b4 = *(const float4*)(Wptr + (size_t)kt*Nc);
    As[ak4+0][arow]=a4.x; As[ak4+1][arow]=a4.y; As[ak4+2][arow]=a4.z; As[ak4+3][arow]=a4.w;
    *(float4*)&Bs[brow][bc4]=b4;
    __syncthreads();
    #pragma unroll
    for(int kk=0;kk<16;++kk){
      float4 av=*(const float4*)&As[kk][ty*4];
      float4 bv=*(const float4*)&Bs[kk][tx*4];
      float a_[4]={av.x,av.y,av.z,av.w};
      float b_[4]={bv.x,bv.y,bv.z,bv.w};
      #pragma unroll
      for(int i=0;i<4;++i)
        #pragma unroll
        for(int j=0;j<4;++j) acc[i][j] += a_[i]*b_[j];
    }
    __syncthreads();
  }
  #pragma unroll
  for(int i=0;i<4;++i){
    size_t rrow = (size_t)(m0+ty*4+i);
    float4 cv4;
    float* cvp = &cv4.x;
    #pragma unroll
    for(int j=0;j<4;++j){
      int ccol = n0+tx*4+j;
      float cv = acc[i][j];
      if(bias) cv += bias[ccol];
      if(ACT==1){ cv = 0.5f*cv*(1.0f+erff(cv*0.70710678118654752f)); }
      cvp[j]=cv;
    }
    if(RESID){
      float4 r4 = *(const float4*)&resid[rrow*Nc + n0 + tx*4];
      cv4.x+=r4.x; cv4.y+=r4.y; cv4.z+=r4.z; cv4.w+=r4.w;
    }
    *(float4*)&Cout[rrow*Nc + n0 + tx*4] = cv4;
  }
}

// ---------------- qp/kp: per (b,h,n) row, 64x32 matvec ----------------
__global__ __launch_bounds__(256) void qkproj_kernel(const float* __restrict__ qkv,
    const float* __restrict__ Wc, const float* __restrict__ bc,
    float* __restrict__ outp, int sel){
  int r = blockIdx.x*8 + (threadIdx.x>>5);
  int col = threadIdx.x&31;
  int b = r/(H_*N_); int rem = r%(H_*N_); int h = rem/N_; int n = rem%N_;
  const float* src = qkv + ((size_t)(b*N_+n)*3 + sel)*C_ + h*CH_;
  float acc = bc[col];
  #pragma unroll
  for(int ch=0;ch<CH_;++ch) acc += src[ch]*Wc[ch*RC_+col];
  outp[(size_t)r*RC_+col]=acc;
}

// ---------------- kk[b,h,c,r] = sum_n kp[b,h,n,c]*proj_n[n,r] ----------------
__global__ __launch_bounds__(768) void kk_kernel(const float* __restrict__ kp,
    const float* __restrict__ proj_n, float* __restrict__ kkb){
  int bh = blockIdx.x;
  int t = threadIdx.x;            // 768 = 32*24
  int c = t/RN_, rr = t%RN_;
  const float* kpb = kp + (size_t)bh*N_*RC_;
  float acc = 0.f;
  for(int n=0;n<N_;++n) acc += kpb[n*RC_+c]*proj_n[n*RN_+rr];
  kkb[(size_t)bh*RC_*RN_ + c*RN_ + rr] = acc;
}

// ---------------- cheap + softmax + keep-top8: one wave per (b,h,n>=1) ----------------
__global__ __launch_bounds__(256) void coef_kernel(const float* __restrict__ qp,
    const float* __restrict__ kkb, float* __restrict__ coef){
  int wid = blockIdx.x*4 + (threadIdx.x>>6);   // (b*H+h)*196 + (n-1)
  int lane = threadIdx.x&63;
  int b = wid/(H_*196); int rem = wid%(H_*196); int h = rem/196; int n = rem%196+1;
  int bh = b*H_+h;
  const float* qpr = qp + ((size_t)bh*N_ + n)*RC_;
  const float* kkp = kkb + (size_t)bh*RC_*RN_;
  float val = -INFINITY;
  if(lane<RN_){
    float acc=0.f;
    #pragma unroll
    for(int c=0;c<RC_;++c) acc += qpr[c]*kkp[c*RN_+lane];
    val = acc * 0.28867513459481287f;   // H^-0.5
  }
  float m = warp_max(val);
  float e = (lane<RN_)? expf(val-m):0.f;
  float ssum = warp_sum(e);
  float p = e/ssum;
  float myv = (lane<RN_)? p : -1.f;
  int cnt=0;
  #pragma unroll
  for(int j=0;j<RN_;++j){ float vj = __shfl(myv, j); cnt += (vj>myv)?1:0; }
  if(lane<RN_) coef[(size_t)wid*RN_+lane] = (cnt<=7)? p : 0.f;
}

// ---------------- basis[r][j] = thresh(|proj_back_n[j][r]|) ----------------
__global__ __launch_bounds__(256) void basis_kernel(const float* __restrict__ pb,
    float* __restrict__ basis){
  int t = blockIdx.x*256 + threadIdx.x;
  if(t < RN_*N_){
    int r = t/N_, j = t%N_;
    float v = fabsf(pb[(size_t)j*RN_ + r]);
    basis[t] = (v > 0.02f) ? v : 0.f;
  }
}

// ---------------- approx_attn + budget top-50 mask (bitwords, 8 u32/row) ----------------
__global__ __launch_bounds__(256) void mask_kernel(const float* __restrict__ coef,
    const float* __restrict__ basis, unsigned int* __restrict__ maskw){
  int row = blockIdx.x;           // (b*H+h)*197 + qi
  int qi = row % N_; int bh = row / N_;
  int tid = threadIdx.x;
  if(qi==0){
    if(tid<8){
      unsigned v = (tid<6)?0xFFFFFFFFu:((tid==6)?0x1Fu:0u);
      maskw[(size_t)row*8+tid]=v;
    }
    return;
  }
  __shared__ float cf[RN_];
  __shared__ float a[N_];
  if(tid<RN_) cf[tid] = coef[((size_t)bh*196 + (qi-1))*RN_ + tid];
  __syncthreads();
  float mv = 0.f;
  if(tid<N_){
    float acc=0.f;
    #pragma unroll
    for(int r=0;r<RN_;++r) acc += cf[r]*basis[r*N_+tid];
    a[tid]=acc; mv=acc;
  }
  __syncthreads();
  bool keep=false;
  if(tid<N_){
    int cnt=0;
    for(int i=0;i<N_;++i) cnt += (a[i] > mv)?1:0;
    keep = (cnt <= 49);           // BUDGET=50 -> rank<=49 <=> a >= 50th largest
  }
  unsigned long long bal = __ballot(keep);
  if((tid&63)==0){
    int w = tid>>6;
    maskw[(size_t)row*8 + 2*w]   = (unsigned)(bal & 0xFFFFFFFFull);
    maskw[(size_t)row*8 + 2*w+1] = (unsigned)(bal>>32);
  }
}

// ---------------- masked attention: one block per (b,h,qi) ----------------
__global__ __launch_bounds__(256) void attn_kernel(const float* __restrict__ qkv,
    const unsigned int* __restrict__ maskw, float* __restrict__ attn_out){
  int row = blockIdx.x;           // (b*H+h)*197 + qi
  int qi = row % N_; int bh = row / N_; int h = bh % H_; int b = bh / H_;
  int tid = threadIdx.x;
  __shared__ float qrow[CH_];
  __shared__ float p[N_];
  __shared__ float red[8];
  __shared__ float pv[4][CH_];
  if(tid<CH_) qrow[tid] = qkv[((size_t)(b*N_+qi)*3)*C_ + h*CH_ + tid] * 0.125f;
  __syncthreads();
  bool ok=false; float s=0.f;
  if(tid<N_){
    ok = (maskw[(size_t)row*8 + (tid>>5)] >> (tid&31)) & 1u;
    if(ok){
      const float* kr = qkv + ((size_t)(b*N_+tid)*3 + 1)*C_ + h*CH_;
      float acc=0.f;
      #pragma unroll
      for(int c=0;c<CH_;++c) acc += qrow[c]*kr[c];
      s = acc;
    }
  }
  float m = warp_max(ok ? s : -FLT_MAX);
  if((tid&63)==0) red[tid>>6]=m;
  __syncthreads();
  m = fmaxf(fmaxf(red[0],red[1]),fmaxf(red[2],red[3]));
  float e = ok ? expf(s-m) : 0.f;
  float ssum = warp_sum(e);
  if((tid&63)==0) red[4+(tid>>6)]=ssum;
  __syncthreads();
  float tot = red[4]+red[5]+red[6]+red[7];
  if(tid<N_) p[tid] = e/tot;
  __syncthreads();
  int c = tid&63, jg = tid>>6;
  float acc = 0.f;
  for(int j=jg;j<N_;j+=4){
    acc += p[j] * qkv[((size_t)(b*N_+j)*3 + 2)*C_ + h*CH_ + c];
  }
  pv[jg][c]=acc;
  __syncthreads();
  if(tid<CH_){
    attn_out[((size_t)(b*N_+qi))*C_ + h*CH_ + tid] = pv[0][tid]+pv[1][tid]+pv[2][tid]+pv[3][tid];
  }
}

extern "C" void kernel_launch(void* const* d_in, const int* in_sizes, int n_in,
                              void* d_out, int out_size, void* d_ws, size_t ws_size,
                              hipStream_t stream){
  const float* x    =(const float*)d_in[0];
  const float* Wqkv =(const float*)d_in[1];
  const float* Wcq  =(const float*)d_in[2];
  const float* bcq  =(const float*)d_in[3];
  const float* Wck  =(const float*)d_in[4];
  const float* bck  =(const float*)d_in[5];
  const float* proj_n=(const float*)d_in[6];
  const float* proj_back_n=(const float*)d_in[7];
  const float* Wproj=(const float*)d_in[8];
  const float* bproj=(const float*)d_in[9];
  const float* g1=(const float*)d_in[10];
  const float* b1=(const float*)d_in[11];
  const float* g2=(const float*)d_in[12];
  const float* b2=(const float*)d_in[13];
  const float* W1=(const float*)d_in[14];
  const float* bfc1=(const float*)d_in[15];
  const float* W2=(const float*)d_in[16];
  const float* bfc2=(const float*)d_in[17];
  float* out=(float*)d_out;

  // ---- workspace layout (floats). Total = 53,832,320 fl = 215.3 MB ----
  // hbuf also serves as attn_out (dead interval between QKV GEMM and LN2).
  // hidden (12608*3072 = 38,731,776 fl) aliases qkv+qp+kp (exactly equal size),
  // all dead by MLP time. x1 lives in d_out (fully overwritten each call).
  float* ws=(float*)d_ws;
  size_t off=0;
  float* hbuf = ws;            off += (size_t)12608*768;    // 9,682,944
  size_t qkv_off = off;
  float* qkv  = ws+off;        off += (size_t)12608*2304;   // 29,048,832
  float* qp   = ws+off;        off += (size_t)768*197*32;   // 4,841,472
  float* kp   = ws+off;        off += (size_t)768*197*32;   // 4,841,472
  float* kkb  = ws+off;        off += (size_t)768*32*24;    // 589,824
  float* coef = ws+off;        off += (size_t)768*196*24;   // 3,612,672
  float* basis= ws+off;        off += 4736;
  unsigned int* maskw=(unsigned int*)(ws+off); off += (size_t)768*197*8; // 1,210,368
  float* attn_out = hbuf;
  float* x1   = out;
  float* hidden = ws + qkv_off;

  // 1. h = LN(x)
  ln_kernel<<<12608,256,0,stream>>>(x,g1,b1,hbuf);
  // 2. qkv = h @ Wqkv
  gemm_f32<0,false><<<dim3(36,197),256,0,stream>>>(hbuf,Wqkv,nullptr,nullptr,qkv,12608,768,2304);
  // 3. qp, kp
  qkproj_kernel<<<18912,256,0,stream>>>(qkv,Wcq,bcq,qp,0);
  qkproj_kernel<<<18912,256,0,stream>>>(qkv,Wck,bck,kp,1);
  // 4. kk
  kk_kernel<<<768,768,0,stream>>>(kp,proj_n,kkb);
  // 5. basis
  basis_kernel<<<19,256,0,stream>>>(proj_back_n,basis);
  // 6. cheap + softmax + top8
  coef_kernel<<<37632,256,0,stream>>>(qp,kkb,coef);
  // 7. approx_attn + budget mask
  mask_kernel<<<151296,256,0,stream>>>(coef,basis,maskw);
  // 8. masked attention (writes attn_out == hbuf)
  attn_kernel<<<151296,256,0,stream>>>(qkv,maskw,attn_out);
  // 9. x1 = x + attn_out @ Wproj + bproj   (x1 == d_out)
  gemm_f32<0,true><<<dim3(12,197),256,0,stream>>>(attn_out,Wproj,bproj,x,x1,12608,768,768);
  // 10. h2 = LN(x1) (reuse hbuf)
  ln_kernel<<<12608,256,0,stream>>>(x1,g2,b2,hbuf);
  // 11. hidden = gelu(h2 @ W1 + bfc1)   (hidden aliases dead qkv/qp/kp)
  gemm_f32<1,false><<<dim3(48,197),256,0,stream>>>(hbuf,W1,bfc1,nullptr,hidden,12608,768,3072);
  // 12. out = x1 + hidden @ W2 + bfc2   (reads+overwrites d_out elementwise)
  gemm_f32<0,true><<<dim3(12,197),256,0,stream>>>(hidden,W2,bfc2,x1,out,12608,3072,768);
}

// Round 3
// 2488.077 us; speedup vs baseline: 1.8431x; 1.8431x over previous
//
#include <hip/hip_runtime.h>
#include <math.h>
#include <float.h>

#define B_ 64
#define N_ 197
#define C_ 768
#define H_ 12
#define CH_ 64
#define RC_ 32
#define RN_ 24

typedef __attribute__((ext_vector_type(8))) short short8;
typedef __attribute__((ext_vector_type(4))) short shortv4;
typedef __attribute__((ext_vector_type(4))) float f32x4;
typedef __attribute__((address_space(3))) void  lds_void;
typedef __attribute__((address_space(1))) const void g_void;

__device__ __forceinline__ float warp_sum(float v){
  #pragma unroll
  for(int o=32;o>=1;o>>=1) v += __shfl_xor(v,o);
  return v;
}
__device__ __forceinline__ float warp_max(float v){
  #pragma unroll
  for(int o=32;o>=1;o>>=1) v = fmaxf(v,__shfl_xor(v,o));
  return v;
}
__device__ __forceinline__ unsigned short f2bf(float f){
  union{float f; unsigned u;} c; c.f = f;
  unsigned r = c.u + 0x7FFF + ((c.u>>16)&1);
  return (unsigned short)(r>>16);
}
__device__ __forceinline__ float bf2f(unsigned short u){
  union{unsigned u; float f;} c; c.u = ((unsigned)u)<<16; return c.f;
}

// ---------------- LayerNorm: one block per row of 768, bf16 out ----------------
__global__ __launch_bounds__(256) void ln_kernel(const float* __restrict__ x,
    const float* __restrict__ g, const float* __restrict__ bb, unsigned short* __restrict__ out){
  int r = blockIdx.x; int tid = threadIdx.x;
  const float* xr = x + (size_t)r*C_;
  float v0=xr[tid], v1=xr[tid+256], v2=xr[tid+512];
  __shared__ float red[8];
  float s = warp_sum(v0+v1+v2);
  if((tid&63)==0) red[tid>>6]=s;
  __syncthreads();
  float mu = (red[0]+red[1]+red[2]+red[3]) * (1.f/768.f);
  float d0=v0-mu,d1=v1-mu,d2=v2-mu;
  float s2 = warp_sum(d0*d0+d1*d1+d2*d2);
  if((tid&63)==0) red[4+(tid>>6)]=s2;
  __syncthreads();
  float rinv = rsqrtf((red[4]+red[5]+red[6]+red[7])*(1.f/768.f)+1e-5f);
  unsigned short* orow = out + (size_t)r*C_;
  orow[tid]     = f2bf(d0*rinv*g[tid]    +bb[tid]);
  orow[tid+256] = f2bf(d1*rinv*g[tid+256]+bb[tid+256]);
  orow[tid+512] = f2bf(d2*rinv*g[tid+512]+bb[tid+512]);
}

// ---------------- transpose+convert: in f32 [K][N] -> out bf16 [N][K] ----------------
__global__ __launch_bounds__(256) void wtrans_kernel(const float* __restrict__ in,
    unsigned short* __restrict__ out, int K, int N){
  __shared__ float tile[32][33];
  int n0 = blockIdx.x*32, k0 = blockIdx.y*32;
  int tx = threadIdx.x&31, ty = threadIdx.x>>5;   // ty: 8 rows per pass
  #pragma unroll
  for(int i=0;i<4;++i) tile[ty+8*i][tx] = in[(size_t)(k0+ty+8*i)*N + n0+tx];
  __syncthreads();
  #pragma unroll
  for(int i=0;i<4;++i) out[(size_t)(n0+ty+8*i)*K + k0+tx] = f2bf(tile[tx][ty+8*i]);
}

// ---------------- bf16 MFMA GEMM: Cout = act(A@W + bias) + resid ----------------
// A [M][K] bf16, WT [Nc][K] bf16. 128x128 tile, BK=32, 256 thr, 4 waves each 64x64.
template<int ACT, int RESID, int OUTBF16>
__global__ __launch_bounds__(256) void gemm_bf16(
    const unsigned short* __restrict__ A, const unsigned short* __restrict__ WT,
    const float* __restrict__ bias, const float* __restrict__ resid,
    void* __restrict__ Cout, int M, int K, int Nc){
  __shared__ unsigned short As[128*32];
  __shared__ unsigned short Bs[128*32];
  int tid = threadIdx.x, lane = tid&63, wid = tid>>6;
  int m0 = blockIdx.y*128, n0 = blockIdx.x*128;
  int wr = wid>>1, wc = wid&1;
  int lm = lane&15, lg = lane>>4;
  f32x4 acc[4][4] = {};
  for(int kt=0; kt<K; kt+=32){
    #pragma unroll
    for(int it=0; it<2; ++it){
      int ci = it*256 + tid;
      int row = ci>>2, kc=(ci&3)*8;
      int ar = m0+row; if(ar > M-1) ar = M-1;
      const unsigned short* ga = A  + (size_t)ar*K        + kt + kc;
      const unsigned short* gb = WT + (size_t)(n0+row)*K  + kt + kc;
      __builtin_amdgcn_global_load_lds((g_void*)ga, (lds_void*)(As + (it*256 + wid*64)*8), 16, 0, 0);
      __builtin_amdgcn_global_load_lds((g_void*)gb, (lds_void*)(Bs + (it*256 + wid*64)*8), 16, 0, 0);
    }
    __syncthreads();
    short8 af[4], bfv[4];
    #pragma unroll
    for(int i=0;i<4;++i){
      af[i]  = *(const short8*)(As + (64*wr + 16*i + lm)*32 + lg*8);
      bfv[i] = *(const short8*)(Bs + (64*wc + 16*i + lm)*32 + lg*8);
    }
    #pragma unroll
    for(int i=0;i<4;++i)
      #pragma unroll
      for(int j=0;j<4;++j)
        acc[i][j] = __builtin_amdgcn_mfma_f32_16x16x32_bf16(af[i], bfv[j], acc[i][j], 0,0,0);
    __syncthreads();
  }
  // epilogue: D row = (lane>>4)*4 + r, col = lane&15  (within each 16x16 frag)
  #pragma unroll
  for(int i=0;i<4;++i){
    #pragma unroll
    for(int j=0;j<4;++j){
      int gcol = n0 + 64*wc + 16*j + lm;
      float bv = bias ? bias[gcol] : 0.f;
      #pragma unroll
      for(int r=0;r<4;++r){
        int grow = m0 + 64*wr + 16*i + lg*4 + r;
        if(grow < M){
          float cv = acc[i][j][r] + bv;
          if(ACT==1) cv = 0.5f*cv*(1.0f+erff(cv*0.70710678118654752f));
          if(RESID) cv += resid[(size_t)grow*Nc + gcol];
          if(OUTBF16) ((unsigned short*)Cout)[(size_t)grow*Nc+gcol] = f2bf(cv);
          else        ((float*)Cout)[(size_t)grow*Nc+gcol] = cv;
        }
      }
    }
  }
}

// ---------------- qp/kp: per (b,h,n) row, 64x32 matvec ----------------
__global__ __launch_bounds__(256) void qkproj_kernel(const float* __restrict__ qkv,
    const float* __restrict__ Wc, const float* __restrict__ bc,
    float* __restrict__ outp, int sel){
  int r = blockIdx.x*8 + (threadIdx.x>>5);
  int col = threadIdx.x&31;
  int b = r/(H_*N_); int rem = r%(H_*N_); int h = rem/N_; int n = rem%N_;
  const float* src = qkv + ((size_t)(b*N_+n)*3 + sel)*C_ + h*CH_;
  float acc = bc[col];
  #pragma unroll
  for(int ch=0;ch<CH_;++ch) acc += src[ch]*Wc[ch*RC_+col];
  outp[(size_t)r*RC_+col]=acc;
}

// ---------------- kk[b,h,c,r] = sum_n kp[b,h,n,c]*proj_n[n,r] ----------------
__global__ __launch_bounds__(768) void kk_kernel(const float* __restrict__ kp,
    const float* __restrict__ proj_n, float* __restrict__ kkb){
  int bh = blockIdx.x;
  int t = threadIdx.x;            // 768 = 32*24
  int c = t/RN_, rr = t%RN_;
  const float* kpb = kp + (size_t)bh*N_*RC_;
  float acc = 0.f;
  for(int n=0;n<N_;++n) acc += kpb[n*RC_+c]*proj_n[n*RN_+rr];
  kkb[(size_t)bh*RC_*RN_ + c*RN_ + rr] = acc;
}

// ---------------- cheap + softmax + keep-top8: one wave per (b,h,n>=1) ----------------
__global__ __launch_bounds__(256) void coef_kernel(const float* __restrict__ qp,
    const float* __restrict__ kkb, float* __restrict__ coef){
  int wid = blockIdx.x*4 + (threadIdx.x>>6);   // (b*H+h)*196 + (n-1)
  int lane = threadIdx.x&63;
  int b = wid/(H_*196); int rem = wid%(H_*196); int h = rem/196; int n = rem%196+1;
  int bh = b*H_+h;
  const float* qpr = qp + ((size_t)bh*N_ + n)*RC_;
  const float* kkp = kkb + (size_t)bh*RC_*RN_;
  float val = -INFINITY;
  if(lane<RN_){
    float acc=0.f;
    #pragma unroll
    for(int c=0;c<RC_;++c) acc += qpr[c]*kkp[c*RN_+lane];
    val = acc * 0.28867513459481287f;   // H^-0.5
  }
  float m = warp_max(val);
  float e = (lane<RN_)? expf(val-m):0.f;
  float ssum = warp_sum(e);
  float p = e/ssum;
  float myv = (lane<RN_)? p : -1.f;
  int cnt=0;
  #pragma unroll
  for(int j=0;j<RN_;++j){ float vj = __shfl(myv, j); cnt += (vj>myv)?1:0; }
  if(lane<RN_) coef[(size_t)wid*RN_+lane] = (cnt<=7)? p : 0.f;
}

// ---------------- basis[r][j] = thresh(|proj_back_n[j][r]|) ----------------
__global__ __launch_bounds__(256) void basis_kernel(const float* __restrict__ pb,
    float* __restrict__ basis){
  int t = blockIdx.x*256 + threadIdx.x;
  if(t < RN_*N_){
    int r = t/N_, j = t%N_;
    float v = fabsf(pb[(size_t)j*RN_ + r]);
    basis[t] = (v > 0.02f) ? v : 0.f;
  }
}

// ---------------- approx_attn + budget top-50 mask (bitwords, 8 u32/row) ----------------
__global__ __launch_bounds__(256) void mask_kernel(const float* __restrict__ coef,
    const float* __restrict__ basis, unsigned int* __restrict__ maskw){
  int row = blockIdx.x;           // (b*H+h)*197 + qi
  int qi = row % N_; int bh = row / N_;
  int tid = threadIdx.x;
  if(qi==0){
    if(tid<8){
      unsigned v = (tid<6)?0xFFFFFFFFu:((tid==6)?0x1Fu:0u);
      maskw[(size_t)row*8+tid]=v;
    }
    return;
  }
  __shared__ float cf[RN_];
  __shared__ float a[N_];
  if(tid<RN_) cf[tid] = coef[((size_t)bh*196 + (qi-1))*RN_ + tid];
  __syncthreads();
  float mv = 0.f;
  if(tid<N_){
    float acc=0.f;
    #pragma unroll
    for(int r=0;r<RN_;++r) acc += cf[r]*basis[r*N_+tid];
    a[tid]=acc; mv=acc;
  }
  __syncthreads();
  bool keep=false;
  if(tid<N_){
    int cnt=0;
    for(int i=0;i<N_;++i) cnt += (a[i] > mv)?1:0;
    keep = (cnt <= 49);           // BUDGET=50 -> rank<=49 <=> a >= 50th largest
  }
  unsigned long long bal = __ballot(keep);
  if((tid&63)==0){
    int w = tid>>6;
    maskw[(size_t)row*8 + 2*w]   = (unsigned)(bal & 0xFFFFFFFFull);
    maskw[(size_t)row*8 + 2*w+1] = (unsigned)(bal>>32);
  }
}

// ---------------- masked attention v2: one block per (b,h), K^T/V staged in LDS ----------------
__global__ __launch_bounds__(256) void attn2_kernel(const float* __restrict__ qkv,
    const unsigned int* __restrict__ maskw, unsigned short* __restrict__ attn_out){
  int bh = blockIdx.x; int b = bh/H_, h = bh%H_;
  int tid = threadIdx.x, lane = tid&63, w = tid>>6;
  __shared__ unsigned short Kt[64][200];   // [c][k], rows 400B: score reads contiguous per lane
  __shared__ unsigned short Vb[197][66];   // [k][c], rows 132B: PV reads conflict-free
  __shared__ float ps[4][200];             // per-wave probs
  __shared__ float qs[4][64];              // per-wave scaled q row
  const float* Kbase = qkv + ((size_t)(b*N_)*3 + 1)*C_ + h*CH_;
  const float* Vbase = qkv + ((size_t)(b*N_)*3 + 2)*C_ + h*CH_;
  for(int idx = tid; idx < N_*32; idx += 256){
    int k = idx>>5, cp = (idx&31)*2;
    float2 kv = *(const float2*)(Kbase + (size_t)k*3*C_ + cp);
    Kt[cp][k]   = f2bf(kv.x);
    Kt[cp+1][k] = f2bf(kv.y);
    float2 vv = *(const float2*)(Vbase + (size_t)k*3*C_ + cp);
    unsigned pk = (unsigned)f2bf(vv.x) | ((unsigned)f2bf(vv.y)<<16);
    *(unsigned*)&Vb[k][cp] = pk;
  }
  if(tid < 64){ Kt[tid][197]=0; Kt[tid][198]=0; Kt[tid][199]=0; }
  __syncthreads();
  for(int q0=0; q0<N_; q0+=4){
    int q = q0 + w;
    if(q >= N_) continue;
    qs[w][lane] = qkv[((size_t)(b*N_+q)*3)*C_ + h*CH_ + lane] * 0.125f;
    int kb = lane*4;
    bool act = (lane < 50);          // lanes cover k-quads 0..199
    float s0=0.f,s1=0.f,s2=0.f,s3=0.f;
    if(act){
      #pragma unroll 4
      for(int c=0;c<CH_;++c){
        float f = qs[w][c];
        shortv4 kv = *(const shortv4*)&Kt[c][kb];
        s0 += f*bf2f((unsigned short)kv[0]);
        s1 += f*bf2f((unsigned short)kv[1]);
        s2 += f*bf2f((unsigned short)kv[2]);
        s3 += f*bf2f((unsigned short)kv[3]);
      }
    }
    unsigned mword = act ? maskw[(size_t)(bh*N_+q)*8 + (kb>>5)] : 0u;
    int sh = kb&31;
    bool k0ok = (mword>>(sh+0))&1, k1ok = (mword>>(sh+1))&1;
    bool k2ok = (mword>>(sh+2))&1, k3ok = (mword>>(sh+3))&1;
    float v0 = k0ok? s0 : -FLT_MAX, v1 = k1ok? s1 : -FLT_MAX;
    float v2 = k2ok? s2 : -FLT_MAX, v3 = k3ok? s3 : -FLT_MAX;
    float m = warp_max(fmaxf(fmaxf(v0,v1),fmaxf(v2,v3)));
    float e0 = k0ok? expf(s0-m):0.f, e1 = k1ok? expf(s1-m):0.f;
    float e2 = k2ok? expf(s2-m):0.f, e3 = k3ok? expf(s3-m):0.f;
    float tot = warp_sum(e0+e1+e2+e3);
    float inv = 1.f/tot;
    if(act){
      float4 pv4 = make_float4(e0*inv, e1*inv, e2*inv, e3*inv);
      *(float4*)&ps[w][kb] = pv4;
    }
    float o = 0.f;
    for(int k2i=0;k2i<N_;++k2i){
      float pk = ps[w][k2i];
      if(pk != 0.f) o += pk * bf2f(Vb[k2i][lane]);
    }
    attn_out[((size_t)(b*N_+q))*C_ + h*CH_ + lane] = f2bf(o);
  }
}

extern "C" void kernel_launch(void* const* d_in, const int* in_sizes, int n_in,
                              void* d_out, int out_size, void* d_ws, size_t ws_size,
                              hipStream_t stream){
  const float* x    =(const float*)d_in[0];
  const float* Wqkv =(const float*)d_in[1];
  const float* Wcq  =(const float*)d_in[2];
  const float* bcq  =(const float*)d_in[3];
  const float* Wck  =(const float*)d_in[4];
  const float* bck  =(const float*)d_in[5];
  const float* proj_n=(const float*)d_in[6];
  const float* proj_back_n=(const float*)d_in[7];
  const float* Wproj=(const float*)d_in[8];
  const float* bproj=(const float*)d_in[9];
  const float* g1=(const float*)d_in[10];
  const float* b1=(const float*)d_in[11];
  const float* g2=(const float*)d_in[12];
  const float* b2=(const float*)d_in[13];
  const float* W1=(const float*)d_in[14];
  const float* bfc1=(const float*)d_in[15];
  const float* W2=(const float*)d_in[16];
  const float* bfc2=(const float*)d_in[17];
  float* out=(float*)d_out;

  // ---- workspace layout (float slots). Total = 52,529,792 fl = 210.1 MB ----
  float* ws=(float*)d_ws;
  size_t off=0;
  unsigned short* hbuf = (unsigned short*)(ws+off); off += (size_t)12608*768/2;  // bf16, aliased as attn_out
  size_t qkv_off = off;
  float* qkv  = ws+off;        off += (size_t)12608*2304;
  float* qp   = ws+off;        off += (size_t)768*197*32;
  float* kp   = ws+off;        off += (size_t)768*197*32;
  float* kkb  = ws+off;        off += (size_t)768*32*24;
  float* coef = ws+off;        off += (size_t)768*196*24;
  float* basis= ws+off;        off += 4736;
  unsigned int* maskw=(unsigned int*)(ws+off); off += (size_t)768*197*8;
  unsigned short* WqkvT = (unsigned short*)(ws+off); off += (size_t)2304*768/2;
  unsigned short* WprojT= (unsigned short*)(ws+off); off += (size_t)768*768/2;
  unsigned short* W1T   = (unsigned short*)(ws+off); off += (size_t)3072*768/2;
  unsigned short* W2T   = (unsigned short*)(ws+off); off += (size_t)768*3072/2;
  unsigned short* attn_out = hbuf;                    // alias (hbuf dead after qkv GEMM)
  unsigned short* hidden = (unsigned short*)(ws+qkv_off); // alias (qkv dead after attn)
  float* x1 = out;

  // 0. weight transpose+bf16 conversions
  wtrans_kernel<<<dim3(72,24),256,0,stream>>>(Wqkv, WqkvT, 768, 2304);
  wtrans_kernel<<<dim3(24,24),256,0,stream>>>(Wproj, WprojT, 768, 768);
  wtrans_kernel<<<dim3(96,24),256,0,stream>>>(W1, W1T, 768, 3072);
  wtrans_kernel<<<dim3(24,96),256,0,stream>>>(W2, W2T, 3072, 768);
  // 1. h = LN(x) -> bf16
  ln_kernel<<<12608,256,0,stream>>>(x,g1,b1,hbuf);
  // 2. qkv = h @ Wqkv (f32 out)
  gemm_bf16<0,0,0><<<dim3(18,99),256,0,stream>>>(hbuf,WqkvT,nullptr,nullptr,qkv,12608,768,2304);
  // 3. qp, kp
  qkproj_kernel<<<18912,256,0,stream>>>(qkv,Wcq,bcq,qp,0);
  qkproj_kernel<<<18912,256,0,stream>>>(qkv,Wck,bck,kp,1);
  // 4. kk
  kk_kernel<<<768,768,0,stream>>>(kp,proj_n,kkb);
  // 5. basis
  basis_kernel<<<19,256,0,stream>>>(proj_back_n,basis);
  // 6. cheap + softmax + top8
  coef_kernel<<<37632,256,0,stream>>>(qp,kkb,coef);
  // 7. approx_attn + budget mask
  mask_kernel<<<151296,256,0,stream>>>(coef,basis,maskw);
  // 8. masked attention (bf16 out, aliases hbuf)
  attn2_kernel<<<768,256,0,stream>>>(qkv,maskw,attn_out);
  // 9. x1 = x + attn_out @ Wproj + bproj   (x1 == d_out)
  gemm_bf16<0,1,0><<<dim3(6,99),256,0,stream>>>(attn_out,WprojT,bproj,x,x1,12608,768,768);
  // 10. h2 = LN(x1) -> bf16 (reuse hbuf)
  ln_kernel<<<12608,256,0,stream>>>(x1,g2,b2,hbuf);
  // 11. hidden = gelu(h2 @ W1 + bfc1) -> bf16 (aliases dead qkv)
  gemm_bf16<1,0,1><<<dim3(24,99),256,0,stream>>>(hbuf,W1T,bfc1,nullptr,hidden,12608,768,3072);
  // 12. out = x1 + hidden @ W2 + bfc2
  gemm_bf16<0,1,0><<<dim3(6,99),256,0,stream>>>(hidden,W2T,bfc2,x1,out,12608,3072,768);
}

// Round 4
// 1196.722 us; speedup vs baseline: 3.8319x; 2.0791x over previous
//
#include <hip/hip_runtime.h>
#include <math.h>
#include <float.h>

#define B_ 64
#define N_ 197
#define C_ 768
#define H_ 12
#define CH_ 64
#define RC_ 32
#define RN_ 24

typedef __attribute__((ext_vector_type(8))) short short8;
typedef __attribute__((ext_vector_type(4))) float f32x4;
typedef __attribute__((address_space(3))) void  lds_void;
typedef __attribute__((address_space(1))) const void g_void;

__device__ __forceinline__ float warp_sum(float v){
  #pragma unroll
  for(int o=32;o>=1;o>>=1) v += __shfl_xor(v,o);
  return v;
}
__device__ __forceinline__ float warp_max(float v){
  #pragma unroll
  for(int o=32;o>=1;o>>=1) v = fmaxf(v,__shfl_xor(v,o));
  return v;
}
__device__ __forceinline__ unsigned short f2bf(float f){
  union{float f; unsigned u;} c; c.f = f;
  unsigned r = c.u + 0x7FFF + ((c.u>>16)&1);
  return (unsigned short)(r>>16);
}
__device__ __forceinline__ float bf2f(unsigned short u){
  union{unsigned u; float f;} c; c.u = ((unsigned)u)<<16; return c.f;
}

// ---------------- LayerNorm: one block per row of 768, bf16 out ----------------
__global__ __launch_bounds__(256) void ln_kernel(const float* __restrict__ x,
    const float* __restrict__ g, const float* __restrict__ bb, unsigned short* __restrict__ out){
  int r = blockIdx.x; int tid = threadIdx.x;
  const float* xr = x + (size_t)r*C_;
  float v0=xr[tid], v1=xr[tid+256], v2=xr[tid+512];
  __shared__ float red[8];
  float s = warp_sum(v0+v1+v2);
  if((tid&63)==0) red[tid>>6]=s;
  __syncthreads();
  float mu = (red[0]+red[1]+red[2]+red[3]) * (1.f/768.f);
  float d0=v0-mu,d1=v1-mu,d2=v2-mu;
  float s2 = warp_sum(d0*d0+d1*d1+d2*d2);
  if((tid&63)==0) red[4+(tid>>6)]=s2;
  __syncthreads();
  float rinv = rsqrtf((red[4]+red[5]+red[6]+red[7])*(1.f/768.f)+1e-5f);
  unsigned short* orow = out + (size_t)r*C_;
  orow[tid]     = f2bf(d0*rinv*g[tid]    +bb[tid]);
  orow[tid+256] = f2bf(d1*rinv*g[tid+256]+bb[tid+256]);
  orow[tid+512] = f2bf(d2*rinv*g[tid+512]+bb[tid+512]);
}

// ---------------- transpose+convert: in f32 [K][N] -> out bf16 [N][K] ----------------
__global__ __launch_bounds__(256) void wtrans_kernel(const float* __restrict__ in,
    unsigned short* __restrict__ out, int K, int N){
  __shared__ float tile[32][33];
  int n0 = blockIdx.x*32, k0 = blockIdx.y*32;
  int tx = threadIdx.x&31, ty = threadIdx.x>>5;   // ty: 8 rows per pass
  #pragma unroll
  for(int i=0;i<4;++i) tile[ty+8*i][tx] = in[(size_t)(k0+ty+8*i)*N + n0+tx];
  __syncthreads();
  #pragma unroll
  for(int i=0;i<4;++i) out[(size_t)(n0+ty+8*i)*K + k0+tx] = f2bf(tile[tx][ty+8*i]);
}

// ---------------- bf16 MFMA GEMM: Cout = act(A@W + bias) + resid ----------------
// A [M][K] bf16, WT [Nc][K] bf16. 128x128 tile, BK=32, 256 thr, 4 waves each 64x64.
template<int ACT, int RESID, int OUTBF16>
__global__ __launch_bounds__(256) void gemm_bf16(
    const unsigned short* __restrict__ A, const unsigned short* __restrict__ WT,
    const float* __restrict__ bias, const float* __restrict__ resid,
    void* __restrict__ Cout, int M, int K, int Nc){
  __shared__ unsigned short As[128*32];
  __shared__ unsigned short Bs[128*32];
  int tid = threadIdx.x, lane = tid&63, wid = tid>>6;
  int m0 = blockIdx.y*128, n0 = blockIdx.x*128;
  int wr = wid>>1, wc = wid&1;
  int lm = lane&15, lg = lane>>4;
  f32x4 acc[4][4] = {};
  for(int kt=0; kt<K; kt+=32){
    #pragma unroll
    for(int it=0; it<2; ++it){
      int ci = it*256 + tid;
      int row = ci>>2, kc=(ci&3)*8;
      int ar = m0+row; if(ar > M-1) ar = M-1;
      const unsigned short* ga = A  + (size_t)ar*K        + kt + kc;
      const unsigned short* gb = WT + (size_t)(n0+row)*K  + kt + kc;
      __builtin_amdgcn_global_load_lds((g_void*)ga, (lds_void*)(As + (it*256 + wid*64)*8), 16, 0, 0);
      __builtin_amdgcn_global_load_lds((g_void*)gb, (lds_void*)(Bs + (it*256 + wid*64)*8), 16, 0, 0);
    }
    __syncthreads();
    short8 af[4], bfv[4];
    #pragma unroll
    for(int i=0;i<4;++i){
      af[i]  = *(const short8*)(As + (64*wr + 16*i + lm)*32 + lg*8);
      bfv[i] = *(const short8*)(Bs + (64*wc + 16*i + lm)*32 + lg*8);
    }
    #pragma unroll
    for(int i=0;i<4;++i)
      #pragma unroll
      for(int j=0;j<4;++j)
        acc[i][j] = __builtin_amdgcn_mfma_f32_16x16x32_bf16(af[i], bfv[j], acc[i][j], 0,0,0);
    __syncthreads();
  }
  // epilogue: D row = (lane>>4)*4 + r, col = lane&15  (within each 16x16 frag)
  #pragma unroll
  for(int i=0;i<4;++i){
    #pragma unroll
    for(int j=0;j<4;++j){
      int gcol = n0 + 64*wc + 16*j + lm;
      float bv = bias ? bias[gcol] : 0.f;
      #pragma unroll
      for(int r=0;r<4;++r){
        int grow = m0 + 64*wr + 16*i + lg*4 + r;
        if(grow < M){
          float cv = acc[i][j][r] + bv;
          if(ACT==1) cv = 0.5f*cv*(1.0f+erff(cv*0.70710678118654752f));
          if(RESID) cv += resid[(size_t)grow*Nc + gcol];
          if(OUTBF16) ((unsigned short*)Cout)[(size_t)grow*Nc+gcol] = f2bf(cv);
          else        ((float*)Cout)[(size_t)grow*Nc+gcol] = cv;
        }
      }
    }
  }
}

// ---------------- qp/kp: per (b,h,n) row, 64x32 matvec ----------------
__global__ __launch_bounds__(256) void qkproj_kernel(const float* __restrict__ qkv,
    const float* __restrict__ Wc, const float* __restrict__ bc,
    float* __restrict__ outp, int sel){
  int r = blockIdx.x*8 + (threadIdx.x>>5);
  int col = threadIdx.x&31;
  int b = r/(H_*N_); int rem = r%(H_*N_); int h = rem/N_; int n = rem%N_;
  const float* src = qkv + ((size_t)(b*N_+n)*3 + sel)*C_ + h*CH_;
  float acc = bc[col];
  #pragma unroll
  for(int ch=0;ch<CH_;++ch) acc += src[ch]*Wc[ch*RC_+col];
  outp[(size_t)r*RC_+col]=acc;
}

// ---------------- kk[b,h,c,r] = sum_n kp[b,h,n,c]*proj_n[n,r] ----------------
__global__ __launch_bounds__(768) void kk_kernel(const float* __restrict__ kp,
    const float* __restrict__ proj_n, float* __restrict__ kkb){
  int bh = blockIdx.x;
  int t = threadIdx.x;            // 768 = 32*24
  int c = t/RN_, rr = t%RN_;
  const float* kpb = kp + (size_t)bh*N_*RC_;
  float acc = 0.f;
  for(int n=0;n<N_;++n) acc += kpb[n*RC_+c]*proj_n[n*RN_+rr];
  kkb[(size_t)bh*RC_*RN_ + c*RN_ + rr] = acc;
}

// ---------------- cheap + softmax + keep-top8: one wave per (b,h,n>=1) ----------------
__global__ __launch_bounds__(256) void coef_kernel(const float* __restrict__ qp,
    const float* __restrict__ kkb, float* __restrict__ coef){
  int wid = blockIdx.x*4 + (threadIdx.x>>6);   // (b*H+h)*196 + (n-1)
  int lane = threadIdx.x&63;
  int b = wid/(H_*196); int rem = wid%(H_*196); int h = rem/196; int n = rem%196+1;
  int bh = b*H_+h;
  const float* qpr = qp + ((size_t)bh*N_ + n)*RC_;
  const float* kkp = kkb + (size_t)bh*RC_*RN_;
  float val = -INFINITY;
  if(lane<RN_){
    float acc=0.f;
    #pragma unroll
    for(int c=0;c<RC_;++c) acc += qpr[c]*kkp[c*RN_+lane];
    val = acc * 0.28867513459481287f;   // H^-0.5
  }
  float m = warp_max(val);
  float e = (lane<RN_)? expf(val-m):0.f;
  float ssum = warp_sum(e);
  float p = e/ssum;
  float myv = (lane<RN_)? p : -1.f;
  int cnt=0;
  #pragma unroll
  for(int j=0;j<RN_;++j){ float vj = __shfl(myv, j); cnt += (vj>myv)?1:0; }
  if(lane<RN_) coef[(size_t)wid*RN_+lane] = (cnt<=7)? p : 0.f;
}

// ---------------- basis[r][j] = thresh(|proj_back_n[j][r]|) ----------------
__global__ __launch_bounds__(256) void basis_kernel(const float* __restrict__ pb,
    float* __restrict__ basis){
  int t = blockIdx.x*256 + threadIdx.x;
  if(t < RN_*N_){
    int r = t/N_, j = t%N_;
    float v = fabsf(pb[(size_t)j*RN_ + r]);
    basis[t] = (v > 0.02f) ? v : 0.f;
  }
}

// ---------------- approx_attn + budget top-50 mask (bitwords, 8 u32/row) ----------------
__global__ __launch_bounds__(256) void mask_kernel(const float* __restrict__ coef,
    const float* __restrict__ basis, unsigned int* __restrict__ maskw){
  int row = blockIdx.x;           // (b*H+h)*197 + qi
  int qi = row % N_; int bh = row / N_;
  int tid = threadIdx.x;
  if(qi==0){
    if(tid<8){
      unsigned v = (tid<6)?0xFFFFFFFFu:((tid==6)?0x1Fu:0u);
      maskw[(size_t)row*8+tid]=v;
    }
    return;
  }
  __shared__ float cf[RN_];
  __shared__ float a[N_];
  if(tid<RN_) cf[tid] = coef[((size_t)bh*196 + (qi-1))*RN_ + tid];
  __syncthreads();
  float mv = 0.f;
  if(tid<N_){
    float acc=0.f;
    #pragma unroll
    for(int r=0;r<RN_;++r) acc += cf[r]*basis[r*N_+tid];
    a[tid]=acc; mv=acc;
  }
  __syncthreads();
  bool keep=false;
  if(tid<N_){
    int cnt=0;
    for(int i=0;i<N_;++i) cnt += (a[i] > mv)?1:0;
    keep = (cnt <= 49);           // BUDGET=50 -> rank<=49 <=> a >= 50th largest
  }
  unsigned long long bal = __ballot(keep);
  if((tid&63)==0){
    int w = tid>>6;
    maskw[(size_t)row*8 + 2*w]   = (unsigned)(bal & 0xFFFFFFFFull);
    maskw[(size_t)row*8 + 2*w+1] = (unsigned)(bal>>32);
  }
}

// ---------------- masked attention v3: MFMA flash-style, one block per (b,h) ----------------
// K in LDS [208][64] bf16, rows 128B, XOR-swizzled (byte ^= (k&7)<<4).
// V in LDS transposed [64][220] bf16 (rows 440B: 2-way-free frag reads).
// P round-trip through LDS [16][224] per wave (448B rows, XOR-swizzled).
__global__ __launch_bounds__(512) void attn3_kernel(const float* __restrict__ qkv,
    const unsigned int* __restrict__ maskw, unsigned short* __restrict__ attn_out){
  int bh = blockIdx.x; int b = bh/H_, h = bh%H_;
  int tid = threadIdx.x, lane = tid&63, wv = tid>>6;
  int g = lane>>4, c16 = lane&15;
  __shared__ unsigned short Kb[208*64];     // 26.6 KB
  __shared__ unsigned short Vt[64*220];     // 28.2 KB
  __shared__ unsigned short Pl[8*16*224];   // 57.3 KB
  __shared__ unsigned int   Ml[8][16][8];   // 4 KB
  const float* Kbase = qkv + ((size_t)(b*N_)*3 + 1)*C_ + h*CH_;
  const float* Vbase = qkv + ((size_t)(b*N_)*3 + 2)*C_ + h*CH_;
  // stage K rows 0..207 (zero-pad >=197), u32-packed writes, swizzled
  for(int idx = tid; idx < 208*32; idx += 512){
    int k = idx>>5, cp = idx&31;
    unsigned pk = 0;
    if(k < N_){
      float2 kv = *(const float2*)(Kbase + (size_t)k*3*C_ + cp*2);
      pk = (unsigned)f2bf(kv.x) | ((unsigned)f2bf(kv.y)<<16);
    }
    unsigned off = (unsigned)(k*128 + cp*4) ^ ((unsigned)(k&7)<<4);
    *(unsigned*)((char*)Kb + off) = pk;
  }
  // stage V transposed, zero-pad k>=197 (prevents NaN*0 in PV)
  for(int idx = tid; idx < 64*110; idx += 512){
    int kp = idx>>6, c = idx&63;
    int k0 = kp*2, k1 = kp*2+1;
    float v0 = (k0<N_) ? Vbase[(size_t)k0*3*C_ + c] : 0.f;
    float v1 = (k1<N_) ? Vbase[(size_t)k1*3*C_ + c] : 0.f;
    *(unsigned*)((char*)Vt + c*440 + kp*4) = (unsigned)f2bf(v0) | ((unsigned)f2bf(v1)<<16);
  }
  __syncthreads();
  size_t pbase = (size_t)wv*16*448;
  // zero P tail (k=208..223) once per wave
  for(int i=lane;i<128;i+=64){
    int ql = i>>3; int kk = 208 + (i&7)*2;
    unsigned off = (unsigned)(ql*448 + kk*2) ^ ((unsigned)(ql&7)<<4);
    *(unsigned*)((char*)Pl + pbase + off) = 0u;
  }
  for(int t = wv; t < 13; t += 8){
    int qb = t*16;
    // mask tile -> LDS (per-wave region, no block sync needed)
    for(int i = lane; i < 128; i += 64){
      int row = i>>3, word = i&7;
      int qr = qb+row; if(qr>196) qr=196;
      Ml[wv][row][word] = maskw[(size_t)(bh*N_+qr)*8 + word];
    }
    // Q A-frags straight from global (L2-hot), ATTN_SCALE folded in
    int qrow = qb + c16; if(qrow>196) qrow=196;
    const float* Qr = qkv + ((size_t)(b*N_+qrow)*3)*C_ + h*CH_ + g*8;
    short8 af[2];
    #pragma unroll
    for(int s=0;s<2;++s)
      #pragma unroll
      for(int j=0;j<8;++j) af[s][j] = (short)f2bf(Qr[s*32+j]*0.125f);
    // S = Q @ K^T : 13 frags x 2 k-steps
    f32x4 sf[13];
    #pragma unroll
    for(int f=0;f<13;++f){
      sf[f] = (f32x4){0.f,0.f,0.f,0.f};
      #pragma unroll
      for(int s=0;s<2;++s){
        int row = f*16 + c16;
        unsigned off = (unsigned)(row*128 + s*64 + g*16) ^ ((unsigned)(row&7)<<4);
        short8 bfr = *(const short8*)((char*)Kb + off);
        sf[f] = __builtin_amdgcn_mfma_f32_16x16x32_bf16(af[s], bfr, sf[f], 0,0,0);
      }
    }
    // masked softmax (row = q = g*4+r across 16-lane groups; col k = lane&15)
    unsigned keep[4] = {0,0,0,0};
    float m[4] = {-FLT_MAX,-FLT_MAX,-FLT_MAX,-FLT_MAX};
    #pragma unroll
    for(int f=0;f<13;++f)
      #pragma unroll
      for(int r=0;r<4;++r){
        unsigned bit = (Ml[wv][g*4+r][f>>1] >> ((f&1)*16 + c16)) & 1u;
        keep[r] |= bit<<f;
        if(bit) m[r] = fmaxf(m[r], sf[f][r]);
      }
    #pragma unroll
    for(int r=0;r<4;++r){
      #pragma unroll
      for(int o=8;o>=1;o>>=1) m[r] = fmaxf(m[r], __shfl_xor(m[r], o));
    }
    float sum[4] = {0,0,0,0};
    #pragma unroll
    for(int f=0;f<13;++f)
      #pragma unroll
      for(int r=0;r<4;++r){
        float e = ((keep[r]>>f)&1u) ? expf(sf[f][r]-m[r]) : 0.f;
        sf[f][r] = e; sum[r] += e;
      }
    #pragma unroll
    for(int r=0;r<4;++r){
      #pragma unroll
      for(int o=8;o>=1;o>>=1) sum[r] += __shfl_xor(sum[r], o);
      sum[r] = 1.f/sum[r];
    }
    // P -> LDS (A-fragment layout source), swizzled
    #pragma unroll
    for(int f=0;f<13;++f)
      #pragma unroll
      for(int r=0;r<4;++r){
        int ql = g*4+r;
        unsigned off = (unsigned)(ql*448 + (f*16+c16)*2) ^ ((unsigned)(ql&7)<<4);
        *(unsigned short*)((char*)Pl + pbase + off) = f2bf(sf[f][r]*sum[r]);
      }
    // O = P @ V : 4 col-tiles x 7 k-steps
    #pragma unroll
    for(int ct=0;ct<4;++ct){
      f32x4 oa = (f32x4){0.f,0.f,0.f,0.f};
      #pragma unroll
      for(int ks=0;ks<7;++ks){
        unsigned offa = (unsigned)(c16*448 + (ks*32+g*8)*2) ^ ((unsigned)(c16&7)<<4);
        short8 pa = *(const short8*)((char*)Pl + pbase + offa);
        short8 vb = *(const short8*)((char*)Vt + (size_t)(ct*16+c16)*440 + (ks*32+g*8)*2);
        oa = __builtin_amdgcn_mfma_f32_16x16x32_bf16(pa, vb, oa, 0,0,0);
      }
      #pragma unroll
      for(int r=0;r<4;++r){
        int qq = qb + g*4 + r;
        if(qq < N_)
          attn_out[((size_t)(b*N_+qq))*C_ + h*CH_ + ct*16 + c16] = f2bf(oa[r]);
      }
    }
  }
}

extern "C" void kernel_launch(void* const* d_in, const int* in_sizes, int n_in,
                              void* d_out, int out_size, void* d_ws, size_t ws_size,
                              hipStream_t stream){
  const float* x    =(const float*)d_in[0];
  const float* Wqkv =(const float*)d_in[1];
  const float* Wcq  =(const float*)d_in[2];
  const float* bcq  =(const float*)d_in[3];
  const float* Wck  =(const float*)d_in[4];
  const float* bck  =(const float*)d_in[5];
  const float* proj_n=(const float*)d_in[6];
  const float* proj_back_n=(const float*)d_in[7];
  const float* Wproj=(const float*)d_in[8];
  const float* bproj=(const float*)d_in[9];
  const float* g1=(const float*)d_in[10];
  const float* b1=(const float*)d_in[11];
  const float* g2=(const float*)d_in[12];
  const float* b2=(const float*)d_in[13];
  const float* W1=(const float*)d_in[14];
  const float* bfc1=(const float*)d_in[15];
  const float* W2=(const float*)d_in[16];
  const float* bfc2=(const float*)d_in[17];
  float* out=(float*)d_out;

  // ---- workspace layout (float slots). ~210 MB ----
  float* ws=(float*)d_ws;
  size_t off=0;
  unsigned short* hbuf = (unsigned short*)(ws+off); off += (size_t)12608*768/2;  // bf16, aliased as attn_out
  size_t qkv_off = off;
  float* qkv  = ws+off;        off += (size_t)12608*2304;
  float* qp   = ws+off;        off += (size_t)768*197*32;
  float* kp   = ws+off;        off += (size_t)768*197*32;
  float* kkb  = ws+off;        off += (size_t)768*32*24;
  float* coef = ws+off;        off += (size_t)768*196*24;
  float* basis= ws+off;        off += 4736;
  unsigned int* maskw=(unsigned int*)(ws+off); off += (size_t)768*197*8;
  unsigned short* WqkvT = (unsigned short*)(ws+off); off += (size_t)2304*768/2;
  unsigned short* WprojT= (unsigned short*)(ws+off); off += (size_t)768*768/2;
  unsigned short* W1T   = (unsigned short*)(ws+off); off += (size_t)3072*768/2;
  unsigned short* W2T   = (unsigned short*)(ws+off); off += (size_t)768*3072/2;
  unsigned short* attn_out = hbuf;                    // alias (hbuf dead after qkv GEMM)
  unsigned short* hidden = (unsigned short*)(ws+qkv_off); // alias (qkv dead after attn)
  float* x1 = out;

  // 0. weight transpose+bf16 conversions
  wtrans_kernel<<<dim3(72,24),256,0,stream>>>(Wqkv, WqkvT, 768, 2304);
  wtrans_kernel<<<dim3(24,24),256,0,stream>>>(Wproj, WprojT, 768, 768);
  wtrans_kernel<<<dim3(96,24),256,0,stream>>>(W1, W1T, 768, 3072);
  wtrans_kernel<<<dim3(24,96),256,0,stream>>>(W2, W2T, 3072, 768);
  // 1. h = LN(x) -> bf16
  ln_kernel<<<12608,256,0,stream>>>(x,g1,b1,hbuf);
  // 2. qkv = h @ Wqkv (f32 out)
  gemm_bf16<0,0,0><<<dim3(18,99),256,0,stream>>>(hbuf,WqkvT,nullptr,nullptr,qkv,12608,768,2304);
  // 3. qp, kp
  qkproj_kernel<<<18912,256,0,stream>>>(qkv,Wcq,bcq,qp,0);
  qkproj_kernel<<<18912,256,0,stream>>>(qkv,Wck,bck,kp,1);
  // 4. kk
  kk_kernel<<<768,768,0,stream>>>(kp,proj_n,kkb);
  // 5. basis
  basis_kernel<<<19,256,0,stream>>>(proj_back_n,basis);
  // 6. cheap + softmax + top8
  coef_kernel<<<37632,256,0,stream>>>(qp,kkb,coef);
  // 7. approx_attn + budget mask
  mask_kernel<<<151296,256,0,stream>>>(coef,basis,maskw);
  // 8. masked attention (MFMA, bf16 out, aliases hbuf)
  attn3_kernel<<<768,512,0,stream>>>(qkv,maskw,attn_out);
  // 9. x1 = x + attn_out @ Wproj + bproj   (x1 == d_out)
  gemm_bf16<0,1,0><<<dim3(6,99),256,0,stream>>>(attn_out,WprojT,bproj,x,x1,12608,768,768);
  // 10. h2 = LN(x1) -> bf16 (reuse hbuf)
  ln_kernel<<<12608,256,0,stream>>>(x1,g2,b2,hbuf);
  // 11. hidden = gelu(h2 @ W1 + bfc1) -> bf16 (aliases dead qkv)
  gemm_bf16<1,0,1><<<dim3(24,99),256,0,stream>>>(hbuf,W1T,bfc1,nullptr,hidden,12608,768,3072);
  // 12. out = x1 + hidden @ W2 + bfc2
  gemm_bf16<0,1,0><<<dim3(6,99),256,0,stream>>>(hidden,W2T,bfc2,x1,out,12608,3072,768);
}

// Round 5
// 1048.324 us; speedup vs baseline: 4.3743x; 1.1416x over previous
//
#include <hip/hip_runtime.h>
#include <math.h>
#include <float.h>

#define B_ 64
#define N_ 197
#define C_ 768
#define H_ 12
#define CH_ 64
#define RC_ 32
#define RN_ 24

typedef __attribute__((ext_vector_type(8))) short short8;
typedef __attribute__((ext_vector_type(4))) float f32x4;
typedef __attribute__((address_space(3))) void  lds_void;
typedef __attribute__((address_space(1))) const void g_void;

__device__ __forceinline__ float warp_sum(float v){
  #pragma unroll
  for(int o=32;o>=1;o>>=1) v += __shfl_xor(v,o);
  return v;
}
__device__ __forceinline__ float warp_max(float v){
  #pragma unroll
  for(int o=32;o>=1;o>>=1) v = fmaxf(v,__shfl_xor(v,o));
  return v;
}
__device__ __forceinline__ unsigned short f2bf(float f){
  union{float f; unsigned u;} c; c.f = f;
  unsigned r = c.u + 0x7FFF + ((c.u>>16)&1);
  return (unsigned short)(r>>16);
}
__device__ __forceinline__ float bf2f(unsigned short u){
  union{unsigned u; float f;} c; c.u = ((unsigned)u)<<16; return c.f;
}

// ---------------- LayerNorm: one block per row of 768, bf16 out ----------------
__global__ __launch_bounds__(256) void ln_kernel(const float* __restrict__ x,
    const float* __restrict__ g, const float* __restrict__ bb, unsigned short* __restrict__ out){
  int r = blockIdx.x; int tid = threadIdx.x;
  const float* xr = x + (size_t)r*C_;
  float v0=xr[tid], v1=xr[tid+256], v2=xr[tid+512];
  __shared__ float red[8];
  float s = warp_sum(v0+v1+v2);
  if((tid&63)==0) red[tid>>6]=s;
  __syncthreads();
  float mu = (red[0]+red[1]+red[2]+red[3]) * (1.f/768.f);
  float d0=v0-mu,d1=v1-mu,d2=v2-mu;
  float s2 = warp_sum(d0*d0+d1*d1+d2*d2);
  if((tid&63)==0) red[4+(tid>>6)]=s2;
  __syncthreads();
  float rinv = rsqrtf((red[4]+red[5]+red[6]+red[7])*(1.f/768.f)+1e-5f);
  unsigned short* orow = out + (size_t)r*C_;
  orow[tid]     = f2bf(d0*rinv*g[tid]    +bb[tid]);
  orow[tid+256] = f2bf(d1*rinv*g[tid+256]+bb[tid+256]);
  orow[tid+512] = f2bf(d2*rinv*g[tid+512]+bb[tid+512]);
}

// ---------------- transpose+convert: in f32 [K][N] -> out bf16 [N][K] ----------------
__global__ __launch_bounds__(256) void wtrans_kernel(const float* __restrict__ in,
    unsigned short* __restrict__ out, int K, int N){
  __shared__ float tile[32][33];
  int n0 = blockIdx.x*32, k0 = blockIdx.y*32;
  int tx = threadIdx.x&31, ty = threadIdx.x>>5;   // ty: 8 rows per pass
  #pragma unroll
  for(int i=0;i<4;++i) tile[ty+8*i][tx] = in[(size_t)(k0+ty+8*i)*N + n0+tx];
  __syncthreads();
  #pragma unroll
  for(int i=0;i<4;++i) out[(size_t)(n0+ty+8*i)*K + k0+tx] = f2bf(tile[tx][ty+8*i]);
}

// ---------------- bf16 MFMA GEMM: Cout = act(A@W + bias) + resid ----------------
// A [M][K] bf16, WT [Nc][K] bf16. 128x128 tile, BK=32, 256 thr, 4 waves each 64x64.
template<int ACT, int RESID, int OUTBF16>
__global__ __launch_bounds__(256) void gemm_bf16(
    const unsigned short* __restrict__ A, const unsigned short* __restrict__ WT,
    const float* __restrict__ bias, const float* __restrict__ resid,
    void* __restrict__ Cout, int M, int K, int Nc){
  __shared__ unsigned short As[128*32];
  __shared__ unsigned short Bs[128*32];
  int tid = threadIdx.x, lane = tid&63, wid = tid>>6;
  int m0 = blockIdx.y*128, n0 = blockIdx.x*128;
  int wr = wid>>1, wc = wid&1;
  int lm = lane&15, lg = lane>>4;
  f32x4 acc[4][4] = {};
  for(int kt=0; kt<K; kt+=32){
    #pragma unroll
    for(int it=0; it<2; ++it){
      int ci = it*256 + tid;
      int row = ci>>2, kc=(ci&3)*8;
      int ar = m0+row; if(ar > M-1) ar = M-1;
      const unsigned short* ga = A  + (size_t)ar*K        + kt + kc;
      const unsigned short* gb = WT + (size_t)(n0+row)*K  + kt + kc;
      __builtin_amdgcn_global_load_lds((g_void*)ga, (lds_void*)(As + (it*256 + wid*64)*8), 16, 0, 0);
      __builtin_amdgcn_global_load_lds((g_void*)gb, (lds_void*)(Bs + (it*256 + wid*64)*8), 16, 0, 0);
    }
    __syncthreads();
    short8 af[4], bfv[4];
    #pragma unroll
    for(int i=0;i<4;++i){
      af[i]  = *(const short8*)(As + (64*wr + 16*i + lm)*32 + lg*8);
      bfv[i] = *(const short8*)(Bs + (64*wc + 16*i + lm)*32 + lg*8);
    }
    #pragma unroll
    for(int i=0;i<4;++i)
      #pragma unroll
      for(int j=0;j<4;++j)
        acc[i][j] = __builtin_amdgcn_mfma_f32_16x16x32_bf16(af[i], bfv[j], acc[i][j], 0,0,0);
    __syncthreads();
  }
  // epilogue: D row = (lane>>4)*4 + r, col = lane&15  (within each 16x16 frag)
  #pragma unroll
  for(int i=0;i<4;++i){
    #pragma unroll
    for(int j=0;j<4;++j){
      int gcol = n0 + 64*wc + 16*j + lm;
      float bv = bias ? bias[gcol] : 0.f;
      #pragma unroll
      for(int r=0;r<4;++r){
        int grow = m0 + 64*wr + 16*i + lg*4 + r;
        if(grow < M){
          float cv = acc[i][j][r] + bv;
          if(ACT==1) cv = 0.5f*cv*(1.0f+erff(cv*0.70710678118654752f));
          if(RESID) cv += resid[(size_t)grow*Nc + gcol];
          if(OUTBF16) ((unsigned short*)Cout)[(size_t)grow*Nc+gcol] = f2bf(cv);
          else        ((float*)Cout)[(size_t)grow*Nc+gcol] = cv;
        }
      }
    }
  }
}

// ---------------- qp/kp: per (b,h,n) row, 64x32 matvec ----------------
__global__ __launch_bounds__(256) void qkproj_kernel(const float* __restrict__ qkv,
    const float* __restrict__ Wc, const float* __restrict__ bc,
    float* __restrict__ outp, int sel){
  int r = blockIdx.x*8 + (threadIdx.x>>5);
  int col = threadIdx.x&31;
  int b = r/(H_*N_); int rem = r%(H_*N_); int h = rem/N_; int n = rem%N_;
  const float* src = qkv + ((size_t)(b*N_+n)*3 + sel)*C_ + h*CH_;
  float acc = bc[col];
  #pragma unroll
  for(int ch=0;ch<CH_;++ch) acc += src[ch]*Wc[ch*RC_+col];
  outp[(size_t)r*RC_+col]=acc;
}

// ---------------- kk[b,h,c,r] = sum_n kp[b,h,n,c]*proj_n[n,r] ----------------
__global__ __launch_bounds__(768) void kk_kernel(const float* __restrict__ kp,
    const float* __restrict__ proj_n, float* __restrict__ kkb){
  int bh = blockIdx.x;
  int t = threadIdx.x;            // 768 = 32*24
  int c = t/RN_, rr = t%RN_;
  const float* kpb = kp + (size_t)bh*N_*RC_;
  float acc = 0.f;
  for(int n=0;n<N_;++n) acc += kpb[n*RC_+c]*proj_n[n*RN_+rr];
  kkb[(size_t)bh*RC_*RN_ + c*RN_ + rr] = acc;
}

// ---------------- cheap + softmax + keep-top8: one wave per (b,h,n>=1) ----------------
__global__ __launch_bounds__(256) void coef_kernel(const float* __restrict__ qp,
    const float* __restrict__ kkb, float* __restrict__ coef){
  int wid = blockIdx.x*4 + (threadIdx.x>>6);   // (b*H+h)*196 + (n-1)
  int lane = threadIdx.x&63;
  int b = wid/(H_*196); int rem = wid%(H_*196); int h = rem/196; int n = rem%196+1;
  int bh = b*H_+h;
  const float* qpr = qp + ((size_t)bh*N_ + n)*RC_;
  const float* kkp = kkb + (size_t)bh*RC_*RN_;
  float val = -INFINITY;
  if(lane<RN_){
    float acc=0.f;
    #pragma unroll
    for(int c=0;c<RC_;++c) acc += qpr[c]*kkp[c*RN_+lane];
    val = acc * 0.28867513459481287f;   // H^-0.5
  }
  float m = warp_max(val);
  float e = (lane<RN_)? expf(val-m):0.f;
  float ssum = warp_sum(e);
  float p = e/ssum;
  float myv = (lane<RN_)? p : -1.f;
  int cnt=0;
  #pragma unroll
  for(int j=0;j<RN_;++j){ float vj = __shfl(myv, j); cnt += (vj>myv)?1:0; }
  if(lane<RN_) coef[(size_t)wid*RN_+lane] = (cnt<=7)? p : 0.f;
}

// ---------------- basis[r][j] = thresh(|proj_back_n[j][r]|) ----------------
__global__ __launch_bounds__(256) void basis_kernel(const float* __restrict__ pb,
    float* __restrict__ basis){
  int t = blockIdx.x*256 + threadIdx.x;
  if(t < RN_*N_){
    int r = t/N_, j = t%N_;
    float v = fabsf(pb[(size_t)j*RN_ + r]);
    basis[t] = (v > 0.02f) ? v : 0.f;
  }
}

// ---------------- mask v2: one WAVE per row; wave bitonic-sort-256 top-50 select ----------------
// elem = reg*64 + lane (reg-major) so per-reg __ballot == maskw words directly.
__global__ __launch_bounds__(256) void mask2_kernel(const float* __restrict__ coef,
    const float* __restrict__ basis, unsigned int* __restrict__ maskw){
  __shared__ float Bs[24*256];
  __shared__ float cfs[4][24];
  int tid = threadIdx.x, lane = tid&63, wv = tid>>6;
  // stage thresholded basis, zero-padded to 256 cols
  for(int idx = tid; idx < 24*256; idx += 256){
    int r = idx>>8, e = idx&255;
    Bs[idx] = (e < N_) ? basis[r*N_ + e] : 0.f;
  }
  __syncthreads();
  int row = blockIdx.x*4 + wv;          // (b*H+h)*197 + qi
  int qi = row % N_; int bh = row / N_;
  if(qi==0){
    if(lane<8){
      unsigned v = (lane<6)?0xFFFFFFFFu:((lane==6)?0x1Fu:0u);
      maskw[(size_t)row*8+lane]=v;
    }
    return;
  }
  if(lane<24) cfs[wv][lane] = coef[((size_t)bh*196 + (qi-1))*24 + lane];
  // dot: a[elem] = sum_r cf[r]*basis[r][elem], skipping zero coefs (wave-uniform)
  float av[4] = {0.f,0.f,0.f,0.f};
  for(int r=0;r<24;++r){
    float c = cfs[wv][r];
    if(c != 0.f){
      #pragma unroll
      for(int g2=0; g2<4; ++g2) av[g2] += c * Bs[r*256 + g2*64 + lane];
    }
  }
  // sort copies, pads (elem>=197) = -1 so they sink below all real values (>=0)
  float s[4];
  s[0]=av[0]; s[1]=av[1]; s[2]=av[2];
  s[3] = (lane<5) ? av[3] : -1.f;
  // bitonic sort ascending over idx = reg*64+lane
  #pragma unroll
  for(int k=2;k<=256;k<<=1){
    #pragma unroll
    for(int j=k>>1;j>0;j>>=1){
      if(j<64){
        #pragma unroll
        for(int r=0;r<4;++r){
          float partner = __shfl_xor(s[r], j);
          bool lower = ((lane & j)==0);
          bool asc = (((r*64+lane) & k)==0);
          bool take_min = (lower == asc);
          float mn = fminf(s[r], partner), mx = fmaxf(s[r], partner);
          s[r] = take_min ? mn : mx;
        }
      } else {
        int jr = j>>6;
        #pragma unroll
        for(int r=0;r<4;++r){
          if((r & jr)==0){
            int p = r + jr;
            bool asc = (((r*64) & k)==0);   // k>=128 here: reg-determined, lane-independent
            float a0=s[r], a1=s[p];
            float mn=fminf(a0,a1), mx=fmaxf(a0,a1);
            s[r] = asc? mn : mx;
            s[p] = asc? mx : mn;
          }
        }
      }
    }
  }
  // 50th largest = sorted idx 206 = reg 3, lane 14
  float t = __shfl(s[3], 14);
  #pragma unroll
  for(int r=0;r<4;++r){
    bool valid = (r<3) | (lane<5);
    bool keep = valid && (av[r] >= t);
    unsigned long long bal = __ballot(keep);
    if(lane==0){
      maskw[(size_t)row*8 + 2*r]   = (unsigned)(bal & 0xFFFFFFFFull);
      maskw[(size_t)row*8 + 2*r+1] = (unsigned)(bal>>32);
    }
  }
}

// ---------------- masked attention v3: MFMA flash-style, one block per (b,h) ----------------
// K in LDS [208][64] bf16, rows 128B, XOR-swizzled (byte ^= (k&7)<<4).
// V in LDS transposed [64][220] bf16 (rows 440B: 2-way-free frag reads).
// P round-trip through LDS [16][224] per wave (448B rows, XOR-swizzled).
__global__ __launch_bounds__(512) void attn3_kernel(const float* __restrict__ qkv,
    const unsigned int* __restrict__ maskw, unsigned short* __restrict__ attn_out){
  int bh = blockIdx.x; int b = bh/H_, h = bh%H_;
  int tid = threadIdx.x, lane = tid&63, wv = tid>>6;
  int g = lane>>4, c16 = lane&15;
  __shared__ unsigned short Kb[208*64];     // 26.6 KB
  __shared__ unsigned short Vt[64*220];     // 28.2 KB
  __shared__ unsigned short Pl[8*16*224];   // 57.3 KB
  __shared__ unsigned int   Ml[8][16][8];   // 4 KB
  const float* Kbase = qkv + ((size_t)(b*N_)*3 + 1)*C_ + h*CH_;
  const float* Vbase = qkv + ((size_t)(b*N_)*3 + 2)*C_ + h*CH_;
  // stage K rows 0..207 (zero-pad >=197), u32-packed writes, swizzled
  for(int idx = tid; idx < 208*32; idx += 512){
    int k = idx>>5, cp = idx&31;
    unsigned pk = 0;
    if(k < N_){
      float2 kv = *(const float2*)(Kbase + (size_t)k*3*C_ + cp*2);
      pk = (unsigned)f2bf(kv.x) | ((unsigned)f2bf(kv.y)<<16);
    }
    unsigned off = (unsigned)(k*128 + cp*4) ^ ((unsigned)(k&7)<<4);
    *(unsigned*)((char*)Kb + off) = pk;
  }
  // stage V transposed, zero-pad k>=197 (prevents NaN*0 in PV)
  for(int idx = tid; idx < 64*110; idx += 512){
    int kp = idx>>6, c = idx&63;
    int k0 = kp*2, k1 = kp*2+1;
    float v0 = (k0<N_) ? Vbase[(size_t)k0*3*C_ + c] : 0.f;
    float v1 = (k1<N_) ? Vbase[(size_t)k1*3*C_ + c] : 0.f;
    *(unsigned*)((char*)Vt + c*440 + kp*4) = (unsigned)f2bf(v0) | ((unsigned)f2bf(v1)<<16);
  }
  __syncthreads();
  size_t pbase = (size_t)wv*16*448;
  // zero P tail (k=208..223) once per wave
  for(int i=lane;i<128;i+=64){
    int ql = i>>3; int kk = 208 + (i&7)*2;
    unsigned off = (unsigned)(ql*448 + kk*2) ^ ((unsigned)(ql&7)<<4);
    *(unsigned*)((char*)Pl + pbase + off) = 0u;
  }
  for(int t = wv; t < 13; t += 8){
    int qb = t*16;
    // mask tile -> LDS (per-wave region, no block sync needed)
    for(int i = lane; i < 128; i += 64){
      int row = i>>3, word = i&7;
      int qr = qb+row; if(qr>196) qr=196;
      Ml[wv][row][word] = maskw[(size_t)(bh*N_+qr)*8 + word];
    }
    // Q A-frags straight from global (L2-hot), ATTN_SCALE folded in
    int qrow = qb + c16; if(qrow>196) qrow=196;
    const float* Qr = qkv + ((size_t)(b*N_+qrow)*3)*C_ + h*CH_ + g*8;
    short8 af[2];
    #pragma unroll
    for(int s=0;s<2;++s)
      #pragma unroll
      for(int j=0;j<8;++j) af[s][j] = (short)f2bf(Qr[s*32+j]*0.125f);
    // S = Q @ K^T : 13 frags x 2 k-steps
    f32x4 sf[13];
    #pragma unroll
    for(int f=0;f<13;++f){
      sf[f] = (f32x4){0.f,0.f,0.f,0.f};
      #pragma unroll
      for(int s=0;s<2;++s){
        int row = f*16 + c16;
        unsigned off = (unsigned)(row*128 + s*64 + g*16) ^ ((unsigned)(row&7)<<4);
        short8 bfr = *(const short8*)((char*)Kb + off);
        sf[f] = __builtin_amdgcn_mfma_f32_16x16x32_bf16(af[s], bfr, sf[f], 0,0,0);
      }
    }
    // masked softmax (row = q = g*4+r across 16-lane groups; col k = lane&15)
    unsigned keep[4] = {0,0,0,0};
    float m[4] = {-FLT_MAX,-FLT_MAX,-FLT_MAX,-FLT_MAX};
    #pragma unroll
    for(int f=0;f<13;++f)
      #pragma unroll
      for(int r=0;r<4;++r){
        unsigned bit = (Ml[wv][g*4+r][f>>1] >> ((f&1)*16 + c16)) & 1u;
        keep[r] |= bit<<f;
        if(bit) m[r] = fmaxf(m[r], sf[f][r]);
      }
    #pragma unroll
    for(int r=0;r<4;++r){
      #pragma unroll
      for(int o=8;o>=1;o>>=1) m[r] = fmaxf(m[r], __shfl_xor(m[r], o));
    }
    float sum[4] = {0,0,0,0};
    #pragma unroll
    for(int f=0;f<13;++f)
      #pragma unroll
      for(int r=0;r<4;++r){
        float e = ((keep[r]>>f)&1u) ? expf(sf[f][r]-m[r]) : 0.f;
        sf[f][r] = e; sum[r] += e;
      }
    #pragma unroll
    for(int r=0;r<4;++r){
      #pragma unroll
      for(int o=8;o>=1;o>>=1) sum[r] += __shfl_xor(sum[r], o);
      sum[r] = 1.f/sum[r];
    }
    // P -> LDS (A-fragment layout source), swizzled
    #pragma unroll
    for(int f=0;f<13;++f)
      #pragma unroll
      for(int r=0;r<4;++r){
        int ql = g*4+r;
        unsigned off = (unsigned)(ql*448 + (f*16+c16)*2) ^ ((unsigned)(ql&7)<<4);
        *(unsigned short*)((char*)Pl + pbase + off) = f2bf(sf[f][r]*sum[r]);
      }
    // O = P @ V : 4 col-tiles x 7 k-steps
    #pragma unroll
    for(int ct=0;ct<4;++ct){
      f32x4 oa = (f32x4){0.f,0.f,0.f,0.f};
      #pragma unroll
      for(int ks=0;ks<7;++ks){
        unsigned offa = (unsigned)(c16*448 + (ks*32+g*8)*2) ^ ((unsigned)(c16&7)<<4);
        short8 pa = *(const short8*)((char*)Pl + pbase + offa);
        short8 vb = *(const short8*)((char*)Vt + (size_t)(ct*16+c16)*440 + (ks*32+g*8)*2);
        oa = __builtin_amdgcn_mfma_f32_16x16x32_bf16(pa, vb, oa, 0,0,0);
      }
      #pragma unroll
      for(int r=0;r<4;++r){
        int qq = qb + g*4 + r;
        if(qq < N_)
          attn_out[((size_t)(b*N_+qq))*C_ + h*CH_ + ct*16 + c16] = f2bf(oa[r]);
      }
    }
  }
}

extern "C" void kernel_launch(void* const* d_in, const int* in_sizes, int n_in,
                              void* d_out, int out_size, void* d_ws, size_t ws_size,
                              hipStream_t stream){
  const float* x    =(const float*)d_in[0];
  const float* Wqkv =(const float*)d_in[1];
  const float* Wcq  =(const float*)d_in[2];
  const float* bcq  =(const float*)d_in[3];
  const float* Wck  =(const float*)d_in[4];
  const float* bck  =(const float*)d_in[5];
  const float* proj_n=(const float*)d_in[6];
  const float* proj_back_n=(const float*)d_in[7];
  const float* Wproj=(const float*)d_in[8];
  const float* bproj=(const float*)d_in[9];
  const float* g1=(const float*)d_in[10];
  const float* b1=(const float*)d_in[11];
  const float* g2=(const float*)d_in[12];
  const float* b2=(const float*)d_in[13];
  const float* W1=(const float*)d_in[14];
  const float* bfc1=(const float*)d_in[15];
  const float* W2=(const float*)d_in[16];
  const float* bfc2=(const float*)d_in[17];
  float* out=(float*)d_out;

  // ---- workspace layout (float slots). ~210 MB ----
  float* ws=(float*)d_ws;
  size_t off=0;
  unsigned short* hbuf = (unsigned short*)(ws+off); off += (size_t)12608*768/2;  // bf16, aliased as attn_out
  size_t qkv_off = off;
  float* qkv  = ws+off;        off += (size_t)12608*2304;
  float* qp   = ws+off;        off += (size_t)768*197*32;
  float* kp   = ws+off;        off += (size_t)768*197*32;
  float* kkb  = ws+off;        off += (size_t)768*32*24;
  float* coef = ws+off;        off += (size_t)768*196*24;
  float* basis= ws+off;        off += 4736;
  unsigned int* maskw=(unsigned int*)(ws+off); off += (size_t)768*197*8;
  unsigned short* WqkvT = (unsigned short*)(ws+off); off += (size_t)2304*768/2;
  unsigned short* WprojT= (unsigned short*)(ws+off); off += (size_t)768*768/2;
  unsigned short* W1T   = (unsigned short*)(ws+off); off += (size_t)3072*768/2;
  unsigned short* W2T   = (unsigned short*)(ws+off); off += (size_t)768*3072/2;
  unsigned short* attn_out = hbuf;                    // alias (hbuf dead after qkv GEMM)
  unsigned short* hidden = (unsigned short*)(ws+qkv_off); // alias (qkv dead after attn)
  float* x1 = out;

  // 0. weight transpose+bf16 conversions
  wtrans_kernel<<<dim3(72,24),256,0,stream>>>(Wqkv, WqkvT, 768, 2304);
  wtrans_kernel<<<dim3(24,24),256,0,stream>>>(Wproj, WprojT, 768, 768);
  wtrans_kernel<<<dim3(96,24),256,0,stream>>>(W1, W1T, 768, 3072);
  wtrans_kernel<<<dim3(24,96),256,0,stream>>>(W2, W2T, 3072, 768);
  // 1. h = LN(x) -> bf16
  ln_kernel<<<12608,256,0,stream>>>(x,g1,b1,hbuf);
  // 2. qkv = h @ Wqkv (f32 out)
  gemm_bf16<0,0,0><<<dim3(18,99),256,0,stream>>>(hbuf,WqkvT,nullptr,nullptr,qkv,12608,768,2304);
  // 3. qp, kp
  qkproj_kernel<<<18912,256,0,stream>>>(qkv,Wcq,bcq,qp,0);
  qkproj_kernel<<<18912,256,0,stream>>>(qkv,Wck,bck,kp,1);
  // 4. kk
  kk_kernel<<<768,768,0,stream>>>(kp,proj_n,kkb);
  // 5. basis
  basis_kernel<<<19,256,0,stream>>>(proj_back_n,basis);
  // 6. cheap + softmax + top8
  coef_kernel<<<37632,256,0,stream>>>(qp,kkb,coef);
  // 7. approx_attn + budget mask (wave bitonic select)
  mask2_kernel<<<37824,256,0,stream>>>(coef,basis,maskw);
  // 8. masked attention (MFMA, bf16 out, aliases hbuf)
  attn3_kernel<<<768,512,0,stream>>>(qkv,maskw,attn_out);
  // 9. x1 = x + attn_out @ Wproj + bproj   (x1 == d_out)
  gemm_bf16<0,1,0><<<dim3(6,99),256,0,stream>>>(attn_out,WprojT,bproj,x,x1,12608,768,768);
  // 10. h2 = LN(x1) -> bf16 (reuse hbuf)
  ln_kernel<<<12608,256,0,stream>>>(x1,g2,b2,hbuf);
  // 11. hidden = gelu(h2 @ W1 + bfc1) -> bf16 (aliases dead qkv)
  gemm_bf16<1,0,1><<<dim3(24,99),256,0,stream>>>(hbuf,W1T,bfc1,nullptr,hidden,12608,768,3072);
  // 12. out = x1 + hidden @ W2 + bfc2
  gemm_bf16<0,1,0><<<dim3(6,99),256,0,stream>>>(hidden,W2T,bfc2,x1,out,12608,3072,768);
}

// Round 6
// 1003.280 us; speedup vs baseline: 4.5707x; 1.0449x over previous
//
#include <hip/hip_runtime.h>
#include <math.h>
#include <float.h>

#define B_ 64
#define N_ 197
#define C_ 768
#define H_ 12
#define CH_ 64
#define RC_ 32
#define RN_ 24

typedef __attribute__((ext_vector_type(8))) short short8;
typedef __attribute__((ext_vector_type(4))) float f32x4;
typedef __attribute__((address_space(3))) void  lds_void;
typedef __attribute__((address_space(1))) const void g_void;

__device__ __forceinline__ float warp_sum(float v){
  #pragma unroll
  for(int o=32;o>=1;o>>=1) v += __shfl_xor(v,o);
  return v;
}
__device__ __forceinline__ float warp_max(float v){
  #pragma unroll
  for(int o=32;o>=1;o>>=1) v = fmaxf(v,__shfl_xor(v,o));
  return v;
}
__device__ __forceinline__ unsigned short f2bf(float f){
  union{float f; unsigned u;} c; c.f = f;
  unsigned r = c.u + 0x7FFF + ((c.u>>16)&1);
  return (unsigned short)(r>>16);
}
__device__ __forceinline__ float bf2f(unsigned short u){
  union{unsigned u; float f;} c; c.u = ((unsigned)u)<<16; return c.f;
}

// ---------------- LayerNorm: one block per row of 768, bf16 out ----------------
__global__ __launch_bounds__(256) void ln_kernel(const float* __restrict__ x,
    const float* __restrict__ g, const float* __restrict__ bb, unsigned short* __restrict__ out){
  int r = blockIdx.x; int tid = threadIdx.x;
  const float* xr = x + (size_t)r*C_;
  float v0=xr[tid], v1=xr[tid+256], v2=xr[tid+512];
  __shared__ float red[8];
  float s = warp_sum(v0+v1+v2);
  if((tid&63)==0) red[tid>>6]=s;
  __syncthreads();
  float mu = (red[0]+red[1]+red[2]+red[3]) * (1.f/768.f);
  float d0=v0-mu,d1=v1-mu,d2=v2-mu;
  float s2 = warp_sum(d0*d0+d1*d1+d2*d2);
  if((tid&63)==0) red[4+(tid>>6)]=s2;
  __syncthreads();
  float rinv = rsqrtf((red[4]+red[5]+red[6]+red[7])*(1.f/768.f)+1e-5f);
  unsigned short* orow = out + (size_t)r*C_;
  orow[tid]     = f2bf(d0*rinv*g[tid]    +bb[tid]);
  orow[tid+256] = f2bf(d1*rinv*g[tid+256]+bb[tid+256]);
  orow[tid+512] = f2bf(d2*rinv*g[tid+512]+bb[tid+512]);
}

// ---------------- transpose+convert: in f32 [K][N] -> out bf16 [N][K] ----------------
__global__ __launch_bounds__(256) void wtrans_kernel(const float* __restrict__ in,
    unsigned short* __restrict__ out, int K, int N){
  __shared__ float tile[32][33];
  int n0 = blockIdx.x*32, k0 = blockIdx.y*32;
  int tx = threadIdx.x&31, ty = threadIdx.x>>5;   // ty: 8 rows per pass
  #pragma unroll
  for(int i=0;i<4;++i) tile[ty+8*i][tx] = in[(size_t)(k0+ty+8*i)*N + n0+tx];
  __syncthreads();
  #pragma unroll
  for(int i=0;i<4;++i) out[(size_t)(n0+ty+8*i)*K + k0+tx] = f2bf(tile[tx][ty+8*i]);
}

// ---------------- bf16 MFMA GEMM: Cout = act(A@W + bias) + resid ----------------
// A [M][K] bf16, WT [Nc][K] bf16. 128x128 tile, BK=32, 256 thr, 4 waves each 64x64.
template<int ACT, int RESID, int OUTBF16>
__global__ __launch_bounds__(256) void gemm_bf16(
    const unsigned short* __restrict__ A, const unsigned short* __restrict__ WT,
    const float* __restrict__ bias, const float* __restrict__ resid,
    void* __restrict__ Cout, int M, int K, int Nc){
  __shared__ unsigned short As[128*32];
  __shared__ unsigned short Bs[128*32];
  int tid = threadIdx.x, lane = tid&63, wid = tid>>6;
  int m0 = blockIdx.y*128, n0 = blockIdx.x*128;
  int wr = wid>>1, wc = wid&1;
  int lm = lane&15, lg = lane>>4;
  f32x4 acc[4][4] = {};
  for(int kt=0; kt<K; kt+=32){
    #pragma unroll
    for(int it=0; it<2; ++it){
      int ci = it*256 + tid;
      int row = ci>>2, kc=(ci&3)*8;
      int ar = m0+row; if(ar > M-1) ar = M-1;
      const unsigned short* ga = A  + (size_t)ar*K        + kt + kc;
      const unsigned short* gb = WT + (size_t)(n0+row)*K  + kt + kc;
      __builtin_amdgcn_global_load_lds((g_void*)ga, (lds_void*)(As + (it*256 + wid*64)*8), 16, 0, 0);
      __builtin_amdgcn_global_load_lds((g_void*)gb, (lds_void*)(Bs + (it*256 + wid*64)*8), 16, 0, 0);
    }
    __syncthreads();
    short8 af[4], bfv[4];
    #pragma unroll
    for(int i=0;i<4;++i){
      af[i]  = *(const short8*)(As + (64*wr + 16*i + lm)*32 + lg*8);
      bfv[i] = *(const short8*)(Bs + (64*wc + 16*i + lm)*32 + lg*8);
    }
    #pragma unroll
    for(int i=0;i<4;++i)
      #pragma unroll
      for(int j=0;j<4;++j)
        acc[i][j] = __builtin_amdgcn_mfma_f32_16x16x32_bf16(af[i], bfv[j], acc[i][j], 0,0,0);
    __syncthreads();
  }
  // epilogue: D row = (lane>>4)*4 + r, col = lane&15  (within each 16x16 frag)
  #pragma unroll
  for(int i=0;i<4;++i){
    #pragma unroll
    for(int j=0;j<4;++j){
      int gcol = n0 + 64*wc + 16*j + lm;
      float bv = bias ? bias[gcol] : 0.f;
      #pragma unroll
      for(int r=0;r<4;++r){
        int grow = m0 + 64*wr + 16*i + lg*4 + r;
        if(grow < M){
          float cv = acc[i][j][r] + bv;
          if(ACT==1) cv = 0.5f*cv*(1.0f+erff(cv*0.70710678118654752f));
          if(RESID) cv += resid[(size_t)grow*Nc + gcol];
          if(OUTBF16) ((unsigned short*)Cout)[(size_t)grow*Nc+gcol] = f2bf(cv);
          else        ((float*)Cout)[(size_t)grow*Nc+gcol] = cv;
        }
      }
    }
  }
}

// ---------------- qp/kp: per (b,h,n) row, 64x32 matvec ----------------
__global__ __launch_bounds__(256) void qkproj_kernel(const float* __restrict__ qkv,
    const float* __restrict__ Wc, const float* __restrict__ bc,
    float* __restrict__ outp, int sel){
  int r = blockIdx.x*8 + (threadIdx.x>>5);
  int col = threadIdx.x&31;
  int b = r/(H_*N_); int rem = r%(H_*N_); int h = rem/N_; int n = rem%N_;
  const float* src = qkv + ((size_t)(b*N_+n)*3 + sel)*C_ + h*CH_;
  float acc = bc[col];
  #pragma unroll
  for(int ch=0;ch<CH_;++ch) acc += src[ch]*Wc[ch*RC_+col];
  outp[(size_t)r*RC_+col]=acc;
}

// ---------------- kk[b,h,c,r] = sum_n kp[b,h,n,c]*proj_n[n,r] ----------------
__global__ __launch_bounds__(768) void kk_kernel(const float* __restrict__ kp,
    const float* __restrict__ proj_n, float* __restrict__ kkb){
  int bh = blockIdx.x;
  int t = threadIdx.x;            // 768 = 32*24
  int c = t/RN_, rr = t%RN_;
  const float* kpb = kp + (size_t)bh*N_*RC_;
  float acc = 0.f;
  for(int n=0;n<N_;++n) acc += kpb[n*RC_+c]*proj_n[n*RN_+rr];
  kkb[(size_t)bh*RC_*RN_ + c*RN_ + rr] = acc;
}

// ---------------- cheap + softmax + keep-top8: one wave per (b,h,n>=1) ----------------
__global__ __launch_bounds__(256) void coef_kernel(const float* __restrict__ qp,
    const float* __restrict__ kkb, float* __restrict__ coef){
  int wid = blockIdx.x*4 + (threadIdx.x>>6);   // (b*H+h)*196 + (n-1)
  int lane = threadIdx.x&63;
  int b = wid/(H_*196); int rem = wid%(H_*196); int h = rem/196; int n = rem%196+1;
  int bh = b*H_+h;
  const float* qpr = qp + ((size_t)bh*N_ + n)*RC_;
  const float* kkp = kkb + (size_t)bh*RC_*RN_;
  float val = -INFINITY;
  if(lane<RN_){
    float acc=0.f;
    #pragma unroll
    for(int c=0;c<RC_;++c) acc += qpr[c]*kkp[c*RN_+lane];
    val = acc * 0.28867513459481287f;   // H^-0.5
  }
  float m = warp_max(val);
  float e = (lane<RN_)? expf(val-m):0.f;
  float ssum = warp_sum(e);
  float p = e/ssum;
  float myv = (lane<RN_)? p : -1.f;
  int cnt=0;
  #pragma unroll
  for(int j=0;j<RN_;++j){ float vj = __shfl(myv, j); cnt += (vj>myv)?1:0; }
  if(lane<RN_) coef[(size_t)wid*RN_+lane] = (cnt<=7)? p : 0.f;
}

// ---------------- basis[r][j] = thresh(|proj_back_n[j][r]|) ----------------
__global__ __launch_bounds__(256) void basis_kernel(const float* __restrict__ pb,
    float* __restrict__ basis){
  int t = blockIdx.x*256 + threadIdx.x;
  if(t < RN_*N_){
    int r = t/N_, j = t%N_;
    float v = fabsf(pb[(size_t)j*RN_ + r]);
    basis[t] = (v > 0.02f) ? v : 0.f;
  }
}

// ---------------- mask v3: one WAVE per row; ballot radix-select top-50 ----------------
// elem = reg*64 + lane (reg-major) so per-reg __ballot == maskw words directly.
// Values are non-negative floats -> u32 bit pattern is order-isomorphic.
__global__ __launch_bounds__(256) void mask3_kernel(const float* __restrict__ coef,
    const float* __restrict__ basis, unsigned int* __restrict__ maskw){
  __shared__ float Bs[24*256];
  __shared__ float cfs[4][24];
  int tid = threadIdx.x, lane = tid&63, wv = tid>>6;
  // stage thresholded basis, zero-padded to 256 cols
  for(int idx = tid; idx < 24*256; idx += 256){
    int r = idx>>8, e = idx&255;
    Bs[idx] = (e < N_) ? basis[r*N_ + e] : 0.f;
  }
  __syncthreads();
  int row = blockIdx.x*4 + wv;          // (b*H+h)*197 + qi
  int qi = row % N_; int bh = row / N_;
  if(qi==0){
    if(lane<8){
      unsigned v = (lane<6)?0xFFFFFFFFu:((lane==6)?0x1Fu:0u);
      maskw[(size_t)row*8+lane]=v;
    }
    return;
  }
  if(lane<24) cfs[wv][lane] = coef[((size_t)bh*196 + (qi-1))*24 + lane];
  // dot: a[elem] = sum_r cf[r]*basis[r][elem], skipping zero coefs (wave-uniform)
  float av[4] = {0.f,0.f,0.f,0.f};
  for(int r=0;r<24;++r){
    float c = cfs[wv][r];
    if(c != 0.f){
      #pragma unroll
      for(int g2=0; g2<4; ++g2) av[g2] += c * Bs[r*256 + g2*64 + lane];
    }
  }
  // radix select: 50th largest among 256 values (pads=+0.0 rank at bottom; a>=0)
  unsigned u[4];
  #pragma unroll
  for(int r=0;r<4;++r) u[r] = __float_as_uint(av[r]);   // pads are exactly 0u
  unsigned prefix = 0; int k = 50;
  #pragma unroll
  for(int bit=30; bit>=0; --bit){        // bit31 = sign, always 0
    unsigned tgt = (prefix >> bit) | 1u;
    int c = 0;
    #pragma unroll
    for(int r=0;r<4;++r){
      unsigned long long bal = __ballot((u[r] >> bit) == tgt);
      c += __popcll(bal);
    }
    bool take = (c >= k);
    prefix = take ? (prefix | (1u<<bit)) : prefix;
    k      = take ? k : (k - c);
  }
  // keep = a >= t  (t = exact 50th-largest value)
  #pragma unroll
  for(int r=0;r<4;++r){
    bool valid = (r<3) | (lane<5);
    bool keep = valid && (u[r] >= prefix);
    unsigned long long bal = __ballot(keep);
    if(lane==0){
      maskw[(size_t)row*8 + 2*r]   = (unsigned)(bal & 0xFFFFFFFFull);
      maskw[(size_t)row*8 + 2*r+1] = (unsigned)(bal>>32);
    }
  }
}

// ---------------- masked attention v3: MFMA flash-style, one block per (b,h) ----------------
// K in LDS [208][64] bf16, rows 128B, XOR-swizzled (byte ^= (k&7)<<4).
// V in LDS transposed [64][220] bf16 (rows 440B: 2-way-free frag reads).
// P round-trip through LDS [16][224] per wave (448B rows, XOR-swizzled).
__global__ __launch_bounds__(512) void attn3_kernel(const float* __restrict__ qkv,
    const unsigned int* __restrict__ maskw, unsigned short* __restrict__ attn_out){
  int bh = blockIdx.x; int b = bh/H_, h = bh%H_;
  int tid = threadIdx.x, lane = tid&63, wv = tid>>6;
  int g = lane>>4, c16 = lane&15;
  __shared__ unsigned short Kb[208*64];     // 26.6 KB
  __shared__ unsigned short Vt[64*220];     // 28.2 KB
  __shared__ unsigned short Pl[8*16*224];   // 57.3 KB
  __shared__ unsigned int   Ml[8][16][8];   // 4 KB
  const float* Kbase = qkv + ((size_t)(b*N_)*3 + 1)*C_ + h*CH_;
  const float* Vbase = qkv + ((size_t)(b*N_)*3 + 2)*C_ + h*CH_;
  // stage K rows 0..207 (zero-pad >=197), u32-packed writes, swizzled
  for(int idx = tid; idx < 208*32; idx += 512){
    int k = idx>>5, cp = idx&31;
    unsigned pk = 0;
    if(k < N_){
      float2 kv = *(const float2*)(Kbase + (size_t)k*3*C_ + cp*2);
      pk = (unsigned)f2bf(kv.x) | ((unsigned)f2bf(kv.y)<<16);
    }
    unsigned off = (unsigned)(k*128 + cp*4) ^ ((unsigned)(k&7)<<4);
    *(unsigned*)((char*)Kb + off) = pk;
  }
  // stage V transposed, zero-pad k>=197 (prevents NaN*0 in PV)
  for(int idx = tid; idx < 64*110; idx += 512){
    int kp = idx>>6, c = idx&63;
    int k0 = kp*2, k1 = kp*2+1;
    float v0 = (k0<N_) ? Vbase[(size_t)k0*3*C_ + c] : 0.f;
    float v1 = (k1<N_) ? Vbase[(size_t)k1*3*C_ + c] : 0.f;
    *(unsigned*)((char*)Vt + c*440 + kp*4) = (unsigned)f2bf(v0) | ((unsigned)f2bf(v1)<<16);
  }
  __syncthreads();
  size_t pbase = (size_t)wv*16*448;
  // zero P tail (k=208..223) once per wave
  for(int i=lane;i<128;i+=64){
    int ql = i>>3; int kk = 208 + (i&7)*2;
    unsigned off = (unsigned)(ql*448 + kk*2) ^ ((unsigned)(ql&7)<<4);
    *(unsigned*)((char*)Pl + pbase + off) = 0u;
  }
  for(int t = wv; t < 13; t += 8){
    int qb = t*16;
    // mask tile -> LDS (per-wave region, no block sync needed)
    for(int i = lane; i < 128; i += 64){
      int row = i>>3, word = i&7;
      int qr = qb+row; if(qr>196) qr=196;
      Ml[wv][row][word] = maskw[(size_t)(bh*N_+qr)*8 + word];
    }
    // Q A-frags straight from global (L2-hot), ATTN_SCALE folded in
    int qrow = qb + c16; if(qrow>196) qrow=196;
    const float* Qr = qkv + ((size_t)(b*N_+qrow)*3)*C_ + h*CH_ + g*8;
    short8 af[2];
    #pragma unroll
    for(int s=0;s<2;++s)
      #pragma unroll
      for(int j=0;j<8;++j) af[s][j] = (short)f2bf(Qr[s*32+j]*0.125f);
    // S = Q @ K^T : 13 frags x 2 k-steps
    f32x4 sf[13];
    #pragma unroll
    for(int f=0;f<13;++f){
      sf[f] = (f32x4){0.f,0.f,0.f,0.f};
      #pragma unroll
      for(int s=0;s<2;++s){
        int row = f*16 + c16;
        unsigned off = (unsigned)(row*128 + s*64 + g*16) ^ ((unsigned)(row&7)<<4);
        short8 bfr = *(const short8*)((char*)Kb + off);
        sf[f] = __builtin_amdgcn_mfma_f32_16x16x32_bf16(af[s], bfr, sf[f], 0,0,0);
      }
    }
    // masked softmax (row = q = g*4+r across 16-lane groups; col k = lane&15)
    unsigned keep[4] = {0,0,0,0};
    float m[4] = {-FLT_MAX,-FLT_MAX,-FLT_MAX,-FLT_MAX};
    #pragma unroll
    for(int f=0;f<13;++f)
      #pragma unroll
      for(int r=0;r<4;++r){
        unsigned bit = (Ml[wv][g*4+r][f>>1] >> ((f&1)*16 + c16)) & 1u;
        keep[r] |= bit<<f;
        if(bit) m[r] = fmaxf(m[r], sf[f][r]);
      }
    #pragma unroll
    for(int r=0;r<4;++r){
      #pragma unroll
      for(int o=8;o>=1;o>>=1) m[r] = fmaxf(m[r], __shfl_xor(m[r], o));
    }
    float sum[4] = {0,0,0,0};
    #pragma unroll
    for(int f=0;f<13;++f)
      #pragma unroll
      for(int r=0;r<4;++r){
        float e = ((keep[r]>>f)&1u) ? expf(sf[f][r]-m[r]) : 0.f;
        sf[f][r] = e; sum[r] += e;
      }
    #pragma unroll
    for(int r=0;r<4;++r){
      #pragma unroll
      for(int o=8;o>=1;o>>=1) sum[r] += __shfl_xor(sum[r], o);
      sum[r] = 1.f/sum[r];
    }
    // P -> LDS (A-fragment layout source), swizzled
    #pragma unroll
    for(int f=0;f<13;++f)
      #pragma unroll
      for(int r=0;r<4;++r){
        int ql = g*4+r;
        unsigned off = (unsigned)(ql*448 + (f*16+c16)*2) ^ ((unsigned)(ql&7)<<4);
        *(unsigned short*)((char*)Pl + pbase + off) = f2bf(sf[f][r]*sum[r]);
      }
    // O = P @ V : 4 col-tiles x 7 k-steps
    #pragma unroll
    for(int ct=0;ct<4;++ct){
      f32x4 oa = (f32x4){0.f,0.f,0.f,0.f};
      #pragma unroll
      for(int ks=0;ks<7;++ks){
        unsigned offa = (unsigned)(c16*448 + (ks*32+g*8)*2) ^ ((unsigned)(c16&7)<<4);
        short8 pa = *(const short8*)((char*)Pl + pbase + offa);
        short8 vb = *(const short8*)((char*)Vt + (size_t)(ct*16+c16)*440 + (ks*32+g*8)*2);
        oa = __builtin_amdgcn_mfma_f32_16x16x32_bf16(pa, vb, oa, 0,0,0);
      }
      #pragma unroll
      for(int r=0;r<4;++r){
        int qq = qb + g*4 + r;
        if(qq < N_)
          attn_out[((size_t)(b*N_+qq))*C_ + h*CH_ + ct*16 + c16] = f2bf(oa[r]);
      }
    }
  }
}

extern "C" void kernel_launch(void* const* d_in, const int* in_sizes, int n_in,
                              void* d_out, int out_size, void* d_ws, size_t ws_size,
                              hipStream_t stream){
  const float* x    =(const float*)d_in[0];
  const float* Wqkv =(const float*)d_in[1];
  const float* Wcq  =(const float*)d_in[2];
  const float* bcq  =(const float*)d_in[3];
  const float* Wck  =(const float*)d_in[4];
  const float* bck  =(const float*)d_in[5];
  const float* proj_n=(const float*)d_in[6];
  const float* proj_back_n=(const float*)d_in[7];
  const float* Wproj=(const float*)d_in[8];
  const float* bproj=(const float*)d_in[9];
  const float* g1=(const float*)d_in[10];
  const float* b1=(const float*)d_in[11];
  const float* g2=(const float*)d_in[12];
  const float* b2=(const float*)d_in[13];
  const float* W1=(const float*)d_in[14];
  const float* bfc1=(const float*)d_in[15];
  const float* W2=(const float*)d_in[16];
  const float* bfc2=(const float*)d_in[17];
  float* out=(float*)d_out;

  // ---- workspace layout (float slots). ~210 MB ----
  float* ws=(float*)d_ws;
  size_t off=0;
  unsigned short* hbuf = (unsigned short*)(ws+off); off += (size_t)12608*768/2;  // bf16, aliased as attn_out
  size_t qkv_off = off;
  float* qkv  = ws+off;        off += (size_t)12608*2304;
  float* qp   = ws+off;        off += (size_t)768*197*32;
  float* kp   = ws+off;        off += (size_t)768*197*32;
  float* kkb  = ws+off;        off += (size_t)768*32*24;
  float* coef = ws+off;        off += (size_t)768*196*24;
  float* basis= ws+off;        off += 4736;
  unsigned int* maskw=(unsigned int*)(ws+off); off += (size_t)768*197*8;
  unsigned short* WqkvT = (unsigned short*)(ws+off); off += (size_t)2304*768/2;
  unsigned short* WprojT= (unsigned short*)(ws+off); off += (size_t)768*768/2;
  unsigned short* W1T   = (unsigned short*)(ws+off); off += (size_t)3072*768/2;
  unsigned short* W2T   = (unsigned short*)(ws+off); off += (size_t)768*3072/2;
  unsigned short* attn_out = hbuf;                    // alias (hbuf dead after qkv GEMM)
  unsigned short* hidden = (unsigned short*)(ws+qkv_off); // alias (qkv dead after attn)
  float* x1 = out;

  // 0. weight transpose+bf16 conversions
  wtrans_kernel<<<dim3(72,24),256,0,stream>>>(Wqkv, WqkvT, 768, 2304);
  wtrans_kernel<<<dim3(24,24),256,0,stream>>>(Wproj, WprojT, 768, 768);
  wtrans_kernel<<<dim3(96,24),256,0,stream>>>(W1, W1T, 768, 3072);
  wtrans_kernel<<<dim3(24,96),256,0,stream>>>(W2, W2T, 3072, 768);
  // 1. h = LN(x) -> bf16
  ln_kernel<<<12608,256,0,stream>>>(x,g1,b1,hbuf);
  // 2. qkv = h @ Wqkv (f32 out)
  gemm_bf16<0,0,0><<<dim3(18,99),256,0,stream>>>(hbuf,WqkvT,nullptr,nullptr,qkv,12608,768,2304);
  // 3. qp, kp
  qkproj_kernel<<<18912,256,0,stream>>>(qkv,Wcq,bcq,qp,0);
  qkproj_kernel<<<18912,256,0,stream>>>(qkv,Wck,bck,kp,1);
  // 4. kk
  kk_kernel<<<768,768,0,stream>>>(kp,proj_n,kkb);
  // 5. basis
  basis_kernel<<<19,256,0,stream>>>(proj_back_n,basis);
  // 6. cheap + softmax + top8
  coef_kernel<<<37632,256,0,stream>>>(qp,kkb,coef);
  // 7. approx_attn + budget mask (ballot radix select)
  mask3_kernel<<<37824,256,0,stream>>>(coef,basis,maskw);
  // 8. masked attention (MFMA, bf16 out, aliases hbuf)
  attn3_kernel<<<768,512,0,stream>>>(qkv,maskw,attn_out);
  // 9. x1 = x + attn_out @ Wproj + bproj   (x1 == d_out)
  gemm_bf16<0,1,0><<<dim3(6,99),256,0,stream>>>(attn_out,WprojT,bproj,x,x1,12608,768,768);
  // 10. h2 = LN(x1) -> bf16 (reuse hbuf)
  ln_kernel<<<12608,256,0,stream>>>(x1,g2,b2,hbuf);
  // 11. hidden = gelu(h2 @ W1 + bfc1) -> bf16 (aliases dead qkv)
  gemm_bf16<1,0,1><<<dim3(24,99),256,0,stream>>>(hbuf,W1T,bfc1,nullptr,hidden,12608,768,3072);
  // 12. out = x1 + hidden @ W2 + bfc2
  gemm_bf16<0,1,0><<<dim3(6,99),256,0,stream>>>(hidden,W2T,bfc2,x1,out,12608,3072,768);
}

// Round 7
// 928.965 us; speedup vs baseline: 4.9363x; 1.0800x over previous
//
#include <hip/hip_runtime.h>
#include <math.h>
#include <float.h>

#define B_ 64
#define N_ 197
#define C_ 768
#define H_ 12
#define CH_ 64
#define RC_ 32
#define RN_ 24

typedef __attribute__((ext_vector_type(8))) short short8;
typedef __attribute__((ext_vector_type(4))) float f32x4;
typedef __attribute__((address_space(3))) void  lds_void;
typedef __attribute__((address_space(1))) const void g_void;

__device__ __forceinline__ float warp_sum(float v){
  #pragma unroll
  for(int o=32;o>=1;o>>=1) v += __shfl_xor(v,o);
  return v;
}
__device__ __forceinline__ float warp_max(float v){
  #pragma unroll
  for(int o=32;o>=1;o>>=1) v = fmaxf(v,__shfl_xor(v,o));
  return v;
}
__device__ __forceinline__ unsigned short f2bf(float f){
  union{float f; unsigned u;} c; c.f = f;
  unsigned r = c.u + 0x7FFF + ((c.u>>16)&1);
  return (unsigned short)(r>>16);
}
__device__ __forceinline__ float bf2f(unsigned short u){
  union{unsigned u; float f;} c; c.u = ((unsigned)u)<<16; return c.f;
}

// ---------------- LayerNorm: one block per row of 768, bf16 out ----------------
__global__ __launch_bounds__(256) void ln_kernel(const float* __restrict__ x,
    const float* __restrict__ g, const float* __restrict__ bb, unsigned short* __restrict__ out){
  int r = blockIdx.x; int tid = threadIdx.x;
  const float* xr = x + (size_t)r*C_;
  float v0=xr[tid], v1=xr[tid+256], v2=xr[tid+512];
  __shared__ float red[8];
  float s = warp_sum(v0+v1+v2);
  if((tid&63)==0) red[tid>>6]=s;
  __syncthreads();
  float mu = (red[0]+red[1]+red[2]+red[3]) * (1.f/768.f);
  float d0=v0-mu,d1=v1-mu,d2=v2-mu;
  float s2 = warp_sum(d0*d0+d1*d1+d2*d2);
  if((tid&63)==0) red[4+(tid>>6)]=s2;
  __syncthreads();
  float rinv = rsqrtf((red[4]+red[5]+red[6]+red[7])*(1.f/768.f)+1e-5f);
  unsigned short* orow = out + (size_t)r*C_;
  orow[tid]     = f2bf(d0*rinv*g[tid]    +bb[tid]);
  orow[tid+256] = f2bf(d1*rinv*g[tid+256]+bb[tid+256]);
  orow[tid+512] = f2bf(d2*rinv*g[tid+512]+bb[tid+512]);
}

// ---------------- transpose+convert: in f32 [K][N] -> out bf16 [N][K] ----------------
__global__ __launch_bounds__(256) void wtrans_kernel(const float* __restrict__ in,
    unsigned short* __restrict__ out, int K, int N){
  __shared__ float tile[32][33];
  int n0 = blockIdx.x*32, k0 = blockIdx.y*32;
  int tx = threadIdx.x&31, ty = threadIdx.x>>5;   // ty: 8 rows per pass
  #pragma unroll
  for(int i=0;i<4;++i) tile[ty+8*i][tx] = in[(size_t)(k0+ty+8*i)*N + n0+tx];
  __syncthreads();
  #pragma unroll
  for(int i=0;i<4;++i) out[(size_t)(n0+ty+8*i)*K + k0+tx] = f2bf(tile[tx][ty+8*i]);
}

// ---------------- bf16 MFMA GEMM: Cout = act(A@W + bias) + resid ----------------
// A [M][K] bf16, WT [Nc][K] bf16. 128x128 tile, BK=32, 256 thr, 4 waves each 64x64.
template<int ACT, int RESID, int OUTBF16>
__global__ __launch_bounds__(256) void gemm_bf16(
    const unsigned short* __restrict__ A, const unsigned short* __restrict__ WT,
    const float* __restrict__ bias, const float* __restrict__ resid,
    void* __restrict__ Cout, int M, int K, int Nc){
  __shared__ unsigned short As[128*32];
  __shared__ unsigned short Bs[128*32];
  int tid = threadIdx.x, lane = tid&63, wid = tid>>6;
  int m0 = blockIdx.y*128, n0 = blockIdx.x*128;
  int wr = wid>>1, wc = wid&1;
  int lm = lane&15, lg = lane>>4;
  f32x4 acc[4][4] = {};
  for(int kt=0; kt<K; kt+=32){
    #pragma unroll
    for(int it=0; it<2; ++it){
      int ci = it*256 + tid;
      int row = ci>>2, kc=(ci&3)*8;
      int ar = m0+row; if(ar > M-1) ar = M-1;
      const unsigned short* ga = A  + (size_t)ar*K        + kt + kc;
      const unsigned short* gb = WT + (size_t)(n0+row)*K  + kt + kc;
      __builtin_amdgcn_global_load_lds((g_void*)ga, (lds_void*)(As + (it*256 + wid*64)*8), 16, 0, 0);
      __builtin_amdgcn_global_load_lds((g_void*)gb, (lds_void*)(Bs + (it*256 + wid*64)*8), 16, 0, 0);
    }
    __syncthreads();
    short8 af[4], bfv[4];
    #pragma unroll
    for(int i=0;i<4;++i){
      af[i]  = *(const short8*)(As + (64*wr + 16*i + lm)*32 + lg*8);
      bfv[i] = *(const short8*)(Bs + (64*wc + 16*i + lm)*32 + lg*8);
    }
    #pragma unroll
    for(int i=0;i<4;++i)
      #pragma unroll
      for(int j=0;j<4;++j)
        acc[i][j] = __builtin_amdgcn_mfma_f32_16x16x32_bf16(af[i], bfv[j], acc[i][j], 0,0,0);
    __syncthreads();
  }
  // epilogue: D row = (lane>>4)*4 + r, col = lane&15  (within each 16x16 frag)
  #pragma unroll
  for(int i=0;i<4;++i){
    #pragma unroll
    for(int j=0;j<4;++j){
      int gcol = n0 + 64*wc + 16*j + lm;
      float bv = bias ? bias[gcol] : 0.f;
      #pragma unroll
      for(int r=0;r<4;++r){
        int grow = m0 + 64*wr + 16*i + lg*4 + r;
        if(grow < M){
          float cv = acc[i][j][r] + bv;
          if(ACT==1) cv = 0.5f*cv*(1.0f+erff(cv*0.70710678118654752f));
          if(RESID) cv += resid[(size_t)grow*Nc + gcol];
          if(OUTBF16) ((unsigned short*)Cout)[(size_t)grow*Nc+gcol] = f2bf(cv);
          else        ((float*)Cout)[(size_t)grow*Nc+gcol] = cv;
        }
      }
    }
  }
}

// ---------------- qp/kp: per (b,h,n) row, 64x32 matvec ----------------
__global__ __launch_bounds__(256) void qkproj_kernel(const float* __restrict__ qkv,
    const float* __restrict__ Wc, const float* __restrict__ bc,
    float* __restrict__ outp, int sel){
  int r = blockIdx.x*8 + (threadIdx.x>>5);
  int col = threadIdx.x&31;
  int b = r/(H_*N_); int rem = r%(H_*N_); int h = rem/N_; int n = rem%N_;
  const float* src = qkv + ((size_t)(b*N_+n)*3 + sel)*C_ + h*CH_;
  float acc = bc[col];
  #pragma unroll
  for(int ch=0;ch<CH_;++ch) acc += src[ch]*Wc[ch*RC_+col];
  outp[(size_t)r*RC_+col]=acc;
}

// ---------------- kk[b,h,c,r] = sum_n kp[b,h,n,c]*proj_n[n,r] ----------------
__global__ __launch_bounds__(768) void kk_kernel(const float* __restrict__ kp,
    const float* __restrict__ proj_n, float* __restrict__ kkb){
  int bh = blockIdx.x;
  int t = threadIdx.x;            // 768 = 32*24
  int c = t/RN_, rr = t%RN_;
  const float* kpb = kp + (size_t)bh*N_*RC_;
  float acc = 0.f;
  for(int n=0;n<N_;++n) acc += kpb[n*RC_+c]*proj_n[n*RN_+rr];
  kkb[(size_t)bh*RC_*RN_ + c*RN_ + rr] = acc;
}

// ---------------- cheap + softmax + keep-top8: one wave per (b,h,n>=1) ----------------
__global__ __launch_bounds__(256) void coef_kernel(const float* __restrict__ qp,
    const float* __restrict__ kkb, float* __restrict__ coef){
  int wid = blockIdx.x*4 + (threadIdx.x>>6);   // (b*H+h)*196 + (n-1)
  int lane = threadIdx.x&63;
  int b = wid/(H_*196); int rem = wid%(H_*196); int h = rem/196; int n = rem%196+1;
  int bh = b*H_+h;
  const float* qpr = qp + ((size_t)bh*N_ + n)*RC_;
  const float* kkp = kkb + (size_t)bh*RC_*RN_;
  float val = -INFINITY;
  if(lane<RN_){
    float acc=0.f;
    #pragma unroll
    for(int c=0;c<RC_;++c) acc += qpr[c]*kkp[c*RN_+lane];
    val = acc * 0.28867513459481287f;   // H^-0.5
  }
  float m = warp_max(val);
  float e = (lane<RN_)? expf(val-m):0.f;
  float ssum = warp_sum(e);
  float p = e/ssum;
  float myv = (lane<RN_)? p : -1.f;
  int cnt=0;
  #pragma unroll
  for(int j=0;j<RN_;++j){ float vj = __shfl(myv, j); cnt += (vj>myv)?1:0; }
  if(lane<RN_) coef[(size_t)wid*RN_+lane] = (cnt<=7)? p : 0.f;
}

// ---------------- basis[r][j] = thresh(|proj_back_n[j][r]|) ----------------
__global__ __launch_bounds__(256) void basis_kernel(const float* __restrict__ pb,
    float* __restrict__ basis){
  int t = blockIdx.x*256 + threadIdx.x;
  if(t < RN_*N_){
    int r = t/N_, j = t%N_;
    float v = fabsf(pb[(size_t)j*RN_ + r]);
    basis[t] = (v > 0.02f) ? v : 0.f;
  }
}

// ---------------- mask v4: one WAVE per 4 rows; ballot compare-radix top-50 ----------------
// Bs layout: element e of basis row r stored at Bs[r*256 + (e&63)*4 + (e>>6)]
// -> lane reads its 4 elements {g2*64+lane} with ONE ds_read_b128.
// Select: greedy max t with count(u >= t) >= 50 (4 v_cmp_ge vs SGPR per bit).
__global__ __launch_bounds__(256) void mask4_kernel(const float* __restrict__ coef,
    const float* __restrict__ basis, unsigned int* __restrict__ maskw){
  __shared__ float Bs[24*256];
  int tid = threadIdx.x, lane = tid&63, wv = tid>>6;
  for(int idx = tid; idx < 24*256; idx += 256){
    int r = idx>>8, q = idx&255;
    int e = ((q&3)<<6) | (q>>2);          // inverse of dest mapping
    Bs[idx] = (e < N_) ? basis[r*N_ + e] : 0.f;
  }
  __syncthreads();
  int rowbase = blockIdx.x*16 + wv*4;     // 9456 blocks * 16 rows = 151296
  #pragma unroll
  for(int j=0;j<4;++j){
    int row = rowbase + j;                // (b*H+h)*197 + qi
    int qi = row % N_; int bh = row / N_;
    if(qi==0){
      if(lane<8){
        unsigned v = (lane<6)?0xFFFFFFFFu:((lane==6)?0x1Fu:0u);
        maskw[(size_t)row*8+lane]=v;
      }
      continue;
    }
    float cfv = (lane<24) ? coef[((size_t)bh*196 + (qi-1))*24 + lane] : 0.f;
    unsigned long long nz = __ballot(cfv != 0.f);
    float4 av = make_float4(0.f,0.f,0.f,0.f);
    while(nz){
      int r = __ffsll((unsigned long long)nz) - 1;
      nz &= nz - 1;
      float c = __uint_as_float(__builtin_amdgcn_readlane(__float_as_uint(cfv), r));
      float4 bv = *(const float4*)&Bs[r*256 + lane*4];
      av.x += c*bv.x; av.y += c*bv.y; av.z += c*bv.z; av.w += c*bv.w;
    }
    unsigned u0=__float_as_uint(av.x), u1=__float_as_uint(av.y);
    unsigned u2=__float_as_uint(av.z), u3=__float_as_uint(av.w);
    // greedy threshold: largest t with count(u >= t) >= 50
    unsigned prefix = 0;
    #pragma unroll
    for(int bit=30; bit>=0; --bit){
      unsigned t = prefix | (1u<<bit);
      int c = __popcll(__ballot(u0 >= t)) + __popcll(__ballot(u1 >= t))
            + __popcll(__ballot(u2 >= t)) + __popcll(__ballot(u3 >= t));
      if(c >= 50) prefix = t;
    }
    // keep = a >= t (exact 50th-largest); guard pads (elem>=197)
    unsigned uu[4] = {u0,u1,u2,u3};
    #pragma unroll
    for(int r=0;r<4;++r){
      bool valid = (r<3) | (lane<5);
      bool keep = valid && (uu[r] >= prefix);
      unsigned long long bal = __ballot(keep);
      if(lane==0){
        maskw[(size_t)row*8 + 2*r]   = (unsigned)(bal & 0xFFFFFFFFull);
        maskw[(size_t)row*8 + 2*r+1] = (unsigned)(bal>>32);
      }
    }
  }
}

// ---------------- masked attention v3: MFMA flash-style, one block per (b,h) ----------------
// K in LDS [208][64] bf16, rows 128B, XOR-swizzled (byte ^= (k&7)<<4).
// V in LDS transposed [64][220] bf16 (rows 440B: 2-way-free frag reads).
// P round-trip through LDS [16][224] per wave (448B rows, XOR-swizzled).
__global__ __launch_bounds__(512) void attn3_kernel(const float* __restrict__ qkv,
    const unsigned int* __restrict__ maskw, unsigned short* __restrict__ attn_out){
  int bh = blockIdx.x; int b = bh/H_, h = bh%H_;
  int tid = threadIdx.x, lane = tid&63, wv = tid>>6;
  int g = lane>>4, c16 = lane&15;
  __shared__ unsigned short Kb[208*64];     // 26.6 KB
  __shared__ unsigned short Vt[64*220];     // 28.2 KB
  __shared__ unsigned short Pl[8*16*224];   // 57.3 KB
  __shared__ unsigned int   Ml[8][16][8];   // 4 KB
  const float* Kbase = qkv + ((size_t)(b*N_)*3 + 1)*C_ + h*CH_;
  const float* Vbase = qkv + ((size_t)(b*N_)*3 + 2)*C_ + h*CH_;
  // stage K rows 0..207 (zero-pad >=197), u32-packed writes, swizzled
  for(int idx = tid; idx < 208*32; idx += 512){
    int k = idx>>5, cp = idx&31;
    unsigned pk = 0;
    if(k < N_){
      float2 kv = *(const float2*)(Kbase + (size_t)k*3*C_ + cp*2);
      pk = (unsigned)f2bf(kv.x) | ((unsigned)f2bf(kv.y)<<16);
    }
    unsigned off = (unsigned)(k*128 + cp*4) ^ ((unsigned)(k&7)<<4);
    *(unsigned*)((char*)Kb + off) = pk;
  }
  // stage V transposed, zero-pad k>=197 (prevents NaN*0 in PV)
  for(int idx = tid; idx < 64*110; idx += 512){
    int kp = idx>>6, c = idx&63;
    int k0 = kp*2, k1 = kp*2+1;
    float v0 = (k0<N_) ? Vbase[(size_t)k0*3*C_ + c] : 0.f;
    float v1 = (k1<N_) ? Vbase[(size_t)k1*3*C_ + c] : 0.f;
    *(unsigned*)((char*)Vt + c*440 + kp*4) = (unsigned)f2bf(v0) | ((unsigned)f2bf(v1)<<16);
  }
  __syncthreads();
  size_t pbase = (size_t)wv*16*448;
  // zero P tail (k=208..223) once per wave
  for(int i=lane;i<128;i+=64){
    int ql = i>>3; int kk = 208 + (i&7)*2;
    unsigned off = (unsigned)(ql*448 + kk*2) ^ ((unsigned)(ql&7)<<4);
    *(unsigned*)((char*)Pl + pbase + off) = 0u;
  }
  for(int t = wv; t < 13; t += 8){
    int qb = t*16;
    // mask tile -> LDS (per-wave region, no block sync needed)
    for(int i = lane; i < 128; i += 64){
      int row = i>>3, word = i&7;
      int qr = qb+row; if(qr>196) qr=196;
      Ml[wv][row][word] = maskw[(size_t)(bh*N_+qr)*8 + word];
    }
    // Q A-frags straight from global (L2-hot), ATTN_SCALE folded in
    int qrow = qb + c16; if(qrow>196) qrow=196;
    const float* Qr = qkv + ((size_t)(b*N_+qrow)*3)*C_ + h*CH_ + g*8;
    short8 af[2];
    #pragma unroll
    for(int s=0;s<2;++s)
      #pragma unroll
      for(int j=0;j<8;++j) af[s][j] = (short)f2bf(Qr[s*32+j]*0.125f);
    // S = Q @ K^T : 13 frags x 2 k-steps
    f32x4 sf[13];
    #pragma unroll
    for(int f=0;f<13;++f){
      sf[f] = (f32x4){0.f,0.f,0.f,0.f};
      #pragma unroll
      for(int s=0;s<2;++s){
        int row = f*16 + c16;
        unsigned off = (unsigned)(row*128 + s*64 + g*16) ^ ((unsigned)(row&7)<<4);
        short8 bfr = *(const short8*)((char*)Kb + off);
        sf[f] = __builtin_amdgcn_mfma_f32_16x16x32_bf16(af[s], bfr, sf[f], 0,0,0);
      }
    }
    // masked softmax (row = q = g*4+r across 16-lane groups; col k = lane&15)
    unsigned keep[4] = {0,0,0,0};
    float m[4] = {-FLT_MAX,-FLT_MAX,-FLT_MAX,-FLT_MAX};
    #pragma unroll
    for(int f=0;f<13;++f)
      #pragma unroll
      for(int r=0;r<4;++r){
        unsigned bit = (Ml[wv][g*4+r][f>>1] >> ((f&1)*16 + c16)) & 1u;
        keep[r] |= bit<<f;
        if(bit) m[r] = fmaxf(m[r], sf[f][r]);
      }
    #pragma unroll
    for(int r=0;r<4;++r){
      #pragma unroll
      for(int o=8;o>=1;o>>=1) m[r] = fmaxf(m[r], __shfl_xor(m[r], o));
    }
    float sum[4] = {0,0,0,0};
    #pragma unroll
    for(int f=0;f<13;++f)
      #pragma unroll
      for(int r=0;r<4;++r){
        float e = ((keep[r]>>f)&1u) ? expf(sf[f][r]-m[r]) : 0.f;
        sf[f][r] = e; sum[r] += e;
      }
    #pragma unroll
    for(int r=0;r<4;++r){
      #pragma unroll
      for(int o=8;o>=1;o>>=1) sum[r] += __shfl_xor(sum[r], o);
      sum[r] = 1.f/sum[r];
    }
    // P -> LDS (A-fragment layout source), swizzled
    #pragma unroll
    for(int f=0;f<13;++f)
      #pragma unroll
      for(int r=0;r<4;++r){
        int ql = g*4+r;
        unsigned off = (unsigned)(ql*448 + (f*16+c16)*2) ^ ((unsigned)(ql&7)<<4);
        *(unsigned short*)((char*)Pl + pbase + off) = f2bf(sf[f][r]*sum[r]);
      }
    // O = P @ V : 4 col-tiles x 7 k-steps
    #pragma unroll
    for(int ct=0;ct<4;++ct){
      f32x4 oa = (f32x4){0.f,0.f,0.f,0.f};
      #pragma unroll
      for(int ks=0;ks<7;++ks){
        unsigned offa = (unsigned)(c16*448 + (ks*32+g*8)*2) ^ ((unsigned)(c16&7)<<4);
        short8 pa = *(const short8*)((char*)Pl + pbase + offa);
        short8 vb = *(const short8*)((char*)Vt + (size_t)(ct*16+c16)*440 + (ks*32+g*8)*2);
        oa = __builtin_amdgcn_mfma_f32_16x16x32_bf16(pa, vb, oa, 0,0,0);
      }
      #pragma unroll
      for(int r=0;r<4;++r){
        int qq = qb + g*4 + r;
        if(qq < N_)
          attn_out[((size_t)(b*N_+qq))*C_ + h*CH_ + ct*16 + c16] = f2bf(oa[r]);
      }
    }
  }
}

extern "C" void kernel_launch(void* const* d_in, const int* in_sizes, int n_in,
                              void* d_out, int out_size, void* d_ws, size_t ws_size,
                              hipStream_t stream){
  const float* x    =(const float*)d_in[0];
  const float* Wqkv =(const float*)d_in[1];
  const float* Wcq  =(const float*)d_in[2];
  const float* bcq  =(const float*)d_in[3];
  const float* Wck  =(const float*)d_in[4];
  const float* bck  =(const float*)d_in[5];
  const float* proj_n=(const float*)d_in[6];
  const float* proj_back_n=(const float*)d_in[7];
  const float* Wproj=(const float*)d_in[8];
  const float* bproj=(const float*)d_in[9];
  const float* g1=(const float*)d_in[10];
  const float* b1=(const float*)d_in[11];
  const float* g2=(const float*)d_in[12];
  const float* b2=(const float*)d_in[13];
  const float* W1=(const float*)d_in[14];
  const float* bfc1=(const float*)d_in[15];
  const float* W2=(const float*)d_in[16];
  const float* bfc2=(const float*)d_in[17];
  float* out=(float*)d_out;

  // ---- workspace layout (float slots). ~210 MB ----
  float* ws=(float*)d_ws;
  size_t off=0;
  unsigned short* hbuf = (unsigned short*)(ws+off); off += (size_t)12608*768/2;  // bf16, aliased as attn_out
  size_t qkv_off = off;
  float* qkv  = ws+off;        off += (size_t)12608*2304;
  float* qp   = ws+off;        off += (size_t)768*197*32;
  float* kp   = ws+off;        off += (size_t)768*197*32;
  float* kkb  = ws+off;        off += (size_t)768*32*24;
  float* coef = ws+off;        off += (size_t)768*196*24;
  float* basis= ws+off;        off += 4736;
  unsigned int* maskw=(unsigned int*)(ws+off); off += (size_t)768*197*8;
  unsigned short* WqkvT = (unsigned short*)(ws+off); off += (size_t)2304*768/2;
  unsigned short* WprojT= (unsigned short*)(ws+off); off += (size_t)768*768/2;
  unsigned short* W1T   = (unsigned short*)(ws+off); off += (size_t)3072*768/2;
  unsigned short* W2T   = (unsigned short*)(ws+off); off += (size_t)768*3072/2;
  unsigned short* attn_out = hbuf;                    // alias (hbuf dead after qkv GEMM)
  unsigned short* hidden = (unsigned short*)(ws+qkv_off); // alias (qkv dead after attn)
  float* x1 = out;

  // 0. weight transpose+bf16 conversions
  wtrans_kernel<<<dim3(72,24),256,0,stream>>>(Wqkv, WqkvT, 768, 2304);
  wtrans_kernel<<<dim3(24,24),256,0,stream>>>(Wproj, WprojT, 768, 768);
  wtrans_kernel<<<dim3(96,24),256,0,stream>>>(W1, W1T, 768, 3072);
  wtrans_kernel<<<dim3(24,96),256,0,stream>>>(W2, W2T, 3072, 768);
  // 1. h = LN(x) -> bf16
  ln_kernel<<<12608,256,0,stream>>>(x,g1,b1,hbuf);
  // 2. qkv = h @ Wqkv (f32 out)
  gemm_bf16<0,0,0><<<dim3(18,99),256,0,stream>>>(hbuf,WqkvT,nullptr,nullptr,qkv,12608,768,2304);
  // 3. qp, kp
  qkproj_kernel<<<18912,256,0,stream>>>(qkv,Wcq,bcq,qp,0);
  qkproj_kernel<<<18912,256,0,stream>>>(qkv,Wck,bck,kp,1);
  // 4. kk
  kk_kernel<<<768,768,0,stream>>>(kp,proj_n,kkb);
  // 5. basis
  basis_kernel<<<19,256,0,stream>>>(proj_back_n,basis);
  // 6. cheap + softmax + top8
  coef_kernel<<<37632,256,0,stream>>>(qp,kkb,coef);
  // 7. approx_attn + budget mask (compare-radix select, 4 rows/wave)
  mask4_kernel<<<9456,256,0,stream>>>(coef,basis,maskw);
  // 8. masked attention (MFMA, bf16 out, aliases hbuf)
  attn3_kernel<<<768,512,0,stream>>>(qkv,maskw,attn_out);
  // 9. x1 = x + attn_out @ Wproj + bproj   (x1 == d_out)
  gemm_bf16<0,1,0><<<dim3(6,99),256,0,stream>>>(attn_out,WprojT,bproj,x,x1,12608,768,768);
  // 10. h2 = LN(x1) -> bf16 (reuse hbuf)
  ln_kernel<<<12608,256,0,stream>>>(x1,g2,b2,hbuf);
  // 11. hidden = gelu(h2 @ W1 + bfc1) -> bf16 (aliases dead qkv)
  gemm_bf16<1,0,1><<<dim3(24,99),256,0,stream>>>(hbuf,W1T,bfc1,nullptr,hidden,12608,768,3072);
  // 12. out = x1 + hidden @ W2 + bfc2
  gemm_bf16<0,1,0><<<dim3(6,99),256,0,stream>>>(hidden,W2T,bfc2,x1,out,12608,3072,768);
}

// Round 8
// 865.329 us; speedup vs baseline: 5.2993x; 1.0735x over previous
//
#include <hip/hip_runtime.h>
#include <math.h>
#include <float.h>

#define B_ 64
#define N_ 197
#define C_ 768
#define H_ 12
#define CH_ 64
#define RC_ 32
#define RN_ 24

typedef __attribute__((ext_vector_type(8))) short short8;
typedef __attribute__((ext_vector_type(4))) float f32x4;
typedef __attribute__((address_space(3))) void  lds_void;
typedef __attribute__((address_space(1))) const void g_void;

__device__ __forceinline__ float warp_sum(float v){
  #pragma unroll
  for(int o=32;o>=1;o>>=1) v += __shfl_xor(v,o);
  return v;
}
__device__ __forceinline__ float warp_max(float v){
  #pragma unroll
  for(int o=32;o>=1;o>>=1) v = fmaxf(v,__shfl_xor(v,o));
  return v;
}
__device__ __forceinline__ unsigned short f2bf(float f){
  union{float f; unsigned u;} c; c.f = f;
  unsigned r = c.u + 0x7FFF + ((c.u>>16)&1);
  return (unsigned short)(r>>16);
}
__device__ __forceinline__ float bf2f(unsigned short u){
  union{unsigned u; float f;} c; c.u = ((unsigned)u)<<16; return c.f;
}

// ---------------- LayerNorm: one block per row of 768, bf16 out ----------------
__global__ __launch_bounds__(256) void ln_kernel(const float* __restrict__ x,
    const float* __restrict__ g, const float* __restrict__ bb, unsigned short* __restrict__ out){
  int r = blockIdx.x; int tid = threadIdx.x;
  const float* xr = x + (size_t)r*C_;
  float v0=xr[tid], v1=xr[tid+256], v2=xr[tid+512];
  __shared__ float red[8];
  float s = warp_sum(v0+v1+v2);
  if((tid&63)==0) red[tid>>6]=s;
  __syncthreads();
  float mu = (red[0]+red[1]+red[2]+red[3]) * (1.f/768.f);
  float d0=v0-mu,d1=v1-mu,d2=v2-mu;
  float s2 = warp_sum(d0*d0+d1*d1+d2*d2);
  if((tid&63)==0) red[4+(tid>>6)]=s2;
  __syncthreads();
  float rinv = rsqrtf((red[4]+red[5]+red[6]+red[7])*(1.f/768.f)+1e-5f);
  unsigned short* orow = out + (size_t)r*C_;
  orow[tid]     = f2bf(d0*rinv*g[tid]    +bb[tid]);
  orow[tid+256] = f2bf(d1*rinv*g[tid+256]+bb[tid+256]);
  orow[tid+512] = f2bf(d2*rinv*g[tid+512]+bb[tid+512]);
}

// ---------------- transpose+convert: in f32 [K][N] -> out bf16 [N][K] ----------------
__global__ __launch_bounds__(256) void wtrans_kernel(const float* __restrict__ in,
    unsigned short* __restrict__ out, int K, int N){
  __shared__ float tile[32][33];
  int n0 = blockIdx.x*32, k0 = blockIdx.y*32;
  int tx = threadIdx.x&31, ty = threadIdx.x>>5;   // ty: 8 rows per pass
  #pragma unroll
  for(int i=0;i<4;++i) tile[ty+8*i][tx] = in[(size_t)(k0+ty+8*i)*N + n0+tx];
  __syncthreads();
  #pragma unroll
  for(int i=0;i<4;++i) out[(size_t)(n0+ty+8*i)*K + k0+tx] = f2bf(tile[tx][ty+8*i]);
}

// ---------------- bf16 MFMA GEMM: Cout = act(A@W + bias) + resid ----------------
// A [M][K] bf16, WT [Nc][K] bf16. 128x128 tile, BK=32, 256 thr, 4 waves each 64x64.
template<int ACT, int RESID, int OUTBF16>
__global__ __launch_bounds__(256) void gemm_bf16(
    const unsigned short* __restrict__ A, const unsigned short* __restrict__ WT,
    const float* __restrict__ bias, const float* __restrict__ resid,
    void* __restrict__ Cout, int M, int K, int Nc){
  __shared__ unsigned short As[128*32];
  __shared__ unsigned short Bs[128*32];
  int tid = threadIdx.x, lane = tid&63, wid = tid>>6;
  int m0 = blockIdx.y*128, n0 = blockIdx.x*128;
  int wr = wid>>1, wc = wid&1;
  int lm = lane&15, lg = lane>>4;
  f32x4 acc[4][4] = {};
  for(int kt=0; kt<K; kt+=32){
    #pragma unroll
    for(int it=0; it<2; ++it){
      int ci = it*256 + tid;
      int row = ci>>2, kc=(ci&3)*8;
      int ar = m0+row; if(ar > M-1) ar = M-1;
      const unsigned short* ga = A  + (size_t)ar*K        + kt + kc;
      const unsigned short* gb = WT + (size_t)(n0+row)*K  + kt + kc;
      __builtin_amdgcn_global_load_lds((g_void*)ga, (lds_void*)(As + (it*256 + wid*64)*8), 16, 0, 0);
      __builtin_amdgcn_global_load_lds((g_void*)gb, (lds_void*)(Bs + (it*256 + wid*64)*8), 16, 0, 0);
    }
    __syncthreads();
    short8 af[4], bfv[4];
    #pragma unroll
    for(int i=0;i<4;++i){
      af[i]  = *(const short8*)(As + (64*wr + 16*i + lm)*32 + lg*8);
      bfv[i] = *(const short8*)(Bs + (64*wc + 16*i + lm)*32 + lg*8);
    }
    #pragma unroll
    for(int i=0;i<4;++i)
      #pragma unroll
      for(int j=0;j<4;++j)
        acc[i][j] = __builtin_amdgcn_mfma_f32_16x16x32_bf16(af[i], bfv[j], acc[i][j], 0,0,0);
    __syncthreads();
  }
  // epilogue: D row = (lane>>4)*4 + r, col = lane&15  (within each 16x16 frag)
  #pragma unroll
  for(int i=0;i<4;++i){
    #pragma unroll
    for(int j=0;j<4;++j){
      int gcol = n0 + 64*wc + 16*j + lm;
      float bv = bias ? bias[gcol] : 0.f;
      #pragma unroll
      for(int r=0;r<4;++r){
        int grow = m0 + 64*wr + 16*i + lg*4 + r;
        if(grow < M){
          float cv = acc[i][j][r] + bv;
          if(ACT==1){
            // tanh-form GELU: x - x*rcp(1+exp2(x*(c0 + c1*x^2)))
            // c0 = 0.7978845608*2*log2e, c1 = 0.7978845608*0.044715*2*log2e
            float xx = cv;
            float p = xx*fmaf(xx*xx, 0.10294517f, 2.3022079f);
            float q = exp2f(p);
            cv = xx - xx*__builtin_amdgcn_rcpf(1.0f+q);
          }
          if(RESID) cv += resid[(size_t)grow*Nc + gcol];
          if(OUTBF16) ((unsigned short*)Cout)[(size_t)grow*Nc+gcol] = f2bf(cv);
          else        ((float*)Cout)[(size_t)grow*Nc+gcol] = cv;
        }
      }
    }
  }
}

// ---------------- qp/kp: per (b,h,n) row, 64x32 matvec (bf16 qkv in) ----------------
__global__ __launch_bounds__(256) void qkproj_kernel(const unsigned short* __restrict__ qkv,
    const float* __restrict__ Wc, const float* __restrict__ bc,
    float* __restrict__ outp, int sel){
  int r = blockIdx.x*8 + (threadIdx.x>>5);
  int col = threadIdx.x&31;
  int b = r/(H_*N_); int rem = r%(H_*N_); int h = rem/N_; int n = rem%N_;
  const unsigned short* src = qkv + ((size_t)(b*N_+n)*3 + sel)*C_ + h*CH_;
  float acc = bc[col];
  #pragma unroll
  for(int ch=0;ch<CH_;++ch) acc += bf2f(src[ch])*Wc[ch*RC_+col];
  outp[(size_t)r*RC_+col]=acc;
}

// ---------------- kk[b,h,c,r] = sum_n kp[b,h,n,c]*proj_n[n,r] ----------------
__global__ __launch_bounds__(768) void kk_kernel(const float* __restrict__ kp,
    const float* __restrict__ proj_n, float* __restrict__ kkb){
  int bh = blockIdx.x;
  int t = threadIdx.x;            // 768 = 32*24
  int c = t/RN_, rr = t%RN_;
  const float* kpb = kp + (size_t)bh*N_*RC_;
  float acc = 0.f;
  for(int n=0;n<N_;++n) acc += kpb[n*RC_+c]*proj_n[n*RN_+rr];
  kkb[(size_t)bh*RC_*RN_ + c*RN_ + rr] = acc;
}

// ---------------- cheap + softmax + keep-top8: one wave per (b,h,n>=1) ----------------
__global__ __launch_bounds__(256) void coef_kernel(const float* __restrict__ qp,
    const float* __restrict__ kkb, float* __restrict__ coef){
  int wid = blockIdx.x*4 + (threadIdx.x>>6);   // (b*H+h)*196 + (n-1)
  int lane = threadIdx.x&63;
  int b = wid/(H_*196); int rem = wid%(H_*196); int h = rem/196; int n = rem%196+1;
  int bh = b*H_+h;
  const float* qpr = qp + ((size_t)bh*N_ + n)*RC_;
  const float* kkp = kkb + (size_t)bh*RC_*RN_;
  float val = -INFINITY;
  if(lane<RN_){
    float acc=0.f;
    #pragma unroll
    for(int c=0;c<RC_;++c) acc += qpr[c]*kkp[c*RN_+lane];
    val = acc * 0.28867513459481287f;   // H^-0.5
  }
  float m = warp_max(val);
  float e = (lane<RN_)? expf(val-m):0.f;
  float ssum = warp_sum(e);
  float p = e/ssum;
  float myv = (lane<RN_)? p : -1.f;
  int cnt=0;
  #pragma unroll
  for(int j=0;j<RN_;++j){ float vj = __shfl(myv, j); cnt += (vj>myv)?1:0; }
  if(lane<RN_) coef[(size_t)wid*RN_+lane] = (cnt<=7)? p : 0.f;
}

// ---------------- basis[r][j] = thresh(|proj_back_n[j][r]|) ----------------
__global__ __launch_bounds__(256) void basis_kernel(const float* __restrict__ pb,
    float* __restrict__ basis){
  int t = blockIdx.x*256 + threadIdx.x;
  if(t < RN_*N_){
    int r = t/N_, j = t%N_;
    float v = fabsf(pb[(size_t)j*RN_ + r]);
    basis[t] = (v > 0.02f) ? v : 0.f;
  }
}

// ---------------- mask v4: one WAVE per 4 rows; ballot compare-radix top-50 ----------------
// Bs layout: element e of basis row r stored at Bs[r*256 + (e&63)*4 + (e>>6)]
// -> lane reads its 4 elements {g2*64+lane} with ONE ds_read_b128.
// Select: greedy max t with count(u >= t) >= 50 (4 v_cmp_ge vs SGPR per bit).
__global__ __launch_bounds__(256) void mask4_kernel(const float* __restrict__ coef,
    const float* __restrict__ basis, unsigned int* __restrict__ maskw){
  __shared__ float Bs[24*256];
  int tid = threadIdx.x, lane = tid&63, wv = tid>>6;
  for(int idx = tid; idx < 24*256; idx += 256){
    int r = idx>>8, q = idx&255;
    int e = ((q&3)<<6) | (q>>2);          // inverse of dest mapping
    Bs[idx] = (e < N_) ? basis[r*N_ + e] : 0.f;
  }
  __syncthreads();
  int rowbase = blockIdx.x*16 + wv*4;     // 9456 blocks * 16 rows = 151296
  #pragma unroll
  for(int j=0;j<4;++j){
    int row = rowbase + j;                // (b*H+h)*197 + qi
    int qi = row % N_; int bh = row / N_;
    if(qi==0){
      if(lane<8){
        unsigned v = (lane<6)?0xFFFFFFFFu:((lane==6)?0x1Fu:0u);
        maskw[(size_t)row*8+lane]=v;
      }
      continue;
    }
    float cfv = (lane<24) ? coef[((size_t)bh*196 + (qi-1))*24 + lane] : 0.f;
    unsigned long long nz = __ballot(cfv != 0.f);
    float4 av = make_float4(0.f,0.f,0.f,0.f);
    while(nz){
      int r = __ffsll((unsigned long long)nz) - 1;
      nz &= nz - 1;
      float c = __uint_as_float(__builtin_amdgcn_readlane(__float_as_uint(cfv), r));
      float4 bv = *(const float4*)&Bs[r*256 + lane*4];
      av.x += c*bv.x; av.y += c*bv.y; av.z += c*bv.z; av.w += c*bv.w;
    }
    unsigned u0=__float_as_uint(av.x), u1=__float_as_uint(av.y);
    unsigned u2=__float_as_uint(av.z), u3=__float_as_uint(av.w);
    // greedy threshold: largest t with count(u >= t) >= 50
    unsigned prefix = 0;
    #pragma unroll
    for(int bit=30; bit>=0; --bit){
      unsigned t = prefix | (1u<<bit);
      int c = __popcll(__ballot(u0 >= t)) + __popcll(__ballot(u1 >= t))
            + __popcll(__ballot(u2 >= t)) + __popcll(__ballot(u3 >= t));
      if(c >= 50) prefix = t;
    }
    // keep = a >= t (exact 50th-largest); guard pads (elem>=197)
    unsigned uu[4] = {u0,u1,u2,u3};
    #pragma unroll
    for(int r=0;r<4;++r){
      bool valid = (r<3) | (lane<5);
      bool keep = valid && (uu[r] >= prefix);
      unsigned long long bal = __ballot(keep);
      if(lane==0){
        maskw[(size_t)row*8 + 2*r]   = (unsigned)(bal & 0xFFFFFFFFull);
        maskw[(size_t)row*8 + 2*r+1] = (unsigned)(bal>>32);
      }
    }
  }
}

// ---------------- masked attention v3: MFMA flash-style, one block per (b,h) ----------------
// K in LDS [208][64] bf16, rows 128B, XOR-swizzled (byte ^= (k&7)<<4).
// V in LDS transposed [64][220] bf16 (rows 440B: 2-way-free frag reads).
// P round-trip through LDS [16][224] per wave (448B rows, XOR-swizzled).
// qkv input is bf16: staging is pure copies; ATTN_SCALE applied post-MFMA.
__global__ __launch_bounds__(512) void attn3_kernel(const unsigned short* __restrict__ qkv,
    const unsigned int* __restrict__ maskw, unsigned short* __restrict__ attn_out){
  int bh = blockIdx.x; int b = bh/H_, h = bh%H_;
  int tid = threadIdx.x, lane = tid&63, wv = tid>>6;
  int g = lane>>4, c16 = lane&15;
  __shared__ unsigned short Kb[208*64];     // 26.6 KB
  __shared__ unsigned short Vt[64*220];     // 28.2 KB
  __shared__ unsigned short Pl[8*16*224];   // 57.3 KB
  __shared__ unsigned int   Ml[8][16][8];   // 4 KB
  const unsigned short* Kbase = qkv + ((size_t)(b*N_)*3 + 1)*C_ + h*CH_;
  const unsigned short* Vbase = qkv + ((size_t)(b*N_)*3 + 2)*C_ + h*CH_;
  // stage K rows 0..207 (zero-pad >=197), u32 copies, swizzled
  for(int idx = tid; idx < 208*32; idx += 512){
    int k = idx>>5, cp = idx&31;
    unsigned pk = 0;
    if(k < N_) pk = *(const unsigned*)(Kbase + (size_t)k*3*C_ + cp*2);
    unsigned off = (unsigned)(k*128 + cp*4) ^ ((unsigned)(k&7)<<4);
    *(unsigned*)((char*)Kb + off) = pk;
  }
  // stage V transposed, zero-pad k>=197 (prevents NaN*0 in PV)
  for(int idx = tid; idx < 64*110; idx += 512){
    int kp = idx>>6, c = idx&63;
    int k0 = kp*2, k1 = kp*2+1;
    unsigned v0 = (k0<N_) ? Vbase[(size_t)k0*3*C_ + c] : 0;
    unsigned v1 = (k1<N_) ? Vbase[(size_t)k1*3*C_ + c] : 0;
    *(unsigned*)((char*)Vt + c*440 + kp*4) = v0 | (v1<<16);
  }
  __syncthreads();
  size_t pbase = (size_t)wv*16*448;
  // zero P tail (k=208..223) once per wave
  for(int i=lane;i<128;i+=64){
    int ql = i>>3; int kk = 208 + (i&7)*2;
    unsigned off = (unsigned)(ql*448 + kk*2) ^ ((unsigned)(ql&7)<<4);
    *(unsigned*)((char*)Pl + pbase + off) = 0u;
  }
  for(int t = wv; t < 13; t += 8){
    int qb = t*16;
    // mask tile -> LDS (per-wave region, no block sync needed)
    for(int i = lane; i < 128; i += 64){
      int row = i>>3, word = i&7;
      int qr = qb+row; if(qr>196) qr=196;
      Ml[wv][row][word] = maskw[(size_t)(bh*N_+qr)*8 + word];
    }
    // Q A-frags: direct 16B bf16 loads (scale deferred)
    int qrow = qb + c16; if(qrow>196) qrow=196;
    const unsigned short* Qr = qkv + ((size_t)(b*N_+qrow)*3)*C_ + h*CH_ + g*8;
    short8 af[2];
    af[0] = *(const short8*)(Qr);
    af[1] = *(const short8*)(Qr + 32);
    // S = Q @ K^T : 13 frags x 2 k-steps
    f32x4 sf[13];
    #pragma unroll
    for(int f=0;f<13;++f){
      sf[f] = (f32x4){0.f,0.f,0.f,0.f};
      #pragma unroll
      for(int s=0;s<2;++s){
        int row = f*16 + c16;
        unsigned off = (unsigned)(row*128 + s*64 + g*16) ^ ((unsigned)(row&7)<<4);
        short8 bfr = *(const short8*)((char*)Kb + off);
        sf[f] = __builtin_amdgcn_mfma_f32_16x16x32_bf16(af[s], bfr, sf[f], 0,0,0);
      }
      sf[f][0]*=0.125f; sf[f][1]*=0.125f; sf[f][2]*=0.125f; sf[f][3]*=0.125f;
    }
    // masked softmax (row = q = g*4+r across 16-lane groups; col k = lane&15)
    unsigned keep[4] = {0,0,0,0};
    float m[4] = {-FLT_MAX,-FLT_MAX,-FLT_MAX,-FLT_MAX};
    #pragma unroll
    for(int f=0;f<13;++f)
      #pragma unroll
      for(int r=0;r<4;++r){
        unsigned bit = (Ml[wv][g*4+r][f>>1] >> ((f&1)*16 + c16)) & 1u;
        keep[r] |= bit<<f;
        if(bit) m[r] = fmaxf(m[r], sf[f][r]);
      }
    #pragma unroll
    for(int r=0;r<4;++r){
      #pragma unroll
      for(int o=8;o>=1;o>>=1) m[r] = fmaxf(m[r], __shfl_xor(m[r], o));
    }
    float sum[4] = {0,0,0,0};
    #pragma unroll
    for(int f=0;f<13;++f)
      #pragma unroll
      for(int r=0;r<4;++r){
        float e = ((keep[r]>>f)&1u) ? expf(sf[f][r]-m[r]) : 0.f;
        sf[f][r] = e; sum[r] += e;
      }
    #pragma unroll
    for(int r=0;r<4;++r){
      #pragma unroll
      for(int o=8;o>=1;o>>=1) sum[r] += __shfl_xor(sum[r], o);
      sum[r] = 1.f/sum[r];
    }
    // P -> LDS (A-fragment layout source), swizzled
    #pragma unroll
    for(int f=0;f<13;++f)
      #pragma unroll
      for(int r=0;r<4;++r){
        int ql = g*4+r;
        unsigned off = (unsigned)(ql*448 + (f*16+c16)*2) ^ ((unsigned)(ql&7)<<4);
        *(unsigned short*)((char*)Pl + pbase + off) = f2bf(sf[f][r]*sum[r]);
      }
    // O = P @ V : 4 col-tiles x 7 k-steps
    #pragma unroll
    for(int ct=0;ct<4;++ct){
      f32x4 oa = (f32x4){0.f,0.f,0.f,0.f};
      #pragma unroll
      for(int ks=0;ks<7;++ks){
        unsigned offa = (unsigned)(c16*448 + (ks*32+g*8)*2) ^ ((unsigned)(c16&7)<<4);
        short8 pa = *(const short8*)((char*)Pl + pbase + offa);
        short8 vb = *(const short8*)((char*)Vt + (size_t)(ct*16+c16)*440 + (ks*32+g*8)*2);
        oa = __builtin_amdgcn_mfma_f32_16x16x32_bf16(pa, vb, oa, 0,0,0);
      }
      #pragma unroll
      for(int r=0;r<4;++r){
        int qq = qb + g*4 + r;
        if(qq < N_)
          attn_out[((size_t)(b*N_+qq))*C_ + h*CH_ + ct*16 + c16] = f2bf(oa[r]);
      }
    }
  }
}

extern "C" void kernel_launch(void* const* d_in, const int* in_sizes, int n_in,
                              void* d_out, int out_size, void* d_ws, size_t ws_size,
                              hipStream_t stream){
  const float* x    =(const float*)d_in[0];
  const float* Wqkv =(const float*)d_in[1];
  const float* Wcq  =(const float*)d_in[2];
  const float* bcq  =(const float*)d_in[3];
  const float* Wck  =(const float*)d_in[4];
  const float* bck  =(const float*)d_in[5];
  const float* proj_n=(const float*)d_in[6];
  const float* proj_back_n=(const float*)d_in[7];
  const float* Wproj=(const float*)d_in[8];
  const float* bproj=(const float*)d_in[9];
  const float* g1=(const float*)d_in[10];
  const float* b1=(const float*)d_in[11];
  const float* g2=(const float*)d_in[12];
  const float* b2=(const float*)d_in[13];
  const float* W1=(const float*)d_in[14];
  const float* bfc1=(const float*)d_in[15];
  const float* W2=(const float*)d_in[16];
  const float* bfc2=(const float*)d_in[17];
  float* out=(float*)d_out;

  // ---- workspace layout (float slots). ~152 MB ----
  float* ws=(float*)d_ws;
  size_t off=0;
  unsigned short* hbuf = (unsigned short*)(ws+off); off += (size_t)12608*768/2;  // bf16, aliased as attn_out
  size_t qkv_off = off;
  unsigned short* qkv = (unsigned short*)(ws+off); off += (size_t)12608*2304/2; // bf16 now
  float* qp   = ws+off;        off += (size_t)768*197*32;
  float* kp   = ws+off;        off += (size_t)768*197*32;
  float* kkb  = ws+off;        off += (size_t)768*32*24;
  float* coef = ws+off;        off += (size_t)768*196*24;
  float* basis= ws+off;        off += 4736;
  unsigned int* maskw=(unsigned int*)(ws+off); off += (size_t)768*197*8;
  unsigned short* WqkvT = (unsigned short*)(ws+off); off += (size_t)2304*768/2;
  unsigned short* WprojT= (unsigned short*)(ws+off); off += (size_t)768*768/2;
  unsigned short* W1T   = (unsigned short*)(ws+off); off += (size_t)3072*768/2;
  unsigned short* W2T   = (unsigned short*)(ws+off); off += (size_t)768*3072/2;
  unsigned short* attn_out = hbuf;                    // alias (hbuf dead after qkv GEMM)
  // hidden (12608*3072 bf16 = 19.4M float-slots) aliases qkv(14.5M)+qp(4.8M), both dead by MLP
  unsigned short* hidden = (unsigned short*)(ws+qkv_off);
  float* x1 = out;

  // 0. weight transpose+bf16 conversions
  wtrans_kernel<<<dim3(72,24),256,0,stream>>>(Wqkv, WqkvT, 768, 2304);
  wtrans_kernel<<<dim3(24,24),256,0,stream>>>(Wproj, WprojT, 768, 768);
  wtrans_kernel<<<dim3(96,24),256,0,stream>>>(W1, W1T, 768, 3072);
  wtrans_kernel<<<dim3(24,96),256,0,stream>>>(W2, W2T, 3072, 768);
  // 1. h = LN(x) -> bf16
  ln_kernel<<<12608,256,0,stream>>>(x,g1,b1,hbuf);
  // 2. qkv = h @ Wqkv (bf16 out)
  gemm_bf16<0,0,1><<<dim3(18,99),256,0,stream>>>(hbuf,WqkvT,nullptr,nullptr,qkv,12608,768,2304);
  // 3. qp, kp (bf16 in, f32 out)
  qkproj_kernel<<<18912,256,0,stream>>>(qkv,Wcq,bcq,qp,0);
  qkproj_kernel<<<18912,256,0,stream>>>(qkv,Wck,bck,kp,1);
  // 4. kk
  kk_kernel<<<768,768,0,stream>>>(kp,proj_n,kkb);
  // 5. basis
  basis_kernel<<<19,256,0,stream>>>(proj_back_n,basis);
  // 6. cheap + softmax + top8
  coef_kernel<<<37632,256,0,stream>>>(qp,kkb,coef);
  // 7. approx_attn + budget mask (compare-radix select, 4 rows/wave)
  mask4_kernel<<<9456,256,0,stream>>>(coef,basis,maskw);
  // 8. masked attention (MFMA, bf16 in/out, aliases hbuf)
  attn3_kernel<<<768,512,0,stream>>>(qkv,maskw,attn_out);
  // 9. x1 = x + attn_out @ Wproj + bproj   (x1 == d_out)
  gemm_bf16<0,1,0><<<dim3(6,99),256,0,stream>>>(attn_out,WprojT,bproj,x,x1,12608,768,768);
  // 10. h2 = LN(x1) -> bf16 (reuse hbuf)
  ln_kernel<<<12608,256,0,stream>>>(x1,g2,b2,hbuf);
  // 11. hidden = gelu(h2 @ W1 + bfc1) -> bf16 (aliases dead qkv+qp)
  gemm_bf16<1,0,1><<<dim3(24,99),256,0,stream>>>(hbuf,W1T,bfc1,nullptr,hidden,12608,768,3072);
  // 12. out = x1 + hidden @ W2 + bfc2
  gemm_bf16<0,1,0><<<dim3(6,99),256,0,stream>>>(hidden,W2T,bfc2,x1,out,12608,3072,768);
}

// Round 9
// 842.168 us; speedup vs baseline: 5.4451x; 1.0275x over previous
//
#include <hip/hip_runtime.h>
#include <math.h>
#include <float.h>

#define B_ 64
#define N_ 197
#define C_ 768
#define H_ 12
#define CH_ 64
#define RC_ 32
#define RN_ 24

typedef __attribute__((ext_vector_type(8))) short short8;
typedef __attribute__((ext_vector_type(4))) float f32x4;
typedef __attribute__((address_space(3))) void  lds_void;
typedef __attribute__((address_space(1))) const void g_void;

__device__ __forceinline__ float warp_sum(float v){
  #pragma unroll
  for(int o=32;o>=1;o>>=1) v += __shfl_xor(v,o);
  return v;
}
__device__ __forceinline__ float warp_max(float v){
  #pragma unroll
  for(int o=32;o>=1;o>>=1) v = fmaxf(v,__shfl_xor(v,o));
  return v;
}
__device__ __forceinline__ unsigned short f2bf(float f){
  union{float f; unsigned u;} c; c.f = f;
  unsigned r = c.u + 0x7FFF + ((c.u>>16)&1);
  return (unsigned short)(r>>16);
}
__device__ __forceinline__ float bf2f(unsigned short u){
  union{unsigned u; float f;} c; c.u = ((unsigned)u)<<16; return c.f;
}

// ---------------- LayerNorm: one block per row of 768, bf16 out ----------------
__global__ __launch_bounds__(256) void ln_kernel(const float* __restrict__ x,
    const float* __restrict__ g, const float* __restrict__ bb, unsigned short* __restrict__ out){
  int r = blockIdx.x; int tid = threadIdx.x;
  const float* xr = x + (size_t)r*C_;
  float v0=xr[tid], v1=xr[tid+256], v2=xr[tid+512];
  __shared__ float red[8];
  float s = warp_sum(v0+v1+v2);
  if((tid&63)==0) red[tid>>6]=s;
  __syncthreads();
  float mu = (red[0]+red[1]+red[2]+red[3]) * (1.f/768.f);
  float d0=v0-mu,d1=v1-mu,d2=v2-mu;
  float s2 = warp_sum(d0*d0+d1*d1+d2*d2);
  if((tid&63)==0) red[4+(tid>>6)]=s2;
  __syncthreads();
  float rinv = rsqrtf((red[4]+red[5]+red[6]+red[7])*(1.f/768.f)+1e-5f);
  unsigned short* orow = out + (size_t)r*C_;
  orow[tid]     = f2bf(d0*rinv*g[tid]    +bb[tid]);
  orow[tid+256] = f2bf(d1*rinv*g[tid+256]+bb[tid+256]);
  orow[tid+512] = f2bf(d2*rinv*g[tid+512]+bb[tid+512]);
}

// ---------------- transpose+convert: in f32 [K][N] -> out bf16 [N][K] ----------------
__global__ __launch_bounds__(256) void wtrans_kernel(const float* __restrict__ in,
    unsigned short* __restrict__ out, int K, int N){
  __shared__ float tile[32][33];
  int n0 = blockIdx.x*32, k0 = blockIdx.y*32;
  int tx = threadIdx.x&31, ty = threadIdx.x>>5;   // ty: 8 rows per pass
  #pragma unroll
  for(int i=0;i<4;++i) tile[ty+8*i][tx] = in[(size_t)(k0+ty+8*i)*N + n0+tx];
  __syncthreads();
  #pragma unroll
  for(int i=0;i<4;++i) out[(size_t)(n0+ty+8*i)*K + k0+tx] = f2bf(tile[tx][ty+8*i]);
}

// ---------------- bf16 MFMA GEMM, double-buffered (T3-minimum 2-phase) ----------------
// A [M][K] bf16, WT [Nc][K] bf16. 128x128 tile, BK=32, 256 thr, 4 waves each 64x64.
// Per iter: issue next tile's global_load_lds into idle buf, then compute current.
template<int ACT, int RESID, int OUTBF16>
__global__ __launch_bounds__(256) void gemm_bf16(
    const unsigned short* __restrict__ A, const unsigned short* __restrict__ WT,
    const float* __restrict__ bias, const float* __restrict__ resid,
    void* __restrict__ Cout, int M, int K, int Nc){
  __shared__ unsigned short As[2*128*32];
  __shared__ unsigned short Bs[2*128*32];
  int tid = threadIdx.x, lane = tid&63, wid = tid>>6;
  int m0 = blockIdx.y*128, n0 = blockIdx.x*128;
  int wr = wid>>1, wc = wid&1;
  int lm = lane&15, lg = lane>>4;
  // per-thread staging addresses (2 chunks of 256 threads each cover 128 rows x 32 cols)
  int row0 = tid>>2,         kc0 = (tid&3)*8;
  int row1 = (256+tid)>>2,   kc1 = (tid&3)*8;
  int ar0 = m0+row0; if(ar0 > M-1) ar0 = M-1;
  int ar1 = m0+row1; if(ar1 > M-1) ar1 = M-1;
  const unsigned short* gA0 = A  + (size_t)ar0*K + kc0;
  const unsigned short* gA1 = A  + (size_t)ar1*K + kc1;
  const unsigned short* gB0 = WT + (size_t)(n0+row0)*K + kc0;
  const unsigned short* gB1 = WT + (size_t)(n0+row1)*K + kc1;
  unsigned short* lA0 = As + (wid*64)*8;          // +buf*4096, lane offset implicit
  unsigned short* lA1 = As + (256 + wid*64)*8;
  unsigned short* lB0 = Bs + (wid*64)*8;
  unsigned short* lB1 = Bs + (256 + wid*64)*8;

#define STAGE_(buf, kt) do{ \
    __builtin_amdgcn_global_load_lds((g_void*)(gA0 + (kt)), (lds_void*)(lA0 + (buf)*4096), 16, 0, 0); \
    __builtin_amdgcn_global_load_lds((g_void*)(gB0 + (kt)), (lds_void*)(lB0 + (buf)*4096), 16, 0, 0); \
    __builtin_amdgcn_global_load_lds((g_void*)(gA1 + (kt)), (lds_void*)(lA1 + (buf)*4096), 16, 0, 0); \
    __builtin_amdgcn_global_load_lds((g_void*)(gB1 + (kt)), (lds_void*)(lB1 + (buf)*4096), 16, 0, 0); \
  }while(0)

  f32x4 acc[4][4] = {};
  const int nt = K/32;              // even for all our shapes (24 or 96)
  STAGE_(0, 0);
  __syncthreads();                  // tile 0 ready in buf0
  for(int t=0; t<nt; t+=2){
    // ---- compute tile t (buf0), prefetch tile t+1 (buf1) ----
    STAGE_(1, (t+1)*32);
    {
      short8 af[4], bfv[4];
      #pragma unroll
      for(int i=0;i<4;++i){
        af[i]  = *(const short8*)(As + (64*wr + 16*i + lm)*32 + lg*8);
        bfv[i] = *(const short8*)(Bs + (64*wc + 16*i + lm)*32 + lg*8);
      }
      #pragma unroll
      for(int i=0;i<4;++i)
        #pragma unroll
        for(int j=0;j<4;++j)
          acc[i][j] = __builtin_amdgcn_mfma_f32_16x16x32_bf16(af[i], bfv[j], acc[i][j], 0,0,0);
    }
    __syncthreads();                // tile t+1 ready in buf1
    // ---- compute tile t+1 (buf1), prefetch tile t+2 (buf0) ----
    if(t+2 < nt) STAGE_(0, (t+2)*32);
    {
      short8 af[4], bfv[4];
      #pragma unroll
      for(int i=0;i<4;++i){
        af[i]  = *(const short8*)(As + 4096 + (64*wr + 16*i + lm)*32 + lg*8);
        bfv[i] = *(const short8*)(Bs + 4096 + (64*wc + 16*i + lm)*32 + lg*8);
      }
      #pragma unroll
      for(int i=0;i<4;++i)
        #pragma unroll
        for(int j=0;j<4;++j)
          acc[i][j] = __builtin_amdgcn_mfma_f32_16x16x32_bf16(af[i], bfv[j], acc[i][j], 0,0,0);
    }
    __syncthreads();                // tile t+2 ready in buf0
  }
#undef STAGE_
  // epilogue: D row = (lane>>4)*4 + r, col = lane&15  (within each 16x16 frag)
  #pragma unroll
  for(int i=0;i<4;++i){
    #pragma unroll
    for(int j=0;j<4;++j){
      int gcol = n0 + 64*wc + 16*j + lm;
      float bv = bias ? bias[gcol] : 0.f;
      #pragma unroll
      for(int r=0;r<4;++r){
        int grow = m0 + 64*wr + 16*i + lg*4 + r;
        if(grow < M){
          float cv = acc[i][j][r] + bv;
          if(ACT==1){
            // tanh-form GELU via exp2
            float xx = cv;
            float p = xx*fmaf(xx*xx, 0.10294517f, 2.3022079f);
            float q = exp2f(p);
            cv = xx - xx*__builtin_amdgcn_rcpf(1.0f+q);
          }
          if(RESID) cv += resid[(size_t)grow*Nc + gcol];
          if(OUTBF16) ((unsigned short*)Cout)[(size_t)grow*Nc+gcol] = f2bf(cv);
          else        ((float*)Cout)[(size_t)grow*Nc+gcol] = cv;
        }
      }
    }
  }
}

// ---------------- qp/kp: per (b,h,n) row, 64x32 matvec (bf16 qkv in) ----------------
__global__ __launch_bounds__(256) void qkproj_kernel(const unsigned short* __restrict__ qkv,
    const float* __restrict__ Wc, const float* __restrict__ bc,
    float* __restrict__ outp, int sel){
  int r = blockIdx.x*8 + (threadIdx.x>>5);
  int col = threadIdx.x&31;
  int b = r/(H_*N_); int rem = r%(H_*N_); int h = rem/N_; int n = rem%N_;
  const unsigned short* src = qkv + ((size_t)(b*N_+n)*3 + sel)*C_ + h*CH_;
  float acc = bc[col];
  #pragma unroll
  for(int ch=0;ch<CH_;++ch) acc += bf2f(src[ch])*Wc[ch*RC_+col];
  outp[(size_t)r*RC_+col]=acc;
}

// ---------------- kk[b,h,c,r] = sum_n kp[b,h,n,c]*proj_n[n,r] ----------------
__global__ __launch_bounds__(768) void kk_kernel(const float* __restrict__ kp,
    const float* __restrict__ proj_n, float* __restrict__ kkb){
  int bh = blockIdx.x;
  int t = threadIdx.x;            // 768 = 32*24
  int c = t/RN_, rr = t%RN_;
  const float* kpb = kp + (size_t)bh*N_*RC_;
  float acc = 0.f;
  for(int n=0;n<N_;++n) acc += kpb[n*RC_+c]*proj_n[n*RN_+rr];
  kkb[(size_t)bh*RC_*RN_ + c*RN_ + rr] = acc;
}

// ---------------- cheap + softmax + keep-top8: one wave per (b,h,n>=1) ----------------
__global__ __launch_bounds__(256) void coef_kernel(const float* __restrict__ qp,
    const float* __restrict__ kkb, float* __restrict__ coef){
  int wid = blockIdx.x*4 + (threadIdx.x>>6);   // (b*H+h)*196 + (n-1)
  int lane = threadIdx.x&63;
  int b = wid/(H_*196); int rem = wid%(H_*196); int h = rem/196; int n = rem%196+1;
  int bh = b*H_+h;
  const float* qpr = qp + ((size_t)bh*N_ + n)*RC_;
  const float* kkp = kkb + (size_t)bh*RC_*RN_;
  float val = -INFINITY;
  if(lane<RN_){
    float acc=0.f;
    #pragma unroll
    for(int c=0;c<RC_;++c) acc += qpr[c]*kkp[c*RN_+lane];
    val = acc * 0.28867513459481287f;   // H^-0.5
  }
  float m = warp_max(val);
  float e = (lane<RN_)? expf(val-m):0.f;
  float ssum = warp_sum(e);
  float p = e/ssum;
  float myv = (lane<RN_)? p : -1.f;
  int cnt=0;
  #pragma unroll
  for(int j=0;j<RN_;++j){ float vj = __shfl(myv, j); cnt += (vj>myv)?1:0; }
  if(lane<RN_) coef[(size_t)wid*RN_+lane] = (cnt<=7)? p : 0.f;
}

// ---------------- basis[r][j] = thresh(|proj_back_n[j][r]|) ----------------
__global__ __launch_bounds__(256) void basis_kernel(const float* __restrict__ pb,
    float* __restrict__ basis){
  int t = blockIdx.x*256 + threadIdx.x;
  if(t < RN_*N_){
    int r = t/N_, j = t%N_;
    float v = fabsf(pb[(size_t)j*RN_ + r]);
    basis[t] = (v > 0.02f) ? v : 0.f;
  }
}

// ---------------- mask v4: one WAVE per 4 rows; ballot compare-radix top-50 ----------------
__global__ __launch_bounds__(256) void mask4_kernel(const float* __restrict__ coef,
    const float* __restrict__ basis, unsigned int* __restrict__ maskw){
  __shared__ float Bs[24*256];
  int tid = threadIdx.x, lane = tid&63, wv = tid>>6;
  for(int idx = tid; idx < 24*256; idx += 256){
    int r = idx>>8, q = idx&255;
    int e = ((q&3)<<6) | (q>>2);          // inverse of dest mapping
    Bs[idx] = (e < N_) ? basis[r*N_ + e] : 0.f;
  }
  __syncthreads();
  int rowbase = blockIdx.x*16 + wv*4;     // 9456 blocks * 16 rows = 151296
  #pragma unroll
  for(int j=0;j<4;++j){
    int row = rowbase + j;                // (b*H+h)*197 + qi
    int qi = row % N_; int bh = row / N_;
    if(qi==0){
      if(lane<8){
        unsigned v = (lane<6)?0xFFFFFFFFu:((lane==6)?0x1Fu:0u);
        maskw[(size_t)row*8+lane]=v;
      }
      continue;
    }
    float cfv = (lane<24) ? coef[((size_t)bh*196 + (qi-1))*24 + lane] : 0.f;
    unsigned long long nz = __ballot(cfv != 0.f);
    float4 av = make_float4(0.f,0.f,0.f,0.f);
    while(nz){
      int r = __ffsll((unsigned long long)nz) - 1;
      nz &= nz - 1;
      float c = __uint_as_float(__builtin_amdgcn_readlane(__float_as_uint(cfv), r));
      float4 bv = *(const float4*)&Bs[r*256 + lane*4];
      av.x += c*bv.x; av.y += c*bv.y; av.z += c*bv.z; av.w += c*bv.w;
    }
    unsigned u0=__float_as_uint(av.x), u1=__float_as_uint(av.y);
    unsigned u2=__float_as_uint(av.z), u3=__float_as_uint(av.w);
    // greedy threshold: largest t with count(u >= t) >= 50
    unsigned prefix = 0;
    #pragma unroll
    for(int bit=30; bit>=0; --bit){
      unsigned t = prefix | (1u<<bit);
      int c = __popcll(__ballot(u0 >= t)) + __popcll(__ballot(u1 >= t))
            + __popcll(__ballot(u2 >= t)) + __popcll(__ballot(u3 >= t));
      if(c >= 50) prefix = t;
    }
    unsigned uu[4] = {u0,u1,u2,u3};
    #pragma unroll
    for(int r=0;r<4;++r){
      bool valid = (r<3) | (lane<5);
      bool keep = valid && (uu[r] >= prefix);
      unsigned long long bal = __ballot(keep);
      if(lane==0){
        maskw[(size_t)row*8 + 2*r]   = (unsigned)(bal & 0xFFFFFFFFull);
        maskw[(size_t)row*8 + 2*r+1] = (unsigned)(bal>>32);
      }
    }
  }
}

// ---------------- masked attention v3: MFMA flash-style, one block per (b,h) ----------------
__global__ __launch_bounds__(512) void attn3_kernel(const unsigned short* __restrict__ qkv,
    const unsigned int* __restrict__ maskw, unsigned short* __restrict__ attn_out){
  int bh = blockIdx.x; int b = bh/H_, h = bh%H_;
  int tid = threadIdx.x, lane = tid&63, wv = tid>>6;
  int g = lane>>4, c16 = lane&15;
  __shared__ unsigned short Kb[208*64];     // 26.6 KB
  __shared__ unsigned short Vt[64*220];     // 28.2 KB
  __shared__ unsigned short Pl[8*16*224];   // 57.3 KB
  __shared__ unsigned int   Ml[8][16][8];   // 4 KB
  const unsigned short* Kbase = qkv + ((size_t)(b*N_)*3 + 1)*C_ + h*CH_;
  const unsigned short* Vbase = qkv + ((size_t)(b*N_)*3 + 2)*C_ + h*CH_;
  for(int idx = tid; idx < 208*32; idx += 512){
    int k = idx>>5, cp = idx&31;
    unsigned pk = 0;
    if(k < N_) pk = *(const unsigned*)(Kbase + (size_t)k*3*C_ + cp*2);
    unsigned off = (unsigned)(k*128 + cp*4) ^ ((unsigned)(k&7)<<4);
    *(unsigned*)((char*)Kb + off) = pk;
  }
  for(int idx = tid; idx < 64*110; idx += 512){
    int kp = idx>>6, c = idx&63;
    int k0 = kp*2, k1 = kp*2+1;
    unsigned v0 = (k0<N_) ? Vbase[(size_t)k0*3*C_ + c] : 0;
    unsigned v1 = (k1<N_) ? Vbase[(size_t)k1*3*C_ + c] : 0;
    *(unsigned*)((char*)Vt + c*440 + kp*4) = v0 | (v1<<16);
  }
  __syncthreads();
  size_t pbase = (size_t)wv*16*448;
  for(int i=lane;i<128;i+=64){
    int ql = i>>3; int kk = 208 + (i&7)*2;
    unsigned off = (unsigned)(ql*448 + kk*2) ^ ((unsigned)(ql&7)<<4);
    *(unsigned*)((char*)Pl + pbase + off) = 0u;
  }
  for(int t = wv; t < 13; t += 8){
    int qb = t*16;
    for(int i = lane; i < 128; i += 64){
      int row = i>>3, word = i&7;
      int qr = qb+row; if(qr>196) qr=196;
      Ml[wv][row][word] = maskw[(size_t)(bh*N_+qr)*8 + word];
    }
    int qrow = qb + c16; if(qrow>196) qrow=196;
    const unsigned short* Qr = qkv + ((size_t)(b*N_+qrow)*3)*C_ + h*CH_ + g*8;
    short8 af[2];
    af[0] = *(const short8*)(Qr);
    af[1] = *(const short8*)(Qr + 32);
    f32x4 sf[13];
    #pragma unroll
    for(int f=0;f<13;++f){
      sf[f] = (f32x4){0.f,0.f,0.f,0.f};
      #pragma unroll
      for(int s=0;s<2;++s){
        int row = f*16 + c16;
        unsigned off = (unsigned)(row*128 + s*64 + g*16) ^ ((unsigned)(row&7)<<4);
        short8 bfr = *(const short8*)((char*)Kb + off);
        sf[f] = __builtin_amdgcn_mfma_f32_16x16x32_bf16(af[s], bfr, sf[f], 0,0,0);
      }
      sf[f][0]*=0.125f; sf[f][1]*=0.125f; sf[f][2]*=0.125f; sf[f][3]*=0.125f;
    }
    unsigned keep[4] = {0,0,0,0};
    float m[4] = {-FLT_MAX,-FLT_MAX,-FLT_MAX,-FLT_MAX};
    #pragma unroll
    for(int f=0;f<13;++f)
      #pragma unroll
      for(int r=0;r<4;++r){
        unsigned bit = (Ml[wv][g*4+r][f>>1] >> ((f&1)*16 + c16)) & 1u;
        keep[r] |= bit<<f;
        if(bit) m[r] = fmaxf(m[r], sf[f][r]);
      }
    #pragma unroll
    for(int r=0;r<4;++r){
      #pragma unroll
      for(int o=8;o>=1;o>>=1) m[r] = fmaxf(m[r], __shfl_xor(m[r], o));
    }
    float sum[4] = {0,0,0,0};
    #pragma unroll
    for(int f=0;f<13;++f)
      #pragma unroll
      for(int r=0;r<4;++r){
        float e = ((keep[r]>>f)&1u) ? expf(sf[f][r]-m[r]) : 0.f;
        sf[f][r] = e; sum[r] += e;
      }
    #pragma unroll
    for(int r=0;r<4;++r){
      #pragma unroll
      for(int o=8;o>=1;o>>=1) sum[r] += __shfl_xor(sum[r], o);
      sum[r] = 1.f/sum[r];
    }
    #pragma unroll
    for(int f=0;f<13;++f)
      #pragma unroll
      for(int r=0;r<4;++r){
        int ql = g*4+r;
        unsigned off = (unsigned)(ql*448 + (f*16+c16)*2) ^ ((unsigned)(ql&7)<<4);
        *(unsigned short*)((char*)Pl + pbase + off) = f2bf(sf[f][r]*sum[r]);
      }
    #pragma unroll
    for(int ct=0;ct<4;++ct){
      f32x4 oa = (f32x4){0.f,0.f,0.f,0.f};
      #pragma unroll
      for(int ks=0;ks<7;++ks){
        unsigned offa = (unsigned)(c16*448 + (ks*32+g*8)*2) ^ ((unsigned)(c16&7)<<4);
        short8 pa = *(const short8*)((char*)Pl + pbase + offa);
        short8 vb = *(const short8*)((char*)Vt + (size_t)(ct*16+c16)*440 + (ks*32+g*8)*2);
        oa = __builtin_amdgcn_mfma_f32_16x16x32_bf16(pa, vb, oa, 0,0,0);
      }
      #pragma unroll
      for(int r=0;r<4;++r){
        int qq = qb + g*4 + r;
        if(qq < N_)
          attn_out[((size_t)(b*N_+qq))*C_ + h*CH_ + ct*16 + c16] = f2bf(oa[r]);
      }
    }
  }
}

extern "C" void kernel_launch(void* const* d_in, const int* in_sizes, int n_in,
                              void* d_out, int out_size, void* d_ws, size_t ws_size,
                              hipStream_t stream){
  const float* x    =(const float*)d_in[0];
  const float* Wqkv =(const float*)d_in[1];
  const float* Wcq  =(const float*)d_in[2];
  const float* bcq  =(const float*)d_in[3];
  const float* Wck  =(const float*)d_in[4];
  const float* bck  =(const float*)d_in[5];
  const float* proj_n=(const float*)d_in[6];
  const float* proj_back_n=(const float*)d_in[7];
  const float* Wproj=(const float*)d_in[8];
  const float* bproj=(const float*)d_in[9];
  const float* g1=(const float*)d_in[10];
  const float* b1=(const float*)d_in[11];
  const float* g2=(const float*)d_in[12];
  const float* b2=(const float*)d_in[13];
  const float* W1=(const float*)d_in[14];
  const float* bfc1=(const float*)d_in[15];
  const float* W2=(const float*)d_in[16];
  const float* bfc2=(const float*)d_in[17];
  float* out=(float*)d_out;

  // ---- workspace layout (float slots). ~152 MB ----
  float* ws=(float*)d_ws;
  size_t off=0;
  unsigned short* hbuf = (unsigned short*)(ws+off); off += (size_t)12608*768/2;  // bf16, aliased as attn_out
  size_t qkv_off = off;
  unsigned short* qkv = (unsigned short*)(ws+off); off += (size_t)12608*2304/2; // bf16
  float* qp   = ws+off;        off += (size_t)768*197*32;
  float* kp   = ws+off;        off += (size_t)768*197*32;
  float* kkb  = ws+off;        off += (size_t)768*32*24;
  float* coef = ws+off;        off += (size_t)768*196*24;
  float* basis= ws+off;        off += 4736;
  unsigned int* maskw=(unsigned int*)(ws+off); off += (size_t)768*197*8;
  unsigned short* WqkvT = (unsigned short*)(ws+off); off += (size_t)2304*768/2;
  unsigned short* WprojT= (unsigned short*)(ws+off); off += (size_t)768*768/2;
  unsigned short* W1T   = (unsigned short*)(ws+off); off += (size_t)3072*768/2;
  unsigned short* W2T   = (unsigned short*)(ws+off); off += (size_t)768*3072/2;
  unsigned short* attn_out = hbuf;                    // alias (hbuf dead after qkv GEMM)
  unsigned short* hidden = (unsigned short*)(ws+qkv_off); // alias (qkv+qp dead by MLP)
  float* x1 = out;

  // 0. weight transpose+bf16 conversions
  wtrans_kernel<<<dim3(72,24),256,0,stream>>>(Wqkv, WqkvT, 768, 2304);
  wtrans_kernel<<<dim3(24,24),256,0,stream>>>(Wproj, WprojT, 768, 768);
  wtrans_kernel<<<dim3(96,24),256,0,stream>>>(W1, W1T, 768, 3072);
  wtrans_kernel<<<dim3(24,96),256,0,stream>>>(W2, W2T, 3072, 768);
  // 1. h = LN(x) -> bf16
  ln_kernel<<<12608,256,0,stream>>>(x,g1,b1,hbuf);
  // 2. qkv = h @ Wqkv (bf16 out)
  gemm_bf16<0,0,1><<<dim3(18,99),256,0,stream>>>(hbuf,WqkvT,nullptr,nullptr,qkv,12608,768,2304);
  // 3. qp, kp (bf16 in, f32 out)
  qkproj_kernel<<<18912,256,0,stream>>>(qkv,Wcq,bcq,qp,0);
  qkproj_kernel<<<18912,256,0,stream>>>(qkv,Wck,bck,kp,1);
  // 4. kk
  kk_kernel<<<768,768,0,stream>>>(kp,proj_n,kkb);
  // 5. basis
  basis_kernel<<<19,256,0,stream>>>(proj_back_n,basis);
  // 6. cheap + softmax + top8
  coef_kernel<<<37632,256,0,stream>>>(qp,kkb,coef);
  // 7. approx_attn + budget mask (compare-radix select, 4 rows/wave)
  mask4_kernel<<<9456,256,0,stream>>>(coef,basis,maskw);
  // 8. masked attention (MFMA, bf16 in/out, aliases hbuf)
  attn3_kernel<<<768,512,0,stream>>>(qkv,maskw,attn_out);
  // 9. x1 = x + attn_out @ Wproj + bproj   (x1 == d_out)
  gemm_bf16<0,1,0><<<dim3(6,99),256,0,stream>>>(attn_out,WprojT,bproj,x,x1,12608,768,768);
  // 10. h2 = LN(x1) -> bf16 (reuse hbuf)
  ln_kernel<<<12608,256,0,stream>>>(x1,g2,b2,hbuf);
  // 11. hidden = gelu(h2 @ W1 + bfc1) -> bf16 (aliases dead qkv+qp)
  gemm_bf16<1,0,1><<<dim3(24,99),256,0,stream>>>(hbuf,W1T,bfc1,nullptr,hidden,12608,768,3072);
  // 12. out = x1 + hidden @ W2 + bfc2
  gemm_bf16<0,1,0><<<dim3(6,99),256,0,stream>>>(hidden,W2T,bfc2,x1,out,12608,3072,768);
}

// Round 10
// 828.701 us; speedup vs baseline: 5.5336x; 1.0162x over previous
//
#include <hip/hip_runtime.h>
#include <math.h>
#include <float.h>

#define B_ 64
#define N_ 197
#define C_ 768
#define H_ 12
#define CH_ 64
#define RC_ 32
#define RN_ 24

typedef __attribute__((ext_vector_type(8))) short short8;
typedef __attribute__((ext_vector_type(4))) float f32x4;
typedef __attribute__((address_space(3))) void  lds_void;
typedef __attribute__((address_space(1))) const void g_void;

__device__ __forceinline__ float warp_sum(float v){
  #pragma unroll
  for(int o=32;o>=1;o>>=1) v += __shfl_xor(v,o);
  return v;
}
__device__ __forceinline__ float warp_max(float v){
  #pragma unroll
  for(int o=32;o>=1;o>>=1) v = fmaxf(v,__shfl_xor(v,o));
  return v;
}
__device__ __forceinline__ unsigned short f2bf(float f){
  union{float f; unsigned u;} c; c.f = f;
  unsigned r = c.u + 0x7FFF + ((c.u>>16)&1);
  return (unsigned short)(r>>16);
}
__device__ __forceinline__ float bf2f(unsigned short u){
  union{unsigned u; float f;} c; c.u = ((unsigned)u)<<16; return c.f;
}

// ---------------- LayerNorm: one block per row of 768, bf16 out ----------------
__global__ __launch_bounds__(256) void ln_kernel(const float* __restrict__ x,
    const float* __restrict__ g, const float* __restrict__ bb, unsigned short* __restrict__ out){
  int r = blockIdx.x; int tid = threadIdx.x;
  const float* xr = x + (size_t)r*C_;
  float v0=xr[tid], v1=xr[tid+256], v2=xr[tid+512];
  __shared__ float red[8];
  float s = warp_sum(v0+v1+v2);
  if((tid&63)==0) red[tid>>6]=s;
  __syncthreads();
  float mu = (red[0]+red[1]+red[2]+red[3]) * (1.f/768.f);
  float d0=v0-mu,d1=v1-mu,d2=v2-mu;
  float s2 = warp_sum(d0*d0+d1*d1+d2*d2);
  if((tid&63)==0) red[4+(tid>>6)]=s2;
  __syncthreads();
  float rinv = rsqrtf((red[4]+red[5]+red[6]+red[7])*(1.f/768.f)+1e-5f);
  unsigned short* orow = out + (size_t)r*C_;
  orow[tid]     = f2bf(d0*rinv*g[tid]    +bb[tid]);
  orow[tid+256] = f2bf(d1*rinv*g[tid+256]+bb[tid+256]);
  orow[tid+512] = f2bf(d2*rinv*g[tid+512]+bb[tid+512]);
}

// ---------------- transpose+convert: in f32 [K][N] -> out bf16 [N][K] ----------------
__global__ __launch_bounds__(256) void wtrans_kernel(const float* __restrict__ in,
    unsigned short* __restrict__ out, int K, int N){
  __shared__ float tile[32][33];
  int n0 = blockIdx.x*32, k0 = blockIdx.y*32;
  int tx = threadIdx.x&31, ty = threadIdx.x>>5;   // ty: 8 rows per pass
  #pragma unroll
  for(int i=0;i<4;++i) tile[ty+8*i][tx] = in[(size_t)(k0+ty+8*i)*N + n0+tx];
  __syncthreads();
  #pragma unroll
  for(int i=0;i<4;++i) out[(size_t)(n0+ty+8*i)*K + k0+tx] = f2bf(tile[tx][ty+8*i]);
}

// ---------------- bf16 MFMA GEMM, double-buffered ----------------
template<int ACT, int RESID, int OUTBF16>
__global__ __launch_bounds__(256) void gemm_bf16(
    const unsigned short* __restrict__ A, const unsigned short* __restrict__ WT,
    const float* __restrict__ bias, const float* __restrict__ resid,
    void* __restrict__ Cout, int M, int K, int Nc){
  __shared__ unsigned short As[2*128*32];
  __shared__ unsigned short Bs[2*128*32];
  int tid = threadIdx.x, lane = tid&63, wid = tid>>6;
  int m0 = blockIdx.y*128, n0 = blockIdx.x*128;
  int wr = wid>>1, wc = wid&1;
  int lm = lane&15, lg = lane>>4;
  int row0 = tid>>2,         kc0 = (tid&3)*8;
  int row1 = (256+tid)>>2,   kc1 = (tid&3)*8;
  int ar0 = m0+row0; if(ar0 > M-1) ar0 = M-1;
  int ar1 = m0+row1; if(ar1 > M-1) ar1 = M-1;
  const unsigned short* gA0 = A  + (size_t)ar0*K + kc0;
  const unsigned short* gA1 = A  + (size_t)ar1*K + kc1;
  const unsigned short* gB0 = WT + (size_t)(n0+row0)*K + kc0;
  const unsigned short* gB1 = WT + (size_t)(n0+row1)*K + kc1;
  unsigned short* lA0 = As + (wid*64)*8;
  unsigned short* lA1 = As + (256 + wid*64)*8;
  unsigned short* lB0 = Bs + (wid*64)*8;
  unsigned short* lB1 = Bs + (256 + wid*64)*8;

#define STAGE_(buf, kt) do{ \
    __builtin_amdgcn_global_load_lds((g_void*)(gA0 + (kt)), (lds_void*)(lA0 + (buf)*4096), 16, 0, 0); \
    __builtin_amdgcn_global_load_lds((g_void*)(gB0 + (kt)), (lds_void*)(lB0 + (buf)*4096), 16, 0, 0); \
    __builtin_amdgcn_global_load_lds((g_void*)(gA1 + (kt)), (lds_void*)(lA1 + (buf)*4096), 16, 0, 0); \
    __builtin_amdgcn_global_load_lds((g_void*)(gB1 + (kt)), (lds_void*)(lB1 + (buf)*4096), 16, 0, 0); \
  }while(0)

  f32x4 acc[4][4] = {};
  const int nt = K/32;
  STAGE_(0, 0);
  __syncthreads();
  for(int t=0; t<nt; t+=2){
    STAGE_(1, (t+1)*32);
    {
      short8 af[4], bfv[4];
      #pragma unroll
      for(int i=0;i<4;++i){
        af[i]  = *(const short8*)(As + (64*wr + 16*i + lm)*32 + lg*8);
        bfv[i] = *(const short8*)(Bs + (64*wc + 16*i + lm)*32 + lg*8);
      }
      #pragma unroll
      for(int i=0;i<4;++i)
        #pragma unroll
        for(int j=0;j<4;++j)
          acc[i][j] = __builtin_amdgcn_mfma_f32_16x16x32_bf16(af[i], bfv[j], acc[i][j], 0,0,0);
    }
    __syncthreads();
    if(t+2 < nt) STAGE_(0, (t+2)*32);
    {
      short8 af[4], bfv[4];
      #pragma unroll
      for(int i=0;i<4;++i){
        af[i]  = *(const short8*)(As + 4096 + (64*wr + 16*i + lm)*32 + lg*8);
        bfv[i] = *(const short8*)(Bs + 4096 + (64*wc + 16*i + lm)*32 + lg*8);
      }
      #pragma unroll
      for(int i=0;i<4;++i)
        #pragma unroll
        for(int j=0;j<4;++j)
          acc[i][j] = __builtin_amdgcn_mfma_f32_16x16x32_bf16(af[i], bfv[j], acc[i][j], 0,0,0);
    }
    __syncthreads();
  }
#undef STAGE_
  #pragma unroll
  for(int i=0;i<4;++i){
    #pragma unroll
    for(int j=0;j<4;++j){
      int gcol = n0 + 64*wc + 16*j + lm;
      float bv = bias ? bias[gcol] : 0.f;
      #pragma unroll
      for(int r=0;r<4;++r){
        int grow = m0 + 64*wr + 16*i + lg*4 + r;
        if(grow < M){
          float cv = acc[i][j][r] + bv;
          if(ACT==1){
            float xx = cv;
            float p = xx*fmaf(xx*xx, 0.10294517f, 2.3022079f);
            float q = exp2f(p);
            cv = xx - xx*__builtin_amdgcn_rcpf(1.0f+q);
          }
          if(RESID) cv += resid[(size_t)grow*Nc + gcol];
          if(OUTBF16) ((unsigned short*)Cout)[(size_t)grow*Nc+gcol] = f2bf(cv);
          else        ((float*)Cout)[(size_t)grow*Nc+gcol] = cv;
        }
      }
    }
  }
}

// ---------------- fused cheap path: qp/kp + kk + cheap + softmax + top8 ----------------
// One block per (b,h), 512 threads. Replaces qkproj x2, kk_kernel, coef_kernel.
// All dot products keep ascending-index order (matches previous kernels).
__global__ __launch_bounds__(512) void cheap_kernel(
    const unsigned short* __restrict__ qkv,
    const float* __restrict__ Wcq, const float* __restrict__ bcq,
    const float* __restrict__ Wck, const float* __restrict__ bck,
    const float* __restrict__ proj_n, float* __restrict__ coef){
  int bh = blockIdx.x; int b = bh/H_, h = bh%H_;
  int tid = threadIdx.x, lane = tid&63, wv = tid>>6;
  __shared__ unsigned short KQ[197*64];   // 25.2 KB: K rows, later Q rows
  __shared__ float P2[197*32];            // 25.2 KB: kp, later qp
  __shared__ float Wq[64*32];             // 8 KB
  __shared__ float Wk[64*32];             // 8 KB
  __shared__ float PN[197*24];            // 18.5 KB
  __shared__ float KK[32*24];             // 3 KB
  __shared__ float BQ[32], BK2[32];
  const unsigned short* Kbase = qkv + ((size_t)(b*N_)*3 + 1)*C_ + h*CH_;
  const unsigned short* Qbase = qkv + ((size_t)(b*N_)*3 + 0)*C_ + h*CH_;
  // stage K (u32 copies), weights, proj_n, biases
  for(int idx = tid; idx < 197*32; idx += 512){
    int k = idx>>5, cp = (idx&31)*2;
    *(unsigned*)&KQ[k*64+cp] = *(const unsigned*)(Kbase + (size_t)k*3*C_ + cp);
  }
  for(int idx = tid; idx < 2048; idx += 512){ Wq[idx]=Wcq[idx]; Wk[idx]=Wck[idx]; }
  for(int idx = tid; idx < 4728; idx += 512) PN[idx]=proj_n[idx];
  if(tid<32){ BQ[tid]=bcq[tid]; BK2[tid]=bck[tid]; }
  __syncthreads();
  int mycol = tid&31;
  // kp -> P2   (thread's col fixed; weights cached in regs)
  {
    float wreg[64];
    #pragma unroll 64
    for(int c=0;c<64;++c) wreg[c] = Wk[c*32+mycol];
    for(int idx = tid; idx < 197*32; idx += 512){
      int n = idx>>5;
      float acc = BK2[mycol];
      const uint4* krow = (const uint4*)(KQ + n*64);
      #pragma unroll
      for(int q8=0;q8<8;++q8){
        uint4 u4 = krow[q8];
        unsigned uu[4] = {u4.x,u4.y,u4.z,u4.w};
        #pragma unroll
        for(int p2=0;p2<4;++p2){
          float lo = __uint_as_float(uu[p2]<<16);
          float hi = __uint_as_float(uu[p2]&0xffff0000u);
          acc += lo*wreg[q8*8+p2*2];
          acc += hi*wreg[q8*8+p2*2+1];
        }
      }
      P2[idx] = acc;
    }
  }
  __syncthreads();
  // kk -> KK  (and stage Q over dead K region)
  {
    int i0 = tid, i1 = tid+512;
    int c0 = i0/24, r0 = i0-c0*24;
    int c1 = (i1<768)? i1/24 : 0;
    int r1 = (i1<768)? i1-c1*24 : 0;
    float a0=0.f, a1=0.f;
    for(int n=0;n<197;++n){
      float pn0 = PN[n*24+r0];
      a0 += P2[n*32+c0]*pn0;
      if(i1<768) a1 += P2[n*32+c1]*PN[n*24+r1];
    }
    if(i0<768) KK[i0]=a0;
    if(i1<768) KK[i1]=a1;
    for(int idx = tid; idx < 197*32; idx += 512){
      int k = idx>>5, cp = (idx&31)*2;
      *(unsigned*)&KQ[k*64+cp] = *(const unsigned*)(Qbase + (size_t)k*3*C_ + cp);
    }
  }
  __syncthreads();
  // qp -> P2 (overwrites kp; kp dead after kk)
  {
    float wreg[64];
    #pragma unroll 64
    for(int c=0;c<64;++c) wreg[c] = Wq[c*32+mycol];
    for(int idx = tid; idx < 197*32; idx += 512){
      int n = idx>>5;
      float acc = BQ[mycol];
      const uint4* krow = (const uint4*)(KQ + n*64);
      #pragma unroll
      for(int q8=0;q8<8;++q8){
        uint4 u4 = krow[q8];
        unsigned uu[4] = {u4.x,u4.y,u4.z,u4.w};
        #pragma unroll
        for(int p2=0;p2<4;++p2){
          float lo = __uint_as_float(uu[p2]<<16);
          float hi = __uint_as_float(uu[p2]&0xffff0000u);
          acc += lo*wreg[q8*8+p2*2];
          acc += hi*wreg[q8*8+p2*2+1];
        }
      }
      P2[idx] = acc;
    }
  }
  __syncthreads();
  // cheap + softmax + keep-top8, one wave per row (rows n=1..196)
  for(int i = wv; i < 196; i += 8){
    int n = i+1;
    float val = -INFINITY;
    if(lane < RN_){
      float acc = 0.f;
      #pragma unroll
      for(int c=0;c<32;++c) acc += P2[n*32+c]*KK[c*24+lane];
      val = acc * 0.28867513459481287f;   // H^-0.5
    }
    float m = warp_max(val);
    float e = (lane<RN_)? expf(val-m) : 0.f;
    float ssum = warp_sum(e);
    float p = e/ssum;
    float myv = (lane<RN_)? p : -1.f;
    int cnt=0;
    #pragma unroll
    for(int j=0;j<RN_;++j){ float vj = __shfl(myv,j); cnt += (vj>myv)?1:0; }
    if(lane<RN_) coef[((size_t)bh*196 + i)*24 + lane] = (cnt<=7)? p : 0.f;
  }
}

// ---------------- basis[r][j] = thresh(|proj_back_n[j][r]|) ----------------
__global__ __launch_bounds__(256) void basis_kernel(const float* __restrict__ pb,
    float* __restrict__ basis){
  int t = blockIdx.x*256 + threadIdx.x;
  if(t < RN_*N_){
    int r = t/N_, j = t%N_;
    float v = fabsf(pb[(size_t)j*RN_ + r]);
    basis[t] = (v > 0.02f) ? v : 0.f;
  }
}

// ---------------- mask v4: one WAVE per 4 rows; ballot compare-radix top-50 ----------------
__global__ __launch_bounds__(256) void mask4_kernel(const float* __restrict__ coef,
    const float* __restrict__ basis, unsigned int* __restrict__ maskw){
  __shared__ float Bs[24*256];
  int tid = threadIdx.x, lane = tid&63, wv = tid>>6;
  for(int idx = tid; idx < 24*256; idx += 256){
    int r = idx>>8, q = idx&255;
    int e = ((q&3)<<6) | (q>>2);          // inverse of dest mapping
    Bs[idx] = (e < N_) ? basis[r*N_ + e] : 0.f;
  }
  __syncthreads();
  int rowbase = blockIdx.x*16 + wv*4;     // 9456 blocks * 16 rows = 151296
  #pragma unroll
  for(int j=0;j<4;++j){
    int row = rowbase + j;                // (b*H+h)*197 + qi
    int qi = row % N_; int bh = row / N_;
    if(qi==0){
      if(lane<8){
        unsigned v = (lane<6)?0xFFFFFFFFu:((lane==6)?0x1Fu:0u);
        maskw[(size_t)row*8+lane]=v;
      }
      continue;
    }
    float cfv = (lane<24) ? coef[((size_t)bh*196 + (qi-1))*24 + lane] : 0.f;
    unsigned long long nz = __ballot(cfv != 0.f);
    float4 av = make_float4(0.f,0.f,0.f,0.f);
    while(nz){
      int r = __ffsll((unsigned long long)nz) - 1;
      nz &= nz - 1;
      float c = __uint_as_float(__builtin_amdgcn_readlane(__float_as_uint(cfv), r));
      float4 bv = *(const float4*)&Bs[r*256 + lane*4];
      av.x += c*bv.x; av.y += c*bv.y; av.z += c*bv.z; av.w += c*bv.w;
    }
    unsigned u0=__float_as_uint(av.x), u1=__float_as_uint(av.y);
    unsigned u2=__float_as_uint(av.z), u3=__float_as_uint(av.w);
    unsigned prefix = 0;
    #pragma unroll
    for(int bit=30; bit>=0; --bit){
      unsigned t = prefix | (1u<<bit);
      int c = __popcll(__ballot(u0 >= t)) + __popcll(__ballot(u1 >= t))
            + __popcll(__ballot(u2 >= t)) + __popcll(__ballot(u3 >= t));
      if(c >= 50) prefix = t;
    }
    unsigned uu[4] = {u0,u1,u2,u3};
    #pragma unroll
    for(int r=0;r<4;++r){
      bool valid = (r<3) | (lane<5);
      bool keep = valid && (uu[r] >= prefix);
      unsigned long long bal = __ballot(keep);
      if(lane==0){
        maskw[(size_t)row*8 + 2*r]   = (unsigned)(bal & 0xFFFFFFFFull);
        maskw[(size_t)row*8 + 2*r+1] = (unsigned)(bal>>32);
      }
    }
  }
}

// ---------------- masked attention v3: MFMA flash-style, one block per (b,h) ----------------
__global__ __launch_bounds__(512) void attn3_kernel(const unsigned short* __restrict__ qkv,
    const unsigned int* __restrict__ maskw, unsigned short* __restrict__ attn_out){
  int bh = blockIdx.x; int b = bh/H_, h = bh%H_;
  int tid = threadIdx.x, lane = tid&63, wv = tid>>6;
  int g = lane>>4, c16 = lane&15;
  __shared__ unsigned short Kb[208*64];     // 26.6 KB
  __shared__ unsigned short Vt[64*220];     // 28.2 KB
  __shared__ unsigned short Pl[8*16*224];   // 57.3 KB
  __shared__ unsigned int   Ml[8][16][8];   // 4 KB
  const unsigned short* Kbase = qkv + ((size_t)(b*N_)*3 + 1)*C_ + h*CH_;
  const unsigned short* Vbase = qkv + ((size_t)(b*N_)*3 + 2)*C_ + h*CH_;
  for(int idx = tid; idx < 208*32; idx += 512){
    int k = idx>>5, cp = idx&31;
    unsigned pk = 0;
    if(k < N_) pk = *(const unsigned*)(Kbase + (size_t)k*3*C_ + cp*2);
    unsigned off = (unsigned)(k*128 + cp*4) ^ ((unsigned)(k&7)<<4);
    *(unsigned*)((char*)Kb + off) = pk;
  }
  for(int idx = tid; idx < 64*110; idx += 512){
    int kp = idx>>6, c = idx&63;
    int k0 = kp*2, k1 = kp*2+1;
    unsigned v0 = (k0<N_) ? Vbase[(size_t)k0*3*C_ + c] : 0;
    unsigned v1 = (k1<N_) ? Vbase[(size_t)k1*3*C_ + c] : 0;
    *(unsigned*)((char*)Vt + c*440 + kp*4) = v0 | (v1<<16);
  }
  __syncthreads();
  size_t pbase = (size_t)wv*16*448;
  for(int i=lane;i<128;i+=64){
    int ql = i>>3; int kk = 208 + (i&7)*2;
    unsigned off = (unsigned)(ql*448 + kk*2) ^ ((unsigned)(ql&7)<<4);
    *(unsigned*)((char*)Pl + pbase + off) = 0u;
  }
  for(int t = wv; t < 13; t += 8){
    int qb = t*16;
    for(int i = lane; i < 128; i += 64){
      int row = i>>3, word = i&7;
      int qr = qb+row; if(qr>196) qr=196;
      Ml[wv][row][word] = maskw[(size_t)(bh*N_+qr)*8 + word];
    }
    int qrow = qb + c16; if(qrow>196) qrow=196;
    const unsigned short* Qr = qkv + ((size_t)(b*N_+qrow)*3)*C_ + h*CH_ + g*8;
    short8 af[2];
    af[0] = *(const short8*)(Qr);
    af[1] = *(const short8*)(Qr + 32);
    f32x4 sf[13];
    #pragma unroll
    for(int f=0;f<13;++f){
      sf[f] = (f32x4){0.f,0.f,0.f,0.f};
      #pragma unroll
      for(int s=0;s<2;++s){
        int row = f*16 + c16;
        unsigned off = (unsigned)(row*128 + s*64 + g*16) ^ ((unsigned)(row&7)<<4);
        short8 bfr = *(const short8*)((char*)Kb + off);
        sf[f] = __builtin_amdgcn_mfma_f32_16x16x32_bf16(af[s], bfr, sf[f], 0,0,0);
      }
      sf[f][0]*=0.125f; sf[f][1]*=0.125f; sf[f][2]*=0.125f; sf[f][3]*=0.125f;
    }
    unsigned keep[4] = {0,0,0,0};
    float m[4] = {-FLT_MAX,-FLT_MAX,-FLT_MAX,-FLT_MAX};
    #pragma unroll
    for(int f=0;f<13;++f)
      #pragma unroll
      for(int r=0;r<4;++r){
        unsigned bit = (Ml[wv][g*4+r][f>>1] >> ((f&1)*16 + c16)) & 1u;
        keep[r] |= bit<<f;
        if(bit) m[r] = fmaxf(m[r], sf[f][r]);
      }
    #pragma unroll
    for(int r=0;r<4;++r){
      #pragma unroll
      for(int o=8;o>=1;o>>=1) m[r] = fmaxf(m[r], __shfl_xor(m[r], o));
    }
    float sum[4] = {0,0,0,0};
    #pragma unroll
    for(int f=0;f<13;++f)
      #pragma unroll
      for(int r=0;r<4;++r){
        float e = ((keep[r]>>f)&1u) ? expf(sf[f][r]-m[r]) : 0.f;
        sf[f][r] = e; sum[r] += e;
      }
    #pragma unroll
    for(int r=0;r<4;++r){
      #pragma unroll
      for(int o=8;o>=1;o>>=1) sum[r] += __shfl_xor(sum[r], o);
      sum[r] = 1.f/sum[r];
    }
    #pragma unroll
    for(int f=0;f<13;++f)
      #pragma unroll
      for(int r=0;r<4;++r){
        int ql = g*4+r;
        unsigned off = (unsigned)(ql*448 + (f*16+c16)*2) ^ ((unsigned)(ql&7)<<4);
        *(unsigned short*)((char*)Pl + pbase + off) = f2bf(sf[f][r]*sum[r]);
      }
    #pragma unroll
    for(int ct=0;ct<4;++ct){
      f32x4 oa = (f32x4){0.f,0.f,0.f,0.f};
      #pragma unroll
      for(int ks=0;ks<7;++ks){
        unsigned offa = (unsigned)(c16*448 + (ks*32+g*8)*2) ^ ((unsigned)(c16&7)<<4);
        short8 pa = *(const short8*)((char*)Pl + pbase + offa);
        short8 vb = *(const short8*)((char*)Vt + (size_t)(ct*16+c16)*440 + (ks*32+g*8)*2);
        oa = __builtin_amdgcn_mfma_f32_16x16x32_bf16(pa, vb, oa, 0,0,0);
      }
      #pragma unroll
      for(int r=0;r<4;++r){
        int qq = qb + g*4 + r;
        if(qq < N_)
          attn_out[((size_t)(b*N_+qq))*C_ + h*CH_ + ct*16 + c16] = f2bf(oa[r]);
      }
    }
  }
}

extern "C" void kernel_launch(void* const* d_in, const int* in_sizes, int n_in,
                              void* d_out, int out_size, void* d_ws, size_t ws_size,
                              hipStream_t stream){
  const float* x    =(const float*)d_in[0];
  const float* Wqkv =(const float*)d_in[1];
  const float* Wcq  =(const float*)d_in[2];
  const float* bcq  =(const float*)d_in[3];
  const float* Wck  =(const float*)d_in[4];
  const float* bck  =(const float*)d_in[5];
  const float* proj_n=(const float*)d_in[6];
  const float* proj_back_n=(const float*)d_in[7];
  const float* Wproj=(const float*)d_in[8];
  const float* bproj=(const float*)d_in[9];
  const float* g1=(const float*)d_in[10];
  const float* b1=(const float*)d_in[11];
  const float* g2=(const float*)d_in[12];
  const float* b2=(const float*)d_in[13];
  const float* W1=(const float*)d_in[14];
  const float* bfc1=(const float*)d_in[15];
  const float* W2=(const float*)d_in[16];
  const float* bfc2=(const float*)d_in[17];
  float* out=(float*)d_out;

  // ---- workspace layout (float slots). Layout unchanged; qp/kp/kkb slots
  // retained as padding (hidden aliases qkv+qp exactly). ----
  float* ws=(float*)d_ws;
  size_t off=0;
  unsigned short* hbuf = (unsigned short*)(ws+off); off += (size_t)12608*768/2;
  size_t qkv_off = off;
  unsigned short* qkv = (unsigned short*)(ws+off); off += (size_t)12608*2304/2;
  off += (size_t)768*197*32;   // (was qp — now padding for hidden alias)
  off += (size_t)768*197*32;   // (was kp — unused)
  off += (size_t)768*32*24;    // (was kkb — unused)
  float* coef = ws+off;        off += (size_t)768*196*24;
  float* basis= ws+off;        off += 4736;
  unsigned int* maskw=(unsigned int*)(ws+off); off += (size_t)768*197*8;
  unsigned short* WqkvT = (unsigned short*)(ws+off); off += (size_t)2304*768/2;
  unsigned short* WprojT= (unsigned short*)(ws+off); off += (size_t)768*768/2;
  unsigned short* W1T   = (unsigned short*)(ws+off); off += (size_t)3072*768/2;
  unsigned short* W2T   = (unsigned short*)(ws+off); off += (size_t)768*3072/2;
  unsigned short* attn_out = hbuf;                    // alias (hbuf dead after qkv GEMM)
  unsigned short* hidden = (unsigned short*)(ws+qkv_off); // alias (qkv+qp-slot dead by MLP)
  float* x1 = out;

  // 0. weight transpose+bf16 conversions
  wtrans_kernel<<<dim3(72,24),256,0,stream>>>(Wqkv, WqkvT, 768, 2304);
  wtrans_kernel<<<dim3(24,24),256,0,stream>>>(Wproj, WprojT, 768, 768);
  wtrans_kernel<<<dim3(96,24),256,0,stream>>>(W1, W1T, 768, 3072);
  wtrans_kernel<<<dim3(24,96),256,0,stream>>>(W2, W2T, 3072, 768);
  // 1. h = LN(x) -> bf16
  ln_kernel<<<12608,256,0,stream>>>(x,g1,b1,hbuf);
  // 2. qkv = h @ Wqkv (bf16 out)
  gemm_bf16<0,0,1><<<dim3(18,99),256,0,stream>>>(hbuf,WqkvT,nullptr,nullptr,qkv,12608,768,2304);
  // 3. fused cheap path (qp/kp + kk + cheap + softmax + top8)
  cheap_kernel<<<768,512,0,stream>>>(qkv,Wcq,bcq,Wck,bck,proj_n,coef);
  // 4. basis
  basis_kernel<<<19,256,0,stream>>>(proj_back_n,basis);
  // 5. approx_attn + budget mask (compare-radix select, 4 rows/wave)
  mask4_kernel<<<9456,256,0,stream>>>(coef,basis,maskw);
  // 6. masked attention (MFMA, bf16 in/out, aliases hbuf)
  attn3_kernel<<<768,512,0,stream>>>(qkv,maskw,attn_out);
  // 7. x1 = x + attn_out @ Wproj + bproj   (x1 == d_out)
  gemm_bf16<0,1,0><<<dim3(6,99),256,0,stream>>>(attn_out,WprojT,bproj,x,x1,12608,768,768);
  // 8. h2 = LN(x1) -> bf16 (reuse hbuf)
  ln_kernel<<<12608,256,0,stream>>>(x1,g2,b2,hbuf);
  // 9. hidden = gelu(h2 @ W1 + bfc1) -> bf16
  gemm_bf16<1,0,1><<<dim3(24,99),256,0,stream>>>(hbuf,W1T,bfc1,nullptr,hidden,12608,768,3072);
  // 10. out = x1 + hidden @ W2 + bfc2
  gemm_bf16<0,1,0><<<dim3(6,99),256,0,stream>>>(hidden,W2T,bfc2,x1,out,12608,3072,768);
}

// Round 11
// 762.220 us; speedup vs baseline: 6.0162x; 1.0872x over previous
//
#include <hip/hip_runtime.h>
#include <math.h>
#include <float.h>

#define B_ 64
#define N_ 197
#define C_ 768
#define H_ 12
#define CH_ 64
#define RC_ 32
#define RN_ 24

typedef __attribute__((ext_vector_type(8))) short short8;
typedef __attribute__((ext_vector_type(4))) float f32x4;
typedef __attribute__((address_space(3))) void  lds_void;
typedef __attribute__((address_space(1))) const void g_void;

__device__ __forceinline__ float warp_sum(float v){
  #pragma unroll
  for(int o=32;o>=1;o>>=1) v += __shfl_xor(v,o);
  return v;
}
__device__ __forceinline__ float warp_max(float v){
  #pragma unroll
  for(int o=32;o>=1;o>>=1) v = fmaxf(v,__shfl_xor(v,o));
  return v;
}
__device__ __forceinline__ unsigned short f2bf(float f){
  union{float f; unsigned u;} c; c.f = f;
  unsigned r = c.u + 0x7FFF + ((c.u>>16)&1);
  return (unsigned short)(r>>16);
}
__device__ __forceinline__ float bf2f(unsigned short u){
  union{unsigned u; float f;} c; c.u = ((unsigned)u)<<16; return c.f;
}

// ---------------- LayerNorm: one block per row of 768, bf16 out ----------------
__global__ __launch_bounds__(256) void ln_kernel(const float* __restrict__ x,
    const float* __restrict__ g, const float* __restrict__ bb, unsigned short* __restrict__ out){
  int r = blockIdx.x; int tid = threadIdx.x;
  const float* xr = x + (size_t)r*C_;
  float v0=xr[tid], v1=xr[tid+256], v2=xr[tid+512];
  __shared__ float red[8];
  float s = warp_sum(v0+v1+v2);
  if((tid&63)==0) red[tid>>6]=s;
  __syncthreads();
  float mu = (red[0]+red[1]+red[2]+red[3]) * (1.f/768.f);
  float d0=v0-mu,d1=v1-mu,d2=v2-mu;
  float s2 = warp_sum(d0*d0+d1*d1+d2*d2);
  if((tid&63)==0) red[4+(tid>>6)]=s2;
  __syncthreads();
  float rinv = rsqrtf((red[4]+red[5]+red[6]+red[7])*(1.f/768.f)+1e-5f);
  unsigned short* orow = out + (size_t)r*C_;
  orow[tid]     = f2bf(d0*rinv*g[tid]    +bb[tid]);
  orow[tid+256] = f2bf(d1*rinv*g[tid+256]+bb[tid+256]);
  orow[tid+512] = f2bf(d2*rinv*g[tid+512]+bb[tid+512]);
}

// ---------------- transpose+convert: in f32 [K][N] -> out bf16 [N][K] ----------------
__global__ __launch_bounds__(256) void wtrans_kernel(const float* __restrict__ in,
    unsigned short* __restrict__ out, int K, int N){
  __shared__ float tile[32][33];
  int n0 = blockIdx.x*32, k0 = blockIdx.y*32;
  int tx = threadIdx.x&31, ty = threadIdx.x>>5;   // ty: 8 rows per pass
  #pragma unroll
  for(int i=0;i<4;++i) tile[ty+8*i][tx] = in[(size_t)(k0+ty+8*i)*N + n0+tx];
  __syncthreads();
  #pragma unroll
  for(int i=0;i<4;++i) out[(size_t)(n0+ty+8*i)*K + k0+tx] = f2bf(tile[tx][ty+8*i]);
}

// ---------------- bf16 MFMA GEMM, double-buffered ----------------
template<int ACT, int RESID, int OUTBF16>
__global__ __launch_bounds__(256) void gemm_bf16(
    const unsigned short* __restrict__ A, const unsigned short* __restrict__ WT,
    const float* __restrict__ bias, const float* __restrict__ resid,
    void* __restrict__ Cout, int M, int K, int Nc){
  __shared__ unsigned short As[2*128*32];
  __shared__ unsigned short Bs[2*128*32];
  int tid = threadIdx.x, lane = tid&63, wid = tid>>6;
  int m0 = blockIdx.y*128, n0 = blockIdx.x*128;
  int wr = wid>>1, wc = wid&1;
  int lm = lane&15, lg = lane>>4;
  int row0 = tid>>2,         kc0 = (tid&3)*8;
  int row1 = (256+tid)>>2,   kc1 = (tid&3)*8;
  int ar0 = m0+row0; if(ar0 > M-1) ar0 = M-1;
  int ar1 = m0+row1; if(ar1 > M-1) ar1 = M-1;
  const unsigned short* gA0 = A  + (size_t)ar0*K + kc0;
  const unsigned short* gA1 = A  + (size_t)ar1*K + kc1;
  const unsigned short* gB0 = WT + (size_t)(n0+row0)*K + kc0;
  const unsigned short* gB1 = WT + (size_t)(n0+row1)*K + kc1;
  unsigned short* lA0 = As + (wid*64)*8;
  unsigned short* lA1 = As + (256 + wid*64)*8;
  unsigned short* lB0 = Bs + (wid*64)*8;
  unsigned short* lB1 = Bs + (256 + wid*64)*8;

#define STAGE_(buf, kt) do{ \
    __builtin_amdgcn_global_load_lds((g_void*)(gA0 + (kt)), (lds_void*)(lA0 + (buf)*4096), 16, 0, 0); \
    __builtin_amdgcn_global_load_lds((g_void*)(gB0 + (kt)), (lds_void*)(lB0 + (buf)*4096), 16, 0, 0); \
    __builtin_amdgcn_global_load_lds((g_void*)(gA1 + (kt)), (lds_void*)(lA1 + (buf)*4096), 16, 0, 0); \
    __builtin_amdgcn_global_load_lds((g_void*)(gB1 + (kt)), (lds_void*)(lB1 + (buf)*4096), 16, 0, 0); \
  }while(0)

  f32x4 acc[4][4] = {};
  const int nt = K/32;
  STAGE_(0, 0);
  __syncthreads();
  for(int t=0; t<nt; t+=2){
    STAGE_(1, (t+1)*32);
    {
      short8 af[4], bfv[4];
      #pragma unroll
      for(int i=0;i<4;++i){
        af[i]  = *(const short8*)(As + (64*wr + 16*i + lm)*32 + lg*8);
        bfv[i] = *(const short8*)(Bs + (64*wc + 16*i + lm)*32 + lg*8);
      }
      #pragma unroll
      for(int i=0;i<4;++i)
        #pragma unroll
        for(int j=0;j<4;++j)
          acc[i][j] = __builtin_amdgcn_mfma_f32_16x16x32_bf16(af[i], bfv[j], acc[i][j], 0,0,0);
    }
    __syncthreads();
    if(t+2 < nt) STAGE_(0, (t+2)*32);
    {
      short8 af[4], bfv[4];
      #pragma unroll
      for(int i=0;i<4;++i){
        af[i]  = *(const short8*)(As + 4096 + (64*wr + 16*i + lm)*32 + lg*8);
        bfv[i] = *(const short8*)(Bs + 4096 + (64*wc + 16*i + lm)*32 + lg*8);
      }
      #pragma unroll
      for(int i=0;i<4;++i)
        #pragma unroll
        for(int j=0;j<4;++j)
          acc[i][j] = __builtin_amdgcn_mfma_f32_16x16x32_bf16(af[i], bfv[j], acc[i][j], 0,0,0);
    }
    __syncthreads();
  }
#undef STAGE_
  #pragma unroll
  for(int i=0;i<4;++i){
    #pragma unroll
    for(int j=0;j<4;++j){
      int gcol = n0 + 64*wc + 16*j + lm;
      float bv = bias ? bias[gcol] : 0.f;
      #pragma unroll
      for(int r=0;r<4;++r){
        int grow = m0 + 64*wr + 16*i + lg*4 + r;
        if(grow < M){
          float cv = acc[i][j][r] + bv;
          if(ACT==1){
            float xx = cv;
            float p = xx*fmaf(xx*xx, 0.10294517f, 2.3022079f);
            float q = exp2f(p);
            cv = xx - xx*__builtin_amdgcn_rcpf(1.0f+q);
          }
          if(RESID) cv += resid[(size_t)grow*Nc + gcol];
          if(OUTBF16) ((unsigned short*)Cout)[(size_t)grow*Nc+gcol] = f2bf(cv);
          else        ((float*)Cout)[(size_t)grow*Nc+gcol] = cv;
        }
      }
    }
  }
}

// ---------------- fused cheap path v2: qp/kp + kk + cheap + softmax + top8 ----------------
// One block per (b,h), 512 threads, 72 KB LDS (2 blocks/CU).
// DS-pipe surgery vs v1: weights/bias from global (L2); KK reg-cached in coef;
// P2 rows via broadcast ds_read_b128; top8 rank via compare-radix ballots.
// All dot orders identical to v1 -> coef bit-identical.
__global__ __launch_bounds__(512) void cheap_kernel(
    const unsigned short* __restrict__ qkv,
    const float* __restrict__ Wcq, const float* __restrict__ bcq,
    const float* __restrict__ Wck, const float* __restrict__ bck,
    const float* __restrict__ proj_n, float* __restrict__ coef){
  int bh = blockIdx.x; int b = bh/H_, h = bh%H_;
  int tid = threadIdx.x, lane = tid&63, wv = tid>>6;
  __shared__ unsigned short KQ[197*64];   // 25.2 KB: K rows, later Q rows
  __shared__ float P2[197*32];            // 25.2 KB: kp, later qp
  __shared__ float PN[197*24];            // 18.5 KB
  __shared__ float KK[32*24];             // 3 KB
  const unsigned short* Kbase = qkv + ((size_t)(b*N_)*3 + 1)*C_ + h*CH_;
  const unsigned short* Qbase = qkv + ((size_t)(b*N_)*3 + 0)*C_ + h*CH_;
  // stage K (u32 copies) + proj_n
  for(int idx = tid; idx < 197*32; idx += 512){
    int k = idx>>5, cp = (idx&31)*2;
    *(unsigned*)&KQ[k*64+cp] = *(const unsigned*)(Kbase + (size_t)k*3*C_ + cp);
  }
  for(int idx = tid; idx < 4728; idx += 512) PN[idx]=proj_n[idx];
  __syncthreads();
  int mycol = tid&31;
  // kp -> P2  (weights/bias from global, L2-hot)
  {
    float wreg[64];
    #pragma unroll 64
    for(int c=0;c<64;++c) wreg[c] = Wck[c*32+mycol];
    float bias = bck[mycol];
    for(int idx = tid; idx < 197*32; idx += 512){
      int n = idx>>5;
      float acc = bias;
      const uint4* krow = (const uint4*)(KQ + n*64);
      #pragma unroll
      for(int q8=0;q8<8;++q8){
        uint4 u4 = krow[q8];
        unsigned uu[4] = {u4.x,u4.y,u4.z,u4.w};
        #pragma unroll
        for(int p2=0;p2<4;++p2){
          float lo = __uint_as_float(uu[p2]<<16);
          float hi = __uint_as_float(uu[p2]&0xffff0000u);
          acc += lo*wreg[q8*8+p2*2];
          acc += hi*wreg[q8*8+p2*2+1];
        }
      }
      P2[idx] = acc;
    }
  }
  __syncthreads();
  // kk -> KK  (and stage Q over dead K region)
  {
    int i0 = tid, i1 = tid+512;
    int c0 = i0/24, r0 = i0-c0*24;
    int c1 = (i1<768)? i1/24 : 0;
    int r1 = (i1<768)? i1-c1*24 : 0;
    float a0=0.f, a1=0.f;
    for(int n=0;n<197;++n){
      float pn0 = PN[n*24+r0];
      a0 += P2[n*32+c0]*pn0;
      if(i1<768) a1 += P2[n*32+c1]*PN[n*24+r1];
    }
    if(i0<768) KK[i0]=a0;
    if(i1<768) KK[i1]=a1;
    for(int idx = tid; idx < 197*32; idx += 512){
      int k = idx>>5, cp = (idx&31)*2;
      *(unsigned*)&KQ[k*64+cp] = *(const unsigned*)(Qbase + (size_t)k*3*C_ + cp);
    }
  }
  __syncthreads();
  // qp -> P2 (overwrites kp; kp dead after kk)
  {
    float wreg[64];
    #pragma unroll 64
    for(int c=0;c<64;++c) wreg[c] = Wcq[c*32+mycol];
    float bias = bcq[mycol];
    for(int idx = tid; idx < 197*32; idx += 512){
      int n = idx>>5;
      float acc = bias;
      const uint4* krow = (const uint4*)(KQ + n*64);
      #pragma unroll
      for(int q8=0;q8<8;++q8){
        uint4 u4 = krow[q8];
        unsigned uu[4] = {u4.x,u4.y,u4.z,u4.w};
        #pragma unroll
        for(int p2=0;p2<4;++p2){
          float lo = __uint_as_float(uu[p2]<<16);
          float hi = __uint_as_float(uu[p2]&0xffff0000u);
          acc += lo*wreg[q8*8+p2*2];
          acc += hi*wreg[q8*8+p2*2+1];
        }
      }
      P2[idx] = acc;
    }
  }
  __syncthreads();
  // KK -> per-lane registers (lane<24 owns column lane)
  bool act = lane < RN_;
  int ll = act ? lane : 0;
  float kkreg[32];
  #pragma unroll
  for(int c=0;c<32;++c) kkreg[c] = KK[c*24 + ll];
  // cheap + softmax + keep-top8, one wave per row (rows n=1..196)
  for(int i = wv; i < 196; i += 8){
    int n = i+1;
    // broadcast row read (uniform address across lanes)
    float pr[32];
    #pragma unroll
    for(int q=0;q<8;++q){
      float4 v4 = *(const float4*)&P2[n*32 + q*4];
      pr[q*4]=v4.x; pr[q*4+1]=v4.y; pr[q*4+2]=v4.z; pr[q*4+3]=v4.w;
    }
    float accv = 0.f;
    #pragma unroll
    for(int c=0;c<32;++c) accv += pr[c]*kkreg[c];
    float val = act ? accv * 0.28867513459481287f : -INFINITY;   // H^-0.5
    float m = warp_max(val);
    float e = act ? expf(val-m) : 0.f;
    float ssum = warp_sum(e);
    float p = e/ssum;
    // top-8 threshold on e (rank on e == rank on p; e>=0 -> bits monotone)
    unsigned u = __float_as_uint(e);
    unsigned prefix = 0;
    #pragma unroll
    for(int bit=30; bit>=0; --bit){
      unsigned t = prefix | (1u<<bit);
      int c = __popcll(__ballot(u >= t));
      if(c >= 8) prefix = t;
    }
    if(act) coef[((size_t)bh*196 + i)*24 + lane] = (u >= prefix) ? p : 0.f;
  }
}

// ---------------- basis[r][j] = thresh(|proj_back_n[j][r]|) ----------------
__global__ __launch_bounds__(256) void basis_kernel(const float* __restrict__ pb,
    float* __restrict__ basis){
  int t = blockIdx.x*256 + threadIdx.x;
  if(t < RN_*N_){
    int r = t/N_, j = t%N_;
    float v = fabsf(pb[(size_t)j*RN_ + r]);
    basis[t] = (v > 0.02f) ? v : 0.f;
  }
}

// ---------------- mask v4: one WAVE per 4 rows; ballot compare-radix top-50 ----------------
__global__ __launch_bounds__(256) void mask4_kernel(const float* __restrict__ coef,
    const float* __restrict__ basis, unsigned int* __restrict__ maskw){
  __shared__ float Bs[24*256];
  int tid = threadIdx.x, lane = tid&63, wv = tid>>6;
  for(int idx = tid; idx < 24*256; idx += 256){
    int r = idx>>8, q = idx&255;
    int e = ((q&3)<<6) | (q>>2);          // inverse of dest mapping
    Bs[idx] = (e < N_) ? basis[r*N_ + e] : 0.f;
  }
  __syncthreads();
  int rowbase = blockIdx.x*16 + wv*4;     // 9456 blocks * 16 rows = 151296
  #pragma unroll
  for(int j=0;j<4;++j){
    int row = rowbase + j;                // (b*H+h)*197 + qi
    int qi = row % N_; int bh = row / N_;
    if(qi==0){
      if(lane<8){
        unsigned v = (lane<6)?0xFFFFFFFFu:((lane==6)?0x1Fu:0u);
        maskw[(size_t)row*8+lane]=v;
      }
      continue;
    }
    float cfv = (lane<24) ? coef[((size_t)bh*196 + (qi-1))*24 + lane] : 0.f;
    unsigned long long nz = __ballot(cfv != 0.f);
    float4 av = make_float4(0.f,0.f,0.f,0.f);
    while(nz){
      int r = __ffsll((unsigned long long)nz) - 1;
      nz &= nz - 1;
      float c = __uint_as_float(__builtin_amdgcn_readlane(__float_as_uint(cfv), r));
      float4 bv = *(const float4*)&Bs[r*256 + lane*4];
      av.x += c*bv.x; av.y += c*bv.y; av.z += c*bv.z; av.w += c*bv.w;
    }
    unsigned u0=__float_as_uint(av.x), u1=__float_as_uint(av.y);
    unsigned u2=__float_as_uint(av.z), u3=__float_as_uint(av.w);
    unsigned prefix = 0;
    #pragma unroll
    for(int bit=30; bit>=0; --bit){
      unsigned t = prefix | (1u<<bit);
      int c = __popcll(__ballot(u0 >= t)) + __popcll(__ballot(u1 >= t))
            + __popcll(__ballot(u2 >= t)) + __popcll(__ballot(u3 >= t));
      if(c >= 50) prefix = t;
    }
    unsigned uu[4] = {u0,u1,u2,u3};
    #pragma unroll
    for(int r=0;r<4;++r){
      bool valid = (r<3) | (lane<5);
      bool keep = valid && (uu[r] >= prefix);
      unsigned long long bal = __ballot(keep);
      if(lane==0){
        maskw[(size_t)row*8 + 2*r]   = (unsigned)(bal & 0xFFFFFFFFull);
        maskw[(size_t)row*8 + 2*r+1] = (unsigned)(bal>>32);
      }
    }
  }
}

// ---------------- masked attention v3: MFMA flash-style, one block per (b,h) ----------------
__global__ __launch_bounds__(512) void attn3_kernel(const unsigned short* __restrict__ qkv,
    const unsigned int* __restrict__ maskw, unsigned short* __restrict__ attn_out){
  int bh = blockIdx.x; int b = bh/H_, h = bh%H_;
  int tid = threadIdx.x, lane = tid&63, wv = tid>>6;
  int g = lane>>4, c16 = lane&15;
  __shared__ unsigned short Kb[208*64];     // 26.6 KB
  __shared__ unsigned short Vt[64*220];     // 28.2 KB
  __shared__ unsigned short Pl[8*16*224];   // 57.3 KB
  __shared__ unsigned int   Ml[8][16][8];   // 4 KB
  const unsigned short* Kbase = qkv + ((size_t)(b*N_)*3 + 1)*C_ + h*CH_;
  const unsigned short* Vbase = qkv + ((size_t)(b*N_)*3 + 2)*C_ + h*CH_;
  for(int idx = tid; idx < 208*32; idx += 512){
    int k = idx>>5, cp = idx&31;
    unsigned pk = 0;
    if(k < N_) pk = *(const unsigned*)(Kbase + (size_t)k*3*C_ + cp*2);
    unsigned off = (unsigned)(k*128 + cp*4) ^ ((unsigned)(k&7)<<4);
    *(unsigned*)((char*)Kb + off) = pk;
  }
  for(int idx = tid; idx < 64*110; idx += 512){
    int kp = idx>>6, c = idx&63;
    int k0 = kp*2, k1 = kp*2+1;
    unsigned v0 = (k0<N_) ? Vbase[(size_t)k0*3*C_ + c] : 0;
    unsigned v1 = (k1<N_) ? Vbase[(size_t)k1*3*C_ + c] : 0;
    *(unsigned*)((char*)Vt + c*440 + kp*4) = v0 | (v1<<16);
  }
  __syncthreads();
  size_t pbase = (size_t)wv*16*448;
  for(int i=lane;i<128;i+=64){
    int ql = i>>3; int kk = 208 + (i&7)*2;
    unsigned off = (unsigned)(ql*448 + kk*2) ^ ((unsigned)(ql&7)<<4);
    *(unsigned*)((char*)Pl + pbase + off) = 0u;
  }
  for(int t = wv; t < 13; t += 8){
    int qb = t*16;
    for(int i = lane; i < 128; i += 64){
      int row = i>>3, word = i&7;
      int qr = qb+row; if(qr>196) qr=196;
      Ml[wv][row][word] = maskw[(size_t)(bh*N_+qr)*8 + word];
    }
    int qrow = qb + c16; if(qrow>196) qrow=196;
    const unsigned short* Qr = qkv + ((size_t)(b*N_+qrow)*3)*C_ + h*CH_ + g*8;
    short8 af[2];
    af[0] = *(const short8*)(Qr);
    af[1] = *(const short8*)(Qr + 32);
    f32x4 sf[13];
    #pragma unroll
    for(int f=0;f<13;++f){
      sf[f] = (f32x4){0.f,0.f,0.f,0.f};
      #pragma unroll
      for(int s=0;s<2;++s){
        int row = f*16 + c16;
        unsigned off = (unsigned)(row*128 + s*64 + g*16) ^ ((unsigned)(row&7)<<4);
        short8 bfr = *(const short8*)((char*)Kb + off);
        sf[f] = __builtin_amdgcn_mfma_f32_16x16x32_bf16(af[s], bfr, sf[f], 0,0,0);
      }
      sf[f][0]*=0.125f; sf[f][1]*=0.125f; sf[f][2]*=0.125f; sf[f][3]*=0.125f;
    }
    unsigned keep[4] = {0,0,0,0};
    float m[4] = {-FLT_MAX,-FLT_MAX,-FLT_MAX,-FLT_MAX};
    #pragma unroll
    for(int f=0;f<13;++f)
      #pragma unroll
      for(int r=0;r<4;++r){
        unsigned bit = (Ml[wv][g*4+r][f>>1] >> ((f&1)*16 + c16)) & 1u;
        keep[r] |= bit<<f;
        if(bit) m[r] = fmaxf(m[r], sf[f][r]);
      }
    #pragma unroll
    for(int r=0;r<4;++r){
      #pragma unroll
      for(int o=8;o>=1;o>>=1) m[r] = fmaxf(m[r], __shfl_xor(m[r], o));
    }
    float sum[4] = {0,0,0,0};
    #pragma unroll
    for(int f=0;f<13;++f)
      #pragma unroll
      for(int r=0;r<4;++r){
        float e = ((keep[r]>>f)&1u) ? expf(sf[f][r]-m[r]) : 0.f;
        sf[f][r] = e; sum[r] += e;
      }
    #pragma unroll
    for(int r=0;r<4;++r){
      #pragma unroll
      for(int o=8;o>=1;o>>=1) sum[r] += __shfl_xor(sum[r], o);
      sum[r] = 1.f/sum[r];
    }
    #pragma unroll
    for(int f=0;f<13;++f)
      #pragma unroll
      for(int r=0;r<4;++r){
        int ql = g*4+r;
        unsigned off = (unsigned)(ql*448 + (f*16+c16)*2) ^ ((unsigned)(ql&7)<<4);
        *(unsigned short*)((char*)Pl + pbase + off) = f2bf(sf[f][r]*sum[r]);
      }
    #pragma unroll
    for(int ct=0;ct<4;++ct){
      f32x4 oa = (f32x4){0.f,0.f,0.f,0.f};
      #pragma unroll
      for(int ks=0;ks<7;++ks){
        unsigned offa = (unsigned)(c16*448 + (ks*32+g*8)*2) ^ ((unsigned)(c16&7)<<4);
        short8 pa = *(const short8*)((char*)Pl + pbase + offa);
        short8 vb = *(const short8*)((char*)Vt + (size_t)(ct*16+c16)*440 + (ks*32+g*8)*2);
        oa = __builtin_amdgcn_mfma_f32_16x16x32_bf16(pa, vb, oa, 0,0,0);
      }
      #pragma unroll
      for(int r=0;r<4;++r){
        int qq = qb + g*4 + r;
        if(qq < N_)
          attn_out[((size_t)(b*N_+qq))*C_ + h*CH_ + ct*16 + c16] = f2bf(oa[r]);
      }
    }
  }
}

extern "C" void kernel_launch(void* const* d_in, const int* in_sizes, int n_in,
                              void* d_out, int out_size, void* d_ws, size_t ws_size,
                              hipStream_t stream){
  const float* x    =(const float*)d_in[0];
  const float* Wqkv =(const float*)d_in[1];
  const float* Wcq  =(const float*)d_in[2];
  const float* bcq  =(const float*)d_in[3];
  const float* Wck  =(const float*)d_in[4];
  const float* bck  =(const float*)d_in[5];
  const float* proj_n=(const float*)d_in[6];
  const float* proj_back_n=(const float*)d_in[7];
  const float* Wproj=(const float*)d_in[8];
  const float* bproj=(const float*)d_in[9];
  const float* g1=(const float*)d_in[10];
  const float* b1=(const float*)d_in[11];
  const float* g2=(const float*)d_in[12];
  const float* b2=(const float*)d_in[13];
  const float* W1=(const float*)d_in[14];
  const float* bfc1=(const float*)d_in[15];
  const float* W2=(const float*)d_in[16];
  const float* bfc2=(const float*)d_in[17];
  float* out=(float*)d_out;

  float* ws=(float*)d_ws;
  size_t off=0;
  unsigned short* hbuf = (unsigned short*)(ws+off); off += (size_t)12608*768/2;
  size_t qkv_off = off;
  unsigned short* qkv = (unsigned short*)(ws+off); off += (size_t)12608*2304/2;
  off += (size_t)768*197*32;   // padding (hidden alias headroom)
  off += (size_t)768*197*32;
  off += (size_t)768*32*24;
  float* coef = ws+off;        off += (size_t)768*196*24;
  float* basis= ws+off;        off += 4736;
  unsigned int* maskw=(unsigned int*)(ws+off); off += (size_t)768*197*8;
  unsigned short* WqkvT = (unsigned short*)(ws+off); off += (size_t)2304*768/2;
  unsigned short* WprojT= (unsigned short*)(ws+off); off += (size_t)768*768/2;
  unsigned short* W1T   = (unsigned short*)(ws+off); off += (size_t)3072*768/2;
  unsigned short* W2T   = (unsigned short*)(ws+off); off += (size_t)768*3072/2;
  unsigned short* attn_out = hbuf;                    // alias (hbuf dead after qkv GEMM)
  unsigned short* hidden = (unsigned short*)(ws+qkv_off); // alias (qkv dead by MLP)
  float* x1 = out;

  // 0. weight transpose+bf16 conversions
  wtrans_kernel<<<dim3(72,24),256,0,stream>>>(Wqkv, WqkvT, 768, 2304);
  wtrans_kernel<<<dim3(24,24),256,0,stream>>>(Wproj, WprojT, 768, 768);
  wtrans_kernel<<<dim3(96,24),256,0,stream>>>(W1, W1T, 768, 3072);
  wtrans_kernel<<<dim3(24,96),256,0,stream>>>(W2, W2T, 3072, 768);
  // 1. h = LN(x) -> bf16
  ln_kernel<<<12608,256,0,stream>>>(x,g1,b1,hbuf);
  // 2. qkv = h @ Wqkv (bf16 out)
  gemm_bf16<0,0,1><<<dim3(18,99),256,0,stream>>>(hbuf,WqkvT,nullptr,nullptr,qkv,12608,768,2304);
  // 3. fused cheap path v2
  cheap_kernel<<<768,512,0,stream>>>(qkv,Wcq,bcq,Wck,bck,proj_n,coef);
  // 4. basis
  basis_kernel<<<19,256,0,stream>>>(proj_back_n,basis);
  // 5. approx_attn + budget mask
  mask4_kernel<<<9456,256,0,stream>>>(coef,basis,maskw);
  // 6. masked attention (MFMA)
  attn3_kernel<<<768,512,0,stream>>>(qkv,maskw,attn_out);
  // 7. x1 = x + attn_out @ Wproj + bproj   (x1 == d_out)
  gemm_bf16<0,1,0><<<dim3(6,99),256,0,stream>>>(attn_out,WprojT,bproj,x,x1,12608,768,768);
  // 8. h2 = LN(x1) -> bf16 (reuse hbuf)
  ln_kernel<<<12608,256,0,stream>>>(x1,g2,b2,hbuf);
  // 9. hidden = gelu(h2 @ W1 + bfc1) -> bf16
  gemm_bf16<1,0,1><<<dim3(24,99),256,0,stream>>>(hbuf,W1T,bfc1,nullptr,hidden,12608,768,3072);
  // 10. out = x1 + hidden @ W2 + bfc2
  gemm_bf16<0,1,0><<<dim3(6,99),256,0,stream>>>(hidden,W2T,bfc2,x1,out,12608,3072,768);
}

// Round 12
// 725.383 us; speedup vs baseline: 6.3217x; 1.0508x over previous
//
#include <hip/hip_runtime.h>
#include <math.h>
#include <float.h>

#define B_ 64
#define N_ 197
#define C_ 768
#define H_ 12
#define CH_ 64
#define RC_ 32
#define RN_ 24

typedef __attribute__((ext_vector_type(8))) short short8;
typedef __attribute__((ext_vector_type(4))) float f32x4;
typedef __attribute__((address_space(3))) void  lds_void;
typedef __attribute__((address_space(1))) const void g_void;

__device__ __forceinline__ float warp_sum(float v){
  #pragma unroll
  for(int o=32;o>=1;o>>=1) v += __shfl_xor(v,o);
  return v;
}
__device__ __forceinline__ float warp_max(float v){
  #pragma unroll
  for(int o=32;o>=1;o>>=1) v = fmaxf(v,__shfl_xor(v,o));
  return v;
}
__device__ __forceinline__ unsigned short f2bf(float f){
  union{float f; unsigned u;} c; c.f = f;
  unsigned r = c.u + 0x7FFF + ((c.u>>16)&1);
  return (unsigned short)(r>>16);
}
__device__ __forceinline__ float bf2f(unsigned short u){
  union{unsigned u; float f;} c; c.u = ((unsigned)u)<<16; return c.f;
}

// ---------------- LayerNorm: one block per row of 768, bf16 out ----------------
__global__ __launch_bounds__(256) void ln_kernel(const float* __restrict__ x,
    const float* __restrict__ g, const float* __restrict__ bb, unsigned short* __restrict__ out){
  int r = blockIdx.x; int tid = threadIdx.x;
  const float* xr = x + (size_t)r*C_;
  float v0=xr[tid], v1=xr[tid+256], v2=xr[tid+512];
  __shared__ float red[8];
  float s = warp_sum(v0+v1+v2);
  if((tid&63)==0) red[tid>>6]=s;
  __syncthreads();
  float mu = (red[0]+red[1]+red[2]+red[3]) * (1.f/768.f);
  float d0=v0-mu,d1=v1-mu,d2=v2-mu;
  float s2 = warp_sum(d0*d0+d1*d1+d2*d2);
  if((tid&63)==0) red[4+(tid>>6)]=s2;
  __syncthreads();
  float rinv = rsqrtf((red[4]+red[5]+red[6]+red[7])*(1.f/768.f)+1e-5f);
  unsigned short* orow = out + (size_t)r*C_;
  orow[tid]     = f2bf(d0*rinv*g[tid]    +bb[tid]);
  orow[tid+256] = f2bf(d1*rinv*g[tid+256]+bb[tid+256]);
  orow[tid+512] = f2bf(d2*rinv*g[tid+512]+bb[tid+512]);
}

// ---------------- transpose+convert: in f32 [K][N] -> out bf16 [N][K] ----------------
__global__ __launch_bounds__(256) void wtrans_kernel(const float* __restrict__ in,
    unsigned short* __restrict__ out, int K, int N){
  __shared__ float tile[32][33];
  int n0 = blockIdx.x*32, k0 = blockIdx.y*32;
  int tx = threadIdx.x&31, ty = threadIdx.x>>5;   // ty: 8 rows per pass
  #pragma unroll
  for(int i=0;i<4;++i) tile[ty+8*i][tx] = in[(size_t)(k0+ty+8*i)*N + n0+tx];
  __syncthreads();
  #pragma unroll
  for(int i=0;i<4;++i) out[(size_t)(n0+ty+8*i)*K + k0+tx] = f2bf(tile[tx][ty+8*i]);
}

// ---------------- Wcq/Wck f32[64][32] -> bf16 transposed [32][64] ----------------
__global__ __launch_bounds__(256) void wcprep_kernel(const float* __restrict__ Wcq,
    const float* __restrict__ Wck, unsigned short* __restrict__ WcqT,
    unsigned short* __restrict__ WckT){
  int t = blockIdx.x*256 + threadIdx.x;
  if(t < 2048){
    int c = t>>6, k = t&63;
    WcqT[t] = f2bf(Wcq[k*32+c]);
    WckT[t] = f2bf(Wck[k*32+c]);
  }
}

// ---------------- bf16 MFMA GEMM, double-buffered ----------------
template<int ACT, int RESID, int OUTBF16>
__global__ __launch_bounds__(256) void gemm_bf16(
    const unsigned short* __restrict__ A, const unsigned short* __restrict__ WT,
    const float* __restrict__ bias, const float* __restrict__ resid,
    void* __restrict__ Cout, int M, int K, int Nc){
  __shared__ unsigned short As[2*128*32];
  __shared__ unsigned short Bs[2*128*32];
  int tid = threadIdx.x, lane = tid&63, wid = tid>>6;
  int m0 = blockIdx.y*128, n0 = blockIdx.x*128;
  int wr = wid>>1, wc = wid&1;
  int lm = lane&15, lg = lane>>4;
  int row0 = tid>>2,         kc0 = (tid&3)*8;
  int row1 = (256+tid)>>2,   kc1 = (tid&3)*8;
  int ar0 = m0+row0; if(ar0 > M-1) ar0 = M-1;
  int ar1 = m0+row1; if(ar1 > M-1) ar1 = M-1;
  const unsigned short* gA0 = A  + (size_t)ar0*K + kc0;
  const unsigned short* gA1 = A  + (size_t)ar1*K + kc1;
  const unsigned short* gB0 = WT + (size_t)(n0+row0)*K + kc0;
  const unsigned short* gB1 = WT + (size_t)(n0+row1)*K + kc1;
  unsigned short* lA0 = As + (wid*64)*8;
  unsigned short* lA1 = As + (256 + wid*64)*8;
  unsigned short* lB0 = Bs + (wid*64)*8;
  unsigned short* lB1 = Bs + (256 + wid*64)*8;

#define STAGE_(buf, kt) do{ \
    __builtin_amdgcn_global_load_lds((g_void*)(gA0 + (kt)), (lds_void*)(lA0 + (buf)*4096), 16, 0, 0); \
    __builtin_amdgcn_global_load_lds((g_void*)(gB0 + (kt)), (lds_void*)(lB0 + (buf)*4096), 16, 0, 0); \
    __builtin_amdgcn_global_load_lds((g_void*)(gA1 + (kt)), (lds_void*)(lA1 + (buf)*4096), 16, 0, 0); \
    __builtin_amdgcn_global_load_lds((g_void*)(gB1 + (kt)), (lds_void*)(lB1 + (buf)*4096), 16, 0, 0); \
  }while(0)

  f32x4 acc[4][4] = {};
  const int nt = K/32;
  STAGE_(0, 0);
  __syncthreads();
  for(int t=0; t<nt; t+=2){
    STAGE_(1, (t+1)*32);
    {
      short8 af[4], bfv[4];
      #pragma unroll
      for(int i=0;i<4;++i){
        af[i]  = *(const short8*)(As + (64*wr + 16*i + lm)*32 + lg*8);
        bfv[i] = *(const short8*)(Bs + (64*wc + 16*i + lm)*32 + lg*8);
      }
      #pragma unroll
      for(int i=0;i<4;++i)
        #pragma unroll
        for(int j=0;j<4;++j)
          acc[i][j] = __builtin_amdgcn_mfma_f32_16x16x32_bf16(af[i], bfv[j], acc[i][j], 0,0,0);
    }
    __syncthreads();
    if(t+2 < nt) STAGE_(0, (t+2)*32);
    {
      short8 af[4], bfv[4];
      #pragma unroll
      for(int i=0;i<4;++i){
        af[i]  = *(const short8*)(As + 4096 + (64*wr + 16*i + lm)*32 + lg*8);
        bfv[i] = *(const short8*)(Bs + 4096 + (64*wc + 16*i + lm)*32 + lg*8);
      }
      #pragma unroll
      for(int i=0;i<4;++i)
        #pragma unroll
        for(int j=0;j<4;++j)
          acc[i][j] = __builtin_amdgcn_mfma_f32_16x16x32_bf16(af[i], bfv[j], acc[i][j], 0,0,0);
    }
    __syncthreads();
  }
#undef STAGE_
  #pragma unroll
  for(int i=0;i<4;++i){
    #pragma unroll
    for(int j=0;j<4;++j){
      int gcol = n0 + 64*wc + 16*j + lm;
      float bv = bias ? bias[gcol] : 0.f;
      #pragma unroll
      for(int r=0;r<4;++r){
        int grow = m0 + 64*wr + 16*i + lg*4 + r;
        if(grow < M){
          float cv = acc[i][j][r] + bv;
          if(ACT==1){
            float xx = cv;
            float p = xx*fmaf(xx*xx, 0.10294517f, 2.3022079f);
            float q = exp2f(p);
            cv = xx - xx*__builtin_amdgcn_rcpf(1.0f+q);
          }
          if(RESID) cv += resid[(size_t)grow*Nc + gcol];
          if(OUTBF16) ((unsigned short*)Cout)[(size_t)grow*Nc+gcol] = f2bf(cv);
          else        ((float*)Cout)[(size_t)grow*Nc+gcol] = cv;
        }
      }
    }
  }
}

// ---------------- fused cheap path v3: MFMA kp/qp + float4 kk + 2-row coef ----------------
// One block per (b,h), 512 threads, 74.3 KB LDS (2 blocks/CU).
__global__ __launch_bounds__(512) void cheap_kernel(
    const unsigned short* __restrict__ qkv,
    const unsigned short* __restrict__ WcqT, const float* __restrict__ bcq,
    const unsigned short* __restrict__ WckT, const float* __restrict__ bck,
    const float* __restrict__ proj_n, float* __restrict__ coef){
  int bh = blockIdx.x; int b = bh/H_, h = bh%H_;
  int tid = threadIdx.x, lane = tid&63, wv = tid>>6;
  int lm = lane&15, lg = lane>>4;
  __shared__ __align__(16) unsigned short KQ[208*64];  // 26.6 KB, XOR-swizzled; K then Q
  __shared__ __align__(16) float P2T[32*212];          // 27.1 KB: kp^T [c][n]; later qp row-major [208][32]
  __shared__ __align__(16) float PNT[24*200];          // 19.2 KB: proj_n^T, zero-padded
  __shared__ float KK[768];                            // 3 KB
  const unsigned short* Kbase = qkv + ((size_t)(b*N_)*3 + 1)*C_ + h*CH_;
  const unsigned short* Qbase = qkv + ((size_t)(b*N_)*3 + 0)*C_ + h*CH_;
  // stage K swizzled (zero-pad rows 197..207) + PNT transposed (zero-pad n>=197)
  for(int idx = tid; idx < 208*32; idx += 512){
    int k = idx>>5, cp = idx&31;
    unsigned v = (k < N_) ? *(const unsigned*)(Kbase + (size_t)k*3*C_ + cp*2) : 0u;
    unsigned off = (unsigned)(k*128 + cp*4) ^ ((unsigned)(k&7)<<4);
    *(unsigned*)((char*)KQ + off) = v;
  }
  for(int idx = tid; idx < 24*200; idx += 512){
    int r = idx/200, n = idx - r*200;
    PNT[idx] = (n < N_) ? proj_n[n*24+r] : 0.f;
  }
  __syncthreads();
  // kp = K @ Wck via MFMA -> P2T[c][n] (+bias); rows>=197 produce bias (x0 later)
  {
    short8 bfr[2][2];
    #pragma unroll
    for(int j=0;j<2;++j)
      #pragma unroll
      for(int s=0;s<2;++s)
        bfr[j][s] = *(const short8*)(WckT + (j*16+lm)*64 + s*32 + lg*8);
    float bias[2] = { bck[lm], bck[16+lm] };
    for(int t=wv; t<13; t+=8){
      int row = t*16 + lm;
      unsigned o0 = (unsigned)(row*128 + lg*16) ^ ((unsigned)(row&7)<<4);
      unsigned o1 = (unsigned)(row*128 + 64 + lg*16) ^ ((unsigned)(row&7)<<4);
      short8 a0 = *(const short8*)((char*)KQ + o0);
      short8 a1 = *(const short8*)((char*)KQ + o1);
      #pragma unroll
      for(int j=0;j<2;++j){
        f32x4 acc = (f32x4){0.f,0.f,0.f,0.f};
        acc = __builtin_amdgcn_mfma_f32_16x16x32_bf16(a0, bfr[j][0], acc, 0,0,0);
        acc = __builtin_amdgcn_mfma_f32_16x16x32_bf16(a1, bfr[j][1], acc, 0,0,0);
        #pragma unroll
        for(int r=0;r<4;++r)
          P2T[(j*16+lm)*212 + t*16 + lg*4 + r] = acc[r] + bias[j];
      }
    }
  }
  __syncthreads();
  // kk: KK[c*24+r] = sum_n kp[n][c]*proj_n[n][r] (float4 streams); stage Q over K
  {
    int i0 = tid, i1 = tid + 512;
    bool has1 = (i1 < 768);
    int c0 = i0/24, r0 = i0 - c0*24;
    int c1 = has1 ? i1/24 : 0, r1 = has1 ? (i1 - (i1/24)*24) : 0;
    float a0=0.f, a1=0.f;
    for(int n=0;n<200;n+=4){
      float4 x0 = *(const float4*)&P2T[c0*212+n];
      float4 p0 = *(const float4*)&PNT[r0*200+n];
      a0 += x0.x*p0.x; a0 += x0.y*p0.y; a0 += x0.z*p0.z; a0 += x0.w*p0.w;
      if(has1){
        float4 x1 = *(const float4*)&P2T[c1*212+n];
        float4 p1 = *(const float4*)&PNT[r1*200+n];
        a1 += x1.x*p1.x; a1 += x1.y*p1.y; a1 += x1.z*p1.z; a1 += x1.w*p1.w;
      }
    }
    KK[i0] = a0;
    if(has1) KK[i1] = a1;
    for(int idx = tid; idx < 197*32; idx += 512){
      int k = idx>>5, cp = idx&31;
      unsigned v = *(const unsigned*)(Qbase + (size_t)k*3*C_ + cp*2);
      unsigned off = (unsigned)(k*128 + cp*4) ^ ((unsigned)(k&7)<<4);
      *(unsigned*)((char*)KQ + off) = v;
    }
  }
  __syncthreads();
  // qp = Q @ Wcq via MFMA -> row-major qp[n][c] into P2T region ([208][32] fits)
  float* QP = P2T;
  {
    short8 bfr[2][2];
    #pragma unroll
    for(int j=0;j<2;++j)
      #pragma unroll
      for(int s=0;s<2;++s)
        bfr[j][s] = *(const short8*)(WcqT + (j*16+lm)*64 + s*32 + lg*8);
    float bias[2] = { bcq[lm], bcq[16+lm] };
    for(int t=wv; t<13; t+=8){
      int row = t*16 + lm;
      unsigned o0 = (unsigned)(row*128 + lg*16) ^ ((unsigned)(row&7)<<4);
      unsigned o1 = (unsigned)(row*128 + 64 + lg*16) ^ ((unsigned)(row&7)<<4);
      short8 a0 = *(const short8*)((char*)KQ + o0);
      short8 a1 = *(const short8*)((char*)KQ + o1);
      #pragma unroll
      for(int j=0;j<2;++j){
        f32x4 acc = (f32x4){0.f,0.f,0.f,0.f};
        acc = __builtin_amdgcn_mfma_f32_16x16x32_bf16(a0, bfr[j][0], acc, 0,0,0);
        acc = __builtin_amdgcn_mfma_f32_16x16x32_bf16(a1, bfr[j][1], acc, 0,0,0);
        #pragma unroll
        for(int r=0;r<4;++r)
          QP[(t*16 + lg*4 + r)*32 + j*16 + lm] = acc[r] + bias[j];
      }
    }
  }
  __syncthreads();
  // coef: 2 rows per wave (lanes 0-23 row A, 32-55 row B)
  int l32 = lane & 31, half = lane >> 5;
  bool act = l32 < RN_;
  int ll = act ? l32 : 0;
  float kkreg[32];
  #pragma unroll
  for(int c=0;c<32;++c) kkreg[c] = KK[c*24 + ll];
  for(int i2 = wv*2; i2 < 196; i2 += 16){
    int i = i2 + half;              // row index 0..195
    int n = i + 1;
    float accv = 0.f;
    #pragma unroll
    for(int q=0;q<8;++q){
      float4 v4 = *(const float4*)&QP[n*32 + q*4];
      accv += v4.x*kkreg[q*4];   accv += v4.y*kkreg[q*4+1];
      accv += v4.z*kkreg[q*4+2]; accv += v4.w*kkreg[q*4+3];
    }
    float val = act ? accv * 0.28867513459481287f : -INFINITY;  // H^-0.5
    float m = val;
    #pragma unroll
    for(int o=16;o>=1;o>>=1) m = fmaxf(m, __shfl_xor(m, o));
    float e = act ? expf(val - m) : 0.f;
    float ssum = e;
    #pragma unroll
    for(int o=16;o>=1;o>>=1) ssum += __shfl_xor(ssum, o);
    float p = e/ssum;
    unsigned u = __float_as_uint(e);
    unsigned pL=0, pH=0;
    #pragma unroll
    for(int bit=30; bit>=0; --bit){
      unsigned tL = pL | (1u<<bit), tH = pH | (1u<<bit);
      unsigned thr = half ? tH : tL;
      unsigned long long bal = __ballot(u >= thr);
      int cL = __popcll(bal & 0xFFFFFFull);
      int cH = __popcll((bal>>32) & 0xFFFFFFull);
      if(cL>=8) pL=tL;
      if(cH>=8) pH=tH;
    }
    unsigned myp = half ? pH : pL;
    if(act) coef[((size_t)bh*196 + i)*24 + l32] = (u >= myp) ? p : 0.f;
  }
}

// ---------------- basis[r][j] = thresh(|proj_back_n[j][r]|) ----------------
__global__ __launch_bounds__(256) void basis_kernel(const float* __restrict__ pb,
    float* __restrict__ basis){
  int t = blockIdx.x*256 + threadIdx.x;
  if(t < RN_*N_){
    int r = t/N_, j = t%N_;
    float v = fabsf(pb[(size_t)j*RN_ + r]);
    basis[t] = (v > 0.02f) ? v : 0.f;
  }
}

// ---------------- mask v4: one WAVE per 4 rows; ballot compare-radix top-50 ----------------
__global__ __launch_bounds__(256) void mask4_kernel(const float* __restrict__ coef,
    const float* __restrict__ basis, unsigned int* __restrict__ maskw){
  __shared__ float Bs[24*256];
  int tid = threadIdx.x, lane = tid&63, wv = tid>>6;
  for(int idx = tid; idx < 24*256; idx += 256){
    int r = idx>>8, q = idx&255;
    int e = ((q&3)<<6) | (q>>2);          // inverse of dest mapping
    Bs[idx] = (e < N_) ? basis[r*N_ + e] : 0.f;
  }
  __syncthreads();
  int rowbase = blockIdx.x*16 + wv*4;     // 9456 blocks * 16 rows = 151296
  #pragma unroll
  for(int j=0;j<4;++j){
    int row = rowbase + j;                // (b*H+h)*197 + qi
    int qi = row % N_; int bh = row / N_;
    if(qi==0){
      if(lane<8){
        unsigned v = (lane<6)?0xFFFFFFFFu:((lane==6)?0x1Fu:0u);
        maskw[(size_t)row*8+lane]=v;
      }
      continue;
    }
    float cfv = (lane<24) ? coef[((size_t)bh*196 + (qi-1))*24 + lane] : 0.f;
    unsigned long long nz = __ballot(cfv != 0.f);
    float4 av = make_float4(0.f,0.f,0.f,0.f);
    while(nz){
      int r = __ffsll((unsigned long long)nz) - 1;
      nz &= nz - 1;
      float c = __uint_as_float(__builtin_amdgcn_readlane(__float_as_uint(cfv), r));
      float4 bv = *(const float4*)&Bs[r*256 + lane*4];
      av.x += c*bv.x; av.y += c*bv.y; av.z += c*bv.z; av.w += c*bv.w;
    }
    unsigned u0=__float_as_uint(av.x), u1=__float_as_uint(av.y);
    unsigned u2=__float_as_uint(av.z), u3=__float_as_uint(av.w);
    unsigned prefix = 0;
    #pragma unroll
    for(int bit=30; bit>=0; --bit){
      unsigned t = prefix | (1u<<bit);
      int c = __popcll(__ballot(u0 >= t)) + __popcll(__ballot(u1 >= t))
            + __popcll(__ballot(u2 >= t)) + __popcll(__ballot(u3 >= t));
      if(c >= 50) prefix = t;
    }
    unsigned uu[4] = {u0,u1,u2,u3};
    #pragma unroll
    for(int r=0;r<4;++r){
      bool valid = (r<3) | (lane<5);
      bool keep = valid && (uu[r] >= prefix);
      unsigned long long bal = __ballot(keep);
      if(lane==0){
        maskw[(size_t)row*8 + 2*r]   = (unsigned)(bal & 0xFFFFFFFFull);
        maskw[(size_t)row*8 + 2*r+1] = (unsigned)(bal>>32);
      }
    }
  }
}

// ---------------- masked attention v3: MFMA flash-style, one block per (b,h) ----------------
__global__ __launch_bounds__(512) void attn3_kernel(const unsigned short* __restrict__ qkv,
    const unsigned int* __restrict__ maskw, unsigned short* __restrict__ attn_out){
  int bh = blockIdx.x; int b = bh/H_, h = bh%H_;
  int tid = threadIdx.x, lane = tid&63, wv = tid>>6;
  int g = lane>>4, c16 = lane&15;
  __shared__ unsigned short Kb[208*64];     // 26.6 KB
  __shared__ unsigned short Vt[64*220];     // 28.2 KB
  __shared__ unsigned short Pl[8*16*224];   // 57.3 KB
  __shared__ unsigned int   Ml[8][16][8];   // 4 KB
  const unsigned short* Kbase = qkv + ((size_t)(b*N_)*3 + 1)*C_ + h*CH_;
  const unsigned short* Vbase = qkv + ((size_t)(b*N_)*3 + 2)*C_ + h*CH_;
  for(int idx = tid; idx < 208*32; idx += 512){
    int k = idx>>5, cp = idx&31;
    unsigned pk = 0;
    if(k < N_) pk = *(const unsigned*)(Kbase + (size_t)k*3*C_ + cp*2);
    unsigned off = (unsigned)(k*128 + cp*4) ^ ((unsigned)(k&7)<<4);
    *(unsigned*)((char*)Kb + off) = pk;
  }
  for(int idx = tid; idx < 64*110; idx += 512){
    int kp = idx>>6, c = idx&63;
    int k0 = kp*2, k1 = kp*2+1;
    unsigned v0 = (k0<N_) ? Vbase[(size_t)k0*3*C_ + c] : 0;
    unsigned v1 = (k1<N_) ? Vbase[(size_t)k1*3*C_ + c] : 0;
    *(unsigned*)((char*)Vt + c*440 + kp*4) = v0 | (v1<<16);
  }
  __syncthreads();
  size_t pbase = (size_t)wv*16*448;
  for(int i=lane;i<128;i+=64){
    int ql = i>>3; int kk = 208 + (i&7)*2;
    unsigned off = (unsigned)(ql*448 + kk*2) ^ ((unsigned)(ql&7)<<4);
    *(unsigned*)((char*)Pl + pbase + off) = 0u;
  }
  for(int t = wv; t < 13; t += 8){
    int qb = t*16;
    for(int i = lane; i < 128; i += 64){
      int row = i>>3, word = i&7;
      int qr = qb+row; if(qr>196) qr=196;
      Ml[wv][row][word] = maskw[(size_t)(bh*N_+qr)*8 + word];
    }
    int qrow = qb + c16; if(qrow>196) qrow=196;
    const unsigned short* Qr = qkv + ((size_t)(b*N_+qrow)*3)*C_ + h*CH_ + g*8;
    short8 af[2];
    af[0] = *(const short8*)(Qr);
    af[1] = *(const short8*)(Qr + 32);
    f32x4 sf[13];
    #pragma unroll
    for(int f=0;f<13;++f){
      sf[f] = (f32x4){0.f,0.f,0.f,0.f};
      #pragma unroll
      for(int s=0;s<2;++s){
        int row = f*16 + c16;
        unsigned off = (unsigned)(row*128 + s*64 + g*16) ^ ((unsigned)(row&7)<<4);
        short8 bfr = *(const short8*)((char*)Kb + off);
        sf[f] = __builtin_amdgcn_mfma_f32_16x16x32_bf16(af[s], bfr, sf[f], 0,0,0);
      }
      sf[f][0]*=0.125f; sf[f][1]*=0.125f; sf[f][2]*=0.125f; sf[f][3]*=0.125f;
    }
    unsigned keep[4] = {0,0,0,0};
    float m[4] = {-FLT_MAX,-FLT_MAX,-FLT_MAX,-FLT_MAX};
    #pragma unroll
    for(int f=0;f<13;++f)
      #pragma unroll
      for(int r=0;r<4;++r){
        unsigned bit = (Ml[wv][g*4+r][f>>1] >> ((f&1)*16 + c16)) & 1u;
        keep[r] |= bit<<f;
        if(bit) m[r] = fmaxf(m[r], sf[f][r]);
      }
    #pragma unroll
    for(int r=0;r<4;++r){
      #pragma unroll
      for(int o=8;o>=1;o>>=1) m[r] = fmaxf(m[r], __shfl_xor(m[r], o));
    }
    float sum[4] = {0,0,0,0};
    #pragma unroll
    for(int f=0;f<13;++f)
      #pragma unroll
      for(int r=0;r<4;++r){
        float e = ((keep[r]>>f)&1u) ? expf(sf[f][r]-m[r]) : 0.f;
        sf[f][r] = e; sum[r] += e;
      }
    #pragma unroll
    for(int r=0;r<4;++r){
      #pragma unroll
      for(int o=8;o>=1;o>>=1) sum[r] += __shfl_xor(sum[r], o);
      sum[r] = 1.f/sum[r];
    }
    #pragma unroll
    for(int f=0;f<13;++f)
      #pragma unroll
      for(int r=0;r<4;++r){
        int ql = g*4+r;
        unsigned off = (unsigned)(ql*448 + (f*16+c16)*2) ^ ((unsigned)(ql&7)<<4);
        *(unsigned short*)((char*)Pl + pbase + off) = f2bf(sf[f][r]*sum[r]);
      }
    #pragma unroll
    for(int ct=0;ct<4;++ct){
      f32x4 oa = (f32x4){0.f,0.f,0.f,0.f};
      #pragma unroll
      for(int ks=0;ks<7;++ks){
        unsigned offa = (unsigned)(c16*448 + (ks*32+g*8)*2) ^ ((unsigned)(c16&7)<<4);
        short8 pa = *(const short8*)((char*)Pl + pbase + offa);
        short8 vb = *(const short8*)((char*)Vt + (size_t)(ct*16+c16)*440 + (ks*32+g*8)*2);
        oa = __builtin_amdgcn_mfma_f32_16x16x32_bf16(pa, vb, oa, 0,0,0);
      }
      #pragma unroll
      for(int r=0;r<4;++r){
        int qq = qb + g*4 + r;
        if(qq < N_)
          attn_out[((size_t)(b*N_+qq))*C_ + h*CH_ + ct*16 + c16] = f2bf(oa[r]);
      }
    }
  }
}

extern "C" void kernel_launch(void* const* d_in, const int* in_sizes, int n_in,
                              void* d_out, int out_size, void* d_ws, size_t ws_size,
                              hipStream_t stream){
  const float* x    =(const float*)d_in[0];
  const float* Wqkv =(const float*)d_in[1];
  const float* Wcq  =(const float*)d_in[2];
  const float* bcq  =(const float*)d_in[3];
  const float* Wck  =(const float*)d_in[4];
  const float* bck  =(const float*)d_in[5];
  const float* proj_n=(const float*)d_in[6];
  const float* proj_back_n=(const float*)d_in[7];
  const float* Wproj=(const float*)d_in[8];
  const float* bproj=(const float*)d_in[9];
  const float* g1=(const float*)d_in[10];
  const float* b1=(const float*)d_in[11];
  const float* g2=(const float*)d_in[12];
  const float* b2=(const float*)d_in[13];
  const float* W1=(const float*)d_in[14];
  const float* bfc1=(const float*)d_in[15];
  const float* W2=(const float*)d_in[16];
  const float* bfc2=(const float*)d_in[17];
  float* out=(float*)d_out;

  float* ws=(float*)d_ws;
  size_t off=0;
  unsigned short* hbuf = (unsigned short*)(ws+off); off += (size_t)12608*768/2;
  size_t qkv_off = off;
  unsigned short* qkv = (unsigned short*)(ws+off); off += (size_t)12608*2304/2;
  off += (size_t)768*197*32;   // padding (hidden alias headroom)
  off += (size_t)768*197*32;
  off += (size_t)768*32*24;
  float* coef = ws+off;        off += (size_t)768*196*24;
  float* basis= ws+off;        off += 4736;
  unsigned int* maskw=(unsigned int*)(ws+off); off += (size_t)768*197*8;
  unsigned short* WqkvT = (unsigned short*)(ws+off); off += (size_t)2304*768/2;
  unsigned short* WprojT= (unsigned short*)(ws+off); off += (size_t)768*768/2;
  unsigned short* W1T   = (unsigned short*)(ws+off); off += (size_t)3072*768/2;
  unsigned short* W2T   = (unsigned short*)(ws+off); off += (size_t)768*3072/2;
  unsigned short* WcqT  = (unsigned short*)(ws+off); off += 1024;
  unsigned short* WckT  = (unsigned short*)(ws+off); off += 1024;
  unsigned short* attn_out = hbuf;                    // alias (hbuf dead after qkv GEMM)
  unsigned short* hidden = (unsigned short*)(ws+qkv_off); // alias (qkv dead by MLP)
  float* x1 = out;

  // 0. weight transpose+bf16 conversions
  wtrans_kernel<<<dim3(72,24),256,0,stream>>>(Wqkv, WqkvT, 768, 2304);
  wtrans_kernel<<<dim3(24,24),256,0,stream>>>(Wproj, WprojT, 768, 768);
  wtrans_kernel<<<dim3(96,24),256,0,stream>>>(W1, W1T, 768, 3072);
  wtrans_kernel<<<dim3(24,96),256,0,stream>>>(W2, W2T, 3072, 768);
  wcprep_kernel<<<8,256,0,stream>>>(Wcq, Wck, WcqT, WckT);
  // 1. h = LN(x) -> bf16
  ln_kernel<<<12608,256,0,stream>>>(x,g1,b1,hbuf);
  // 2. qkv = h @ Wqkv (bf16 out)
  gemm_bf16<0,0,1><<<dim3(18,99),256,0,stream>>>(hbuf,WqkvT,nullptr,nullptr,qkv,12608,768,2304);
  // 3. fused cheap path v3 (MFMA kp/qp)
  cheap_kernel<<<768,512,0,stream>>>(qkv,WcqT,bcq,WckT,bck,proj_n,coef);
  // 4. basis
  basis_kernel<<<19,256,0,stream>>>(proj_back_n,basis);
  // 5. approx_attn + budget mask
  mask4_kernel<<<9456,256,0,stream>>>(coef,basis,maskw);
  // 6. masked attention (MFMA)
  attn3_kernel<<<768,512,0,stream>>>(qkv,maskw,attn_out);
  // 7. x1 = x + attn_out @ Wproj + bproj   (x1 == d_out)
  gemm_bf16<0,1,0><<<dim3(6,99),256,0,stream>>>(attn_out,WprojT,bproj,x,x1,12608,768,768);
  // 8. h2 = LN(x1) -> bf16 (reuse hbuf)
  ln_kernel<<<12608,256,0,stream>>>(x1,g2,b2,hbuf);
  // 9. hidden = gelu(h2 @ W1 + bfc1) -> bf16
  gemm_bf16<1,0,1><<<dim3(24,99),256,0,stream>>>(hbuf,W1T,bfc1,nullptr,hidden,12608,768,3072);
  // 10. out = x1 + hidden @ W2 + bfc2
  gemm_bf16<0,1,0><<<dim3(6,99),256,0,stream>>>(hidden,W2T,bfc2,x1,out,12608,3072,768);
}